// Round 13
// baseline (84785.657 us; speedup 1.0000x reference)
//
#include <hip/hip_runtime.h>

typedef __attribute__((ext_vector_type(4))) float f4;
using u32 = unsigned int;
using u64 = unsigned long long;

constexpr int NB_ = 16;    // batch
constexpr int NS_ = 512;   // seq len
constexpr int ND_ = 1024;  // input dim
constexpr int NH_ = 512;   // hidden
constexpr int NSP_ = 8;    // speakers
constexpr int NH2_ = 256;  // head hidden
constexpr int HP = 520;    // padded fp32 LDS row (130 f4)
constexpr int NBLK = 225;  // persistent grid

struct Params {
  const float *utt;
  const float *pg_wih, *pg_whh, *gg_wih, *gg_whh, *eg_wih, *eg_whh, *out_w1;
  const float *gixp, *gixg;   // precomputed x-projections [B*S][1536] fp32
  const float *init_party, *init_emotion;
  const float *pg_bih, *pg_bhh, *gg_bih, *gg_bhh, *eg_bih, *eg_bhh;
  const float *ln_g, *ln_b, *out_b1, *out_ln_g, *out_ln_b, *out_w2, *out_b2;
  const int *spk;
  float *party_pre;  // [2][B][H] raw pg output (pre-LN), parity t&1
  float *g_new;      // [2][B][H] raw gg output, parity t&1
  float *e_out;      // [2][B][H] raw eg output, parity te&1
  float *glob;       // [B][SP][H] post-LN (or raw init) global states
  float *h1buf;      // [2][B][H2] relu(e@W1+b1), parity th&1
  double *sums;      // [3 groups][4 slots][16 b][2] = 384 doubles
  u32 *flags;        // [NBLK * 16] arrival flags, one 64B line per block
  u32 *gen;          // release word
  float *out;        // [B][S]
};

__device__ __forceinline__ double sigm_d(double x) { return 1.0 / (1.0 + exp(-x)); }
__device__ __forceinline__ int sidx(int g, int slot, int b, int c) {
  return ((g * 4 + slot) * 16 + b) * 2 + c;
}
__device__ __forceinline__ double dot4d(f4 a, f4 w) {
  return ((double)a.x * w.x + (double)a.y * w.y) + ((double)a.z * w.z + (double)a.w * w.w);
}

// ---- cross-block plumbing: relaxed agent-scope atomics (bypass per-XCD L2; no flushes) ----
__device__ __forceinline__ void stA1(float* p, float v) {
  __hip_atomic_store(p, v, __ATOMIC_RELAXED, __HIP_MEMORY_SCOPE_AGENT);
}
__device__ __forceinline__ float ldA1(const float* p) {
  return __hip_atomic_load((float*)p, __ATOMIC_RELAXED, __HIP_MEMORY_SCOPE_AGENT);
}
__device__ __forceinline__ void stA2(float* p, float a, float b) {
  union { float f[2]; u64 u; } x; x.f[0] = a; x.f[1] = b;
  __hip_atomic_store((u64*)p, x.u, __ATOMIC_RELAXED, __HIP_MEMORY_SCOPE_AGENT);
}
__device__ __forceinline__ float2 ldA2(const float* p) {
  u64 u = __hip_atomic_load((u64*)p, __ATOMIC_RELAXED, __HIP_MEMORY_SCOPE_AGENT);
  union { u64 u; float f[2]; } x; x.u = u;
  return make_float2(x.f[0], x.f[1]);
}
__device__ __forceinline__ f4 ldA4(const float* p) {
  float2 lo = ldA2(p), hi = ldA2(p + 2);
  f4 v; v.x = lo.x; v.y = lo.y; v.z = hi.x; v.w = hi.y;
  return v;
}
__device__ __forceinline__ double ldAd(const double* p) {
  return __hip_atomic_load((double*)p, __ATOMIC_RELAXED, __HIP_MEMORY_SCOPE_AGENT);
}
__device__ __forceinline__ void stAd(double* p, double v) {
  __hip_atomic_store(p, v, __ATOMIC_RELAXED, __HIP_MEMORY_SCOPE_AGENT);
}

// Contention-free flag barrier (R12): per-block arrival flag on its own 64B line;
// block 0 scans flags in parallel, publishes gen. No RMW, no cache maintenance.
__device__ __forceinline__ void gbar_flags(u32* flags, u32* gen, int bid, int nb, u32 epoch) {
  __syncthreads();
  const int tid = threadIdx.x;
  if (bid == 0) {
    if (tid == 0)
      __hip_atomic_store(&flags[0], epoch, __ATOMIC_RELAXED, __HIP_MEMORY_SCOPE_AGENT);
    if (tid > 0 && tid < nb) {
      while (__hip_atomic_load(&flags[(size_t)tid * 16], __ATOMIC_RELAXED, __HIP_MEMORY_SCOPE_AGENT) < epoch)
        __builtin_amdgcn_s_sleep(1);
    }
    __syncthreads();
    if (tid == 0) {
      asm volatile("s_waitcnt vmcnt(0)" ::: "memory");
      __hip_atomic_store(gen, epoch, __ATOMIC_RELAXED, __HIP_MEMORY_SCOPE_AGENT);
    }
  } else {
    if (tid == 0) {
      asm volatile("s_waitcnt vmcnt(0) lgkmcnt(0)" ::: "memory");
      __hip_atomic_store(&flags[(size_t)bid * 16], epoch, __ATOMIC_RELAXED, __HIP_MEMORY_SCOPE_AGENT);
      while (__hip_atomic_load(gen, __ATOMIC_RELAXED, __HIP_MEMORY_SCOPE_AGENT) < epoch)
        __builtin_amdgcn_s_sleep(2);
    }
  }
  __syncthreads();
}

struct __align__(16) Smem {
  float hA[NB_][HP];
  float hB[NB_][HP];
  double red[8][NB_][4];
  double redH[16][NB_];
  double stats[NB_][2];
  double stats2[NB_][2];
  int spk[NB_], spkp[NB_];
};

// One pipelined step t: pg(t)|gg(t)|eg(t-1)|wb(t-1)|head(t-2)|score(t-3).
__device__ void step_body(const Params& p, Smem& sm, int t, int bid, int tid) {
  // ---------------- wb + sums zeroing (192..207) ----------------
  if (bid >= 192 && bid < 208) {
    int b = bid - 192;
    if (tid == 0) {
      stAd(&p.sums[sidx(0, (t + 2) & 3, b, 0)], 0.0); stAd(&p.sums[sidx(0, (t + 2) & 3, b, 1)], 0.0);
      stAd(&p.sums[sidx(1, (t + 2) & 3, b, 0)], 0.0); stAd(&p.sums[sidx(1, (t + 2) & 3, b, 1)], 0.0);
      stAd(&p.sums[sidx(2, (t + 1) & 3, b, 0)], 0.0); stAd(&p.sums[sidx(2, (t + 1) & 3, b, 1)], 0.0);
    }
    if (t >= 1 && t <= NS_) {
      int tw = t - 1;
      int spv = p.spk[b * NS_ + tw];
      double s = ldAd(&p.sums[sidx(1, tw & 3, b, 0)]), q = ldAd(&p.sums[sidx(1, tw & 3, b, 1)]);
      double mu = s * (1.0 / NH_), var = q * (1.0 / NH_) - mu * mu, rs = 1.0 / sqrt(var + 1e-5);
      const float* gsrc = p.g_new + (size_t)(tw & 1) * NB_ * NH_;
      float* gd = p.glob + (size_t)(b * NSP_ + spv) * NH_;
      for (int k2 = tid; k2 < NH_ / 2; k2 += 256) {
        float2 gv = ldA2(&gsrc[b * NH_ + k2 * 2]);
        double o0 = ((double)gv.x - mu) * rs * p.ln_g[k2 * 2] + p.ln_b[k2 * 2];
        double o1 = ((double)gv.y - mu) * rs * p.ln_g[k2 * 2 + 1] + p.ln_b[k2 * 2 + 1];
        stA2(&gd[k2 * 2], (float)o0, (float)o1);
      }
    }
  }
  // ---------------- head(t-2) (208..223) ----------------
  else if (bid >= 208 && bid < 224) {
    if (t >= 2 && t <= NS_ + 1) {
      int th = t - 2, ct = bid - 208;
      const float* er = p.e_out + (size_t)(th & 1) * NB_ * NH_;
      for (int idx = tid; idx < NB_ * NH_ / 4; idx += 256) {
        int b = idx >> 7, k = (idx & 127) * 4;
        *(f4*)&sm.hA[b][k] = ldA4(&er[b * NH_ + k]);
      }
      __syncthreads();
      {
        int ci = tid >> 4, kc = tid & 15, c = ct * 16 + ci;
        const f4* W = (const f4*)(p.out_w1 + (size_t)c * 512);
        const f4* H = (const f4*)&sm.hA[0][0];
        double acc[NB_] = {};
#pragma unroll
        for (int i = 0; i < 8; ++i) {
          int q = kc + 16 * i;
          f4 w = W[q];
#pragma unroll
          for (int b = 0; b < NB_; ++b) acc[b] += dot4d(H[b * 130 + q], w);
        }
#pragma unroll
        for (int b = 0; b < NB_; ++b) {
          double v = acc[b];
#pragma unroll
          for (int m = 1; m <= 8; m <<= 1) v += __shfl_xor(v, m);
          if (kc == 0) sm.redH[ci][b] = v;
        }
      }
      __syncthreads();
      {
        int b = tid >> 4, ci = tid & 15, c = ct * 16 + ci;
        double h1 = sm.redH[ci][b] + (double)p.out_b1[c];
        stA1(&p.h1buf[(size_t)(th & 1) * NB_ * NH2_ + b * NH2_ + c], (float)fmax(h1, 0.0));
      }
    }
  }
  // ---------------- score(t-3) (224) ----------------
  else if (bid == 224) {
    if (t >= 3 && t <= NS_ + 2) {
      int ts = t - 3;
      int b = tid >> 4, cg = tid & 15;
      const float* h1p = p.h1buf + (size_t)(ts & 1) * NB_ * NH2_;
      double s1 = 0, s2 = 0;
      float hv[16];
#pragma unroll
      for (int i = 0; i < 16; ++i) {
        float v = ldA1(&h1p[b * NH2_ + cg * 16 + i]);
        hv[i] = v; s1 += (double)v; s2 += (double)v * (double)v;
      }
#pragma unroll
      for (int m = 1; m <= 8; m <<= 1) { s1 += __shfl_xor(s1, m); s2 += __shfl_xor(s2, m); }
      double mu = s1 * (1.0 / NH2_), var = s2 * (1.0 / NH2_) - mu * mu, rstd = 1.0 / sqrt(var + 1e-5);
      double d = 0;
#pragma unroll
      for (int i = 0; i < 16; ++i) {
        int c = cg * 16 + i;
        d += (((double)hv[i] - mu) * rstd * p.out_ln_g[c] + (double)p.out_ln_b[c]) * (double)p.out_w2[c];
      }
#pragma unroll
      for (int m = 1; m <= 8; m <<= 1) d += __shfl_xor(d, m);
      if (cg == 0) p.out[b * NS_ + ts] = (float)sigm_d(d + (double)p.out_b2[0]);
    }
  }
  // ---------------- eg(t-1) (128..191) ----------------
  else if (bid >= 128) {
    if (t >= 1 && t <= NS_) {
      const int te = t - 1;
      const int jj0 = (bid - 128) * 8;
      if (te > 0 && tid < NB_) {
        double s = ldAd(&p.sums[sidx(2, (te - 1) & 3, tid, 0)]);
        double q = ldAd(&p.sums[sidx(2, (te - 1) & 3, tid, 1)]);
        double mu = s * (1.0 / NH_), var = q * (1.0 / NH_) - mu * mu;
        sm.stats[tid][0] = mu; sm.stats[tid][1] = 1.0 / sqrt(var + 1e-5);
      }
      if (tid >= NB_ && tid < 2 * NB_) {
        int b = tid - NB_;
        double s = ldAd(&p.sums[sidx(1, te & 3, b, 0)]);
        double q = ldAd(&p.sums[sidx(1, te & 3, b, 1)]);
        double mu = s * (1.0 / NH_), var = q * (1.0 / NH_) - mu * mu;
        sm.stats2[b][0] = mu; sm.stats2[b][1] = 1.0 / sqrt(var + 1e-5);
      }
      __syncthreads();
      const float* eprev = p.e_out + (size_t)((te - 1) & 1) * NB_ * NH_;
      const float* gcur  = p.g_new + (size_t)(te & 1) * NB_ * NH_;
      for (int idx = tid; idx < NB_ * NH_ / 2; idx += 256) {
        int half = idx >= NB_ * NH_ / 4;
        int r4 = idx & (NB_ * NH_ / 4 - 1);
        int b = r4 >> 7, k = (r4 & 127) * 4;
        f4 g4 = *(const f4*)&p.ln_g[k], b4 = *(const f4*)&p.ln_b[k];
        if (!half) {
          f4 v;
          if (te == 0) v = *(const f4*)&p.init_emotion[k];
          else {
            f4 pv = ldA4(&eprev[b * NH_ + k]);
            double mu = sm.stats[b][0], rs = sm.stats[b][1];
            v.x = (float)(((double)pv.x - mu) * rs * g4.x + b4.x);
            v.y = (float)(((double)pv.y - mu) * rs * g4.y + b4.y);
            v.z = (float)(((double)pv.z - mu) * rs * g4.z + b4.z);
            v.w = (float)(((double)pv.w - mu) * rs * g4.w + b4.w);
          }
          *(f4*)&sm.hA[b][k] = v;
        } else {
          f4 pv = ldA4(&gcur[b * NH_ + k]);
          double mu = sm.stats2[b][0], rs = sm.stats2[b][1];
          f4 v;
          v.x = (float)(((double)pv.x - mu) * rs * g4.x + b4.x);
          v.y = (float)(((double)pv.y - mu) * rs * g4.y + b4.y);
          v.z = (float)(((double)pv.z - mu) * rs * g4.z + b4.z);
          v.w = (float)(((double)pv.w - mu) * rs * g4.w + b4.w);
          *(f4*)&sm.hB[b][k] = v;
        }
      }
      __syncthreads();
      {
        // spill-free dot: (jj 8, bg 2, kc 16), 8 b per thread, stride-16 K interleave.
        int jj = tid >> 5, bg = (tid >> 4) & 1, kc = tid & 15, j = jj0 + jj;
        const f4* Wr_w = (const f4*)(p.eg_wih + (size_t)j * 1024);
        const f4* Wz_w = (const f4*)(p.eg_wih + (size_t)(512 + j) * 1024);
        const f4* Wn_w = (const f4*)(p.eg_wih + (size_t)(1024 + j) * 1024);
        const f4* Wr_h = (const f4*)(p.eg_whh + (size_t)j * 512);
        const f4* Wz_h = (const f4*)(p.eg_whh + (size_t)(512 + j) * 512);
        const f4* Wn_h = (const f4*)(p.eg_whh + (size_t)(1024 + j) * 512);
        const f4* HA = (const f4*)&sm.hA[0][0];
        const f4* HB = (const f4*)&sm.hB[0][0];
        double ar[8] = {}, az[8] = {}, apn[8] = {}, aph[8] = {};
#pragma unroll
        for (int i = 0; i < 24; ++i) {
          int q = kc + 16 * i;
          f4 wr, wz, wn; const f4* Ab; int hq;
          if (i < 16) { wr = Wr_w[q]; wz = Wz_w[q]; wn = Wn_w[q]; }
          else        { int qq = q - 256; wr = Wr_h[qq]; wz = Wz_h[qq]; wn = Wn_h[qq]; }
          if (i < 8)       { Ab = HA; hq = q; }
          else if (i < 16) { Ab = HB; hq = q - 128; }
          else             { Ab = HA; hq = q - 256; }
#pragma unroll
          for (int bb = 0; bb < 8; ++bb) {
            f4 a = Ab[(bg * 8 + bb) * 130 + hq];
            ar[bb] += dot4d(a, wr); az[bb] += dot4d(a, wz);
            if (i < 16) apn[bb] += dot4d(a, wn); else aph[bb] += dot4d(a, wn);
          }
        }
#pragma unroll
        for (int bb = 0; bb < 8; ++bb) {
          double r = ar[bb], z = az[bb], pn = apn[bb], ph = aph[bb];
#pragma unroll
          for (int m = 1; m <= 8; m <<= 1) {
            r += __shfl_xor(r, m); z += __shfl_xor(z, m);
            pn += __shfl_xor(pn, m); ph += __shfl_xor(ph, m);
          }
          if (kc == 0) {
            int b = bg * 8 + bb;
            sm.red[jj][b][0] = r; sm.red[jj][b][1] = z; sm.red[jj][b][2] = pn; sm.red[jj][b][3] = ph;
          }
        }
      }
      __syncthreads();
      if (tid < 128) {
        int b = tid >> 3, jj = tid & 7, j = jj0 + jj;
        const double* rd = sm.red[jj][b];
        double r = sigm_d(rd[0] + (double)p.eg_bih[j] + (double)p.eg_bhh[j]);
        double z = sigm_d(rd[1] + (double)p.eg_bih[512 + j] + (double)p.eg_bhh[512 + j]);
        double inn = rd[2] + (double)p.eg_bih[1024 + j];
        double hn  = rd[3] + (double)p.eg_bhh[1024 + j];
        double n = tanh(inn + r * hn);
        double hp = (double)sm.hA[b][j];
        double hv = (1.0 - z) * n + z * hp;
        float hf = (float)hv;
        stA1(&p.e_out[(size_t)(te & 1) * NB_ * NH_ + b * NH_ + j], hf);
        double s1 = (double)hf, s2 = (double)hf * (double)hf;
#pragma unroll
        for (int m = 1; m <= 4; m <<= 1) { s1 += __shfl_xor(s1, m); s2 += __shfl_xor(s2, m); }
        if (jj == 0) {
          atomicAdd(&p.sums[sidx(2, te & 3, b, 0)], s1);
          atomicAdd(&p.sums[sidx(2, te & 3, b, 1)], s2);
        }
      }
    }
  }
  // ---------------- pg(t) (0..63) | gg(t) (64..127) ----------------
  else {
    if (t < NS_) {
      const bool is_pg = bid < 64;
      const int jj0 = (is_pg ? bid : bid - 64) * 8;
      const float* wih = is_pg ? p.pg_wih : p.gg_wih;
      const float* whh = is_pg ? p.pg_whh : p.gg_whh;
      const float* bih = is_pg ? p.pg_bih : p.gg_bih;
      const float* bhh = is_pg ? p.pg_bhh : p.gg_bhh;
      const float* gix = is_pg ? p.gixp : p.gixg;
      const int g = is_pg ? 0 : 1;

      if (!is_pg) {
        if (tid < NB_) {
          sm.spk[tid]  = p.spk[tid * NS_ + t];
          sm.spkp[tid] = (t > 0) ? p.spk[tid * NS_ + t - 1] : -1;
          if (t > 0) {
            double s = ldAd(&p.sums[sidx(1, (t - 1) & 3, tid, 0)]);
            double q = ldAd(&p.sums[sidx(1, (t - 1) & 3, tid, 1)]);
            double mu = s * (1.0 / NH_), var = q * (1.0 / NH_) - mu * mu;
            sm.stats[tid][0] = mu; sm.stats[tid][1] = 1.0 / sqrt(var + 1e-5);
          }
        }
      } else if (t > 0 && tid < NB_) {
        double s = ldAd(&p.sums[sidx(0, (t - 1) & 3, tid, 0)]);
        double q = ldAd(&p.sums[sidx(0, (t - 1) & 3, tid, 1)]);
        double mu = s * (1.0 / NH_), var = q * (1.0 / NH_) - mu * mu;
        sm.stats[tid][0] = mu; sm.stats[tid][1] = 1.0 / sqrt(var + 1e-5);
      }
      __syncthreads();

      const float* prev = p.party_pre + (size_t)((t - 1) & 1) * NB_ * NH_;
      const float* gprev = p.g_new + (size_t)((t - 1) & 1) * NB_ * NH_;
      for (int idx = tid; idx < NB_ * NH_ / 4; idx += 256) {
        int b = idx >> 7, k = (idx & 127) * 4;
        f4 v;
        if (is_pg) {
          if (t == 0) v = *(const f4*)&p.init_party[k];
          else {
            f4 pv = ldA4(&prev[b * NH_ + k]);
            f4 g4 = *(const f4*)&p.ln_g[k], b4 = *(const f4*)&p.ln_b[k];
            double mu = sm.stats[b][0], rs = sm.stats[b][1];
            v.x = (float)(((double)pv.x - mu) * rs * g4.x + b4.x);
            v.y = (float)(((double)pv.y - mu) * rs * g4.y + b4.y);
            v.z = (float)(((double)pv.z - mu) * rs * g4.z + b4.z);
            v.w = (float)(((double)pv.w - mu) * rs * g4.w + b4.w);
          }
        } else {
          if (sm.spk[b] == sm.spkp[b]) {
            f4 pv = ldA4(&gprev[b * NH_ + k]);
            f4 g4 = *(const f4*)&p.ln_g[k], b4 = *(const f4*)&p.ln_b[k];
            double mu = sm.stats[b][0], rs = sm.stats[b][1];
            v.x = (float)(((double)pv.x - mu) * rs * g4.x + b4.x);
            v.y = (float)(((double)pv.y - mu) * rs * g4.y + b4.y);
            v.z = (float)(((double)pv.z - mu) * rs * g4.z + b4.z);
            v.w = (float)(((double)pv.w - mu) * rs * g4.w + b4.w);
          } else {
            v = ldA4(&p.glob[(size_t)(b * NSP_ + sm.spk[b]) * NH_ + k]);
          }
        }
        *(f4*)&sm.hA[b][k] = v;
      }
      __syncthreads();

      {
        // spill-free dot: (jj 8, bg 2, kc 16), 8 b per thread, stride-16 K interleave.
        int jj = tid >> 5, bg = (tid >> 4) & 1, kc = tid & 15, j = jj0 + jj;
        const f4* Wr_w = (const f4*)(wih + (size_t)j * 1536 + 1024);
        const f4* Wz_w = (const f4*)(wih + (size_t)(512 + j) * 1536 + 1024);
        const f4* Wn_w = (const f4*)(wih + (size_t)(1024 + j) * 1536 + 1024);
        const f4* Wr_h = (const f4*)(whh + (size_t)j * 512);
        const f4* Wz_h = (const f4*)(whh + (size_t)(512 + j) * 512);
        const f4* Wn_h = (const f4*)(whh + (size_t)(1024 + j) * 512);
        const f4* H = (const f4*)&sm.hA[0][0];
        double ar[8] = {}, az[8] = {}, apn[8] = {}, aph[8] = {};
#pragma unroll
        for (int i = 0; i < 16; ++i) {
          int q = kc + 16 * i;
          f4 wr, wz, wn; int hq;
          if (i < 8) { wr = Wr_w[q]; wz = Wz_w[q]; wn = Wn_w[q]; hq = q; }
          else       { int qq = q - 128; wr = Wr_h[qq]; wz = Wz_h[qq]; wn = Wn_h[qq]; hq = qq; }
#pragma unroll
          for (int bb = 0; bb < 8; ++bb) {
            f4 a = H[(bg * 8 + bb) * 130 + hq];
            ar[bb] += dot4d(a, wr); az[bb] += dot4d(a, wz);
            if (i < 8) apn[bb] += dot4d(a, wn); else aph[bb] += dot4d(a, wn);
          }
        }
#pragma unroll
        for (int bb = 0; bb < 8; ++bb) {
          double r = ar[bb], z = az[bb], pn = apn[bb], ph = aph[bb];
#pragma unroll
          for (int m = 1; m <= 8; m <<= 1) {
            r += __shfl_xor(r, m); z += __shfl_xor(z, m);
            pn += __shfl_xor(pn, m); ph += __shfl_xor(ph, m);
          }
          if (kc == 0) {
            int b = bg * 8 + bb;
            sm.red[jj][b][0] = r; sm.red[jj][b][1] = z; sm.red[jj][b][2] = pn; sm.red[jj][b][3] = ph;
          }
        }
      }
      __syncthreads();

      if (tid < 128) {
        int b = tid >> 3, jj = tid & 7, j = jj0 + jj;
        const double* rd = sm.red[jj][b];
        const float* gx = gix + (size_t)(b * NS_ + t) * 1536;
        double r = sigm_d(rd[0] + (double)gx[j] + (double)bih[j] + (double)bhh[j]);
        double z = sigm_d(rd[1] + (double)gx[512 + j] + (double)bih[512 + j] + (double)bhh[512 + j]);
        double inn = rd[2] + (double)gx[1024 + j] + (double)bih[1024 + j];
        double hn  = rd[3] + (double)bhh[1024 + j];
        double n = tanh(inn + r * hn);
        double hp = (double)sm.hA[b][j];
        double hv = (1.0 - z) * n + z * hp;
        float hf = (float)hv;
        float* dst = is_pg ? (p.party_pre + (size_t)(t & 1) * NB_ * NH_)
                           : (p.g_new + (size_t)(t & 1) * NB_ * NH_);
        stA1(&dst[b * NH_ + j], hf);
        double s1 = (double)hf, s2 = (double)hf * (double)hf;
#pragma unroll
        for (int m = 1; m <= 4; m <<= 1) { s1 += __shfl_xor(s1, m); s2 += __shfl_xor(s2, m); }
        if (jj == 0) {
          atomicAdd(&p.sums[sidx(g, t & 3, b, 0)], s1);
          atomicAdd(&p.sums[sidx(g, t & 3, b, 1)], s2);
        }
      }
    }
  }
}

__global__ __launch_bounds__(256, 1) void seq_kernel(Params p) {
  __shared__ Smem sm;
  const int bid = blockIdx.x, tid = threadIdx.x;
  for (int t = 0; t <= NS_ + 2; ++t) {
    step_body(p, sm, t, bid, tid);
    gbar_flags(p.flags, p.gen, bid, gridDim.x, (u32)(t + 1));
  }
}

// x-projection precompute: gix[gru][bs][row] = sum_k utt[bs][k] * wih[row][k], k<1024 (fp64 accum)
__global__ __launch_bounds__(512) void gix_kernel(const float* utt, const float* pgw,
                                                  const float* ggw, float* gix) {
  __shared__ float xs[16][1028];
  const int tid = threadIdx.x;
  long bs0 = (long)blockIdx.x * 16;
  for (int i = tid; i < 16 * 256; i += 512) {
    int bb = i >> 8, kf = i & 255;
    *(f4*)&xs[bb][kf * 4] = *(const f4*)(utt + (bs0 + bb) * 1024 + kf * 4);
  }
  __syncthreads();
  int R = blockIdx.y * 32 + (tid >> 4);
  int bi = tid & 15;
  const float* wrow = (R < 1536) ? pgw + (size_t)R * 1536 : ggw + (size_t)(R - 1536) * 1536;
  const f4* w4 = (const f4*)wrow;
  const f4* x4 = (const f4*)&xs[bi][0];
  double acc = 0;
  for (int k = 0; k < 256; ++k) acc += dot4d(x4[k], w4[k]);
  size_t base = (R < 1536) ? 0 : (size_t)8192 * 1536;
  int r = (R < 1536) ? R : R - 1536;
  gix[base + (size_t)(bs0 + bi) * 1536 + r] = (float)acc;
}

__global__ void init_kernel(float* glob, const float* init_global, double* sums,
                            u32* flags, u32* gen) {
  long stride = (long)gridDim.x * blockDim.x;
  long t0 = (long)blockIdx.x * blockDim.x + threadIdx.x;
  for (long i = t0; i < (long)NB_ * NSP_ * NH_; i += stride) {
    int sp = ((int)i >> 9) & (NSP_ - 1);
    int k = (int)i & (NH_ - 1);
    glob[i] = init_global[sp * NH_ + k];
  }
  for (long i = t0; i < 384; i += stride) sums[i] = 0.0;
  for (long i = t0; i < NBLK * 16; i += stride) flags[i] = 0u;
  if (t0 == 0) *gen = 0u;
}

extern "C" void kernel_launch(void* const* d_in, const int* in_sizes, int n_in,
                              void* d_out, int out_size, void* d_ws, size_t ws_size,
                              hipStream_t stream) {
  (void)in_sizes; (void)n_in; (void)out_size;
  Params p;
  p.utt    = (const float*)d_in[0];
  p.spk    = (const int*)d_in[1];
  p.init_party   = (const float*)d_in[2];
  const float* ig = (const float*)d_in[3];
  p.init_emotion = (const float*)d_in[4];
  p.pg_wih = (const float*)d_in[5];
  p.pg_whh = (const float*)d_in[6];
  p.pg_bih = (const float*)d_in[7];
  p.pg_bhh = (const float*)d_in[8];
  p.gg_wih = (const float*)d_in[9];
  p.gg_whh = (const float*)d_in[10];
  p.gg_bih = (const float*)d_in[11];
  p.gg_bhh = (const float*)d_in[12];
  p.eg_wih = (const float*)d_in[13];
  p.eg_whh = (const float*)d_in[14];
  p.eg_bih = (const float*)d_in[15];
  p.eg_bhh = (const float*)d_in[16];
  // 17..19 attention weights: softmax over length-1 axis == 1 -> provably unused
  p.ln_g   = (const float*)d_in[20];
  p.ln_b   = (const float*)d_in[21];
  p.out_w1 = (const float*)d_in[22];
  p.out_b1 = (const float*)d_in[23];
  p.out_ln_g = (const float*)d_in[24];
  p.out_ln_b = (const float*)d_in[25];
  p.out_w2 = (const float*)d_in[26];
  p.out_b2 = (const float*)d_in[27];

  char* w = (char*)d_ws;
  auto alloc = [&](size_t bytes) { char* r = w; w += (bytes + 255) & ~(size_t)255; return r; };
  float* gix       = (float*)alloc((size_t)2 * 8192 * 1536 * 4);   // ~100.7 MB
  float* party_pre = (float*)alloc((size_t)2 * NB_ * NH_ * 4);
  float* g_new     = (float*)alloc((size_t)2 * NB_ * NH_ * 4);
  float* e_out     = (float*)alloc((size_t)2 * NB_ * NH_ * 4);
  float* glob      = (float*)alloc((size_t)NB_ * NSP_ * NH_ * 4);
  float* h1buf     = (float*)alloc((size_t)2 * NB_ * NH2_ * 4);
  double* sums     = (double*)alloc(384 * 8);
  u32*   flags     = (u32*)alloc((size_t)NBLK * 16 * 4);
  u32*   gen       = (u32*)alloc(256);
  if ((size_t)(w - (char*)d_ws) > ws_size) return;  // ws too small -> loud failure (zeros)

  gix_kernel<<<dim3(512, 96), dim3(512), 0, stream>>>(p.utt, p.pg_wih, p.gg_wih, gix);
  init_kernel<<<dim3(64), dim3(256), 0, stream>>>(glob, ig, sums, flags, gen);

  p.gixp = gix; p.gixg = gix + (size_t)8192 * 1536;
  p.party_pre = party_pre; p.g_new = g_new; p.e_out = e_out; p.glob = glob;
  p.h1buf = h1buf; p.sums = sums; p.flags = flags; p.gen = gen; p.out = (float*)d_out;

  seq_kernel<<<dim3(NBLK), dim3(256), 0, stream>>>(p);
}

// Round 14
// 41459.476 us; speedup vs baseline: 2.0450x; 2.0450x over previous
//
#include <hip/hip_runtime.h>

typedef __attribute__((ext_vector_type(4))) float f4;
using u32 = unsigned int;
using u64 = unsigned long long;

constexpr int NB_ = 16;    // batch
constexpr int NS_ = 512;   // seq len
constexpr int ND_ = 1024;  // input dim
constexpr int NH_ = 512;   // hidden
constexpr int NSP_ = 8;    // speakers
constexpr int NH2_ = 256;  // head hidden
constexpr int HP = 520;    // padded fp32 LDS row (130 f4)
constexpr int NBLK = 256;  // persistent grid: 1 block per CU

struct Params {
  const float *utt;
  const float *pg_wih, *pg_whh, *gg_wih, *gg_whh, *eg_wih, *eg_whh, *out_w1;
  const float *gixp, *gixg;   // precomputed x-projections [B*S][1536] fp32
  const float *init_party, *init_emotion;
  const float *pg_bih, *pg_bhh, *gg_bih, *gg_bhh, *eg_bih, *eg_bhh;
  const float *ln_g, *ln_b, *out_b1, *out_ln_g, *out_ln_b, *out_w2, *out_b2;
  const int *spk;
  float *party_pre;  // [2][B][H] raw pg output (pre-LN), parity t&1
  float *g_new;      // [2][B][H] raw gg output, parity t&1
  float *e_out;      // [2][B][H] raw eg output, parity te&1
  float *glob;       // [B][SP][H] post-LN (or raw init) global states
  float *h1buf;      // [2][B][H2] relu(e@W1+b1), parity th&1
  double *sums;      // [3 groups][4 slots][16 b][2] = 384 doubles
  u32 *flags;        // [NBLK * 16] arrival flags, one 64B line per block
  u32 *gen;          // release word
  float *out;        // [B][S]
};

__device__ __forceinline__ double sigm_d(double x) { return 1.0 / (1.0 + exp(-x)); }
__device__ __forceinline__ int sidx(int g, int slot, int b, int c) {
  return ((g * 4 + slot) * 16 + b) * 2 + c;
}
__device__ __forceinline__ double dot4d(f4 a, f4 w) {
  return ((double)a.x * w.x + (double)a.y * w.y) + ((double)a.z * w.z + (double)a.w * w.w);
}

// ---- cross-block plumbing: relaxed agent-scope atomics (bypass per-XCD L2; no flushes) ----
__device__ __forceinline__ void stA1(float* p, float v) {
  __hip_atomic_store(p, v, __ATOMIC_RELAXED, __HIP_MEMORY_SCOPE_AGENT);
}
__device__ __forceinline__ float ldA1(const float* p) {
  return __hip_atomic_load((float*)p, __ATOMIC_RELAXED, __HIP_MEMORY_SCOPE_AGENT);
}
__device__ __forceinline__ void stA2(float* p, float a, float b) {
  union { float f[2]; u64 u; } x; x.f[0] = a; x.f[1] = b;
  __hip_atomic_store((u64*)p, x.u, __ATOMIC_RELAXED, __HIP_MEMORY_SCOPE_AGENT);
}
__device__ __forceinline__ float2 ldA2(const float* p) {
  u64 u = __hip_atomic_load((u64*)p, __ATOMIC_RELAXED, __HIP_MEMORY_SCOPE_AGENT);
  union { u64 u; float f[2]; } x; x.u = u;
  return make_float2(x.f[0], x.f[1]);
}
__device__ __forceinline__ f4 ldA4(const float* p) {
  float2 lo = ldA2(p), hi = ldA2(p + 2);
  f4 v; v.x = lo.x; v.y = lo.y; v.z = hi.x; v.w = hi.y;
  return v;
}
__device__ __forceinline__ double ldAd(const double* p) {
  return __hip_atomic_load((double*)p, __ATOMIC_RELAXED, __HIP_MEMORY_SCOPE_AGENT);
}
__device__ __forceinline__ void stAd(double* p, double v) {
  __hip_atomic_store(p, v, __ATOMIC_RELAXED, __HIP_MEMORY_SCOPE_AGENT);
}

// Contention-free flag barrier (R12-validated): per-block arrival flag on its own 64B
// line (plain sc1 store, no RMW); block 0 scans all flags in parallel (one per thread),
// then publishes gen. Never emits cache-maintenance; L2/LDS stay warm.
__device__ __forceinline__ void gbar_flags(u32* flags, u32* gen, int bid, int nb, u32 epoch) {
  __syncthreads();
  const int tid = threadIdx.x;
  if (bid == 0) {
    if (tid == 0)
      __hip_atomic_store(&flags[0], epoch, __ATOMIC_RELAXED, __HIP_MEMORY_SCOPE_AGENT);
    if (tid > 0 && tid < nb) {
      while (__hip_atomic_load(&flags[(size_t)tid * 16], __ATOMIC_RELAXED, __HIP_MEMORY_SCOPE_AGENT) < epoch)
        __builtin_amdgcn_s_sleep(1);
    }
    __syncthreads();
    if (tid == 0) {
      asm volatile("s_waitcnt vmcnt(0)" ::: "memory");
      __hip_atomic_store(gen, epoch, __ATOMIC_RELAXED, __HIP_MEMORY_SCOPE_AGENT);
    }
  } else {
    if (tid == 0) {
      asm volatile("s_waitcnt vmcnt(0) lgkmcnt(0)" ::: "memory");
      __hip_atomic_store(&flags[(size_t)bid * 16], epoch, __ATOMIC_RELAXED, __HIP_MEMORY_SCOPE_AGENT);
      while (__hip_atomic_load(gen, __ATOMIC_RELAXED, __HIP_MEMORY_SCOPE_AGENT) < epoch)
        __builtin_amdgcn_s_sleep(2);
    }
  }
  __syncthreads();
}

// LDS layouts (R11-validated). Weights live in LDS for the entire run.
struct PggS {                       // pg / gg blocks (8 j-columns)
  float wctx[24][512];              // wih ctx cols [1024,1536): row = gate*8+jj   (48 KB)
  float whh[24][512];               // whh: row = gate*8+jj                        (48 KB)
  float hA[NB_][HP];                // staged hidden operand                        (32.5 KB)
  double red[8][NB_][4];            // dot partials / head redH reuse               (4 KB)
  double stats[NB_][2];
  int spk[NB_], spkp[NB_];
};
struct EgS {                        // eg blocks (4 j-columns)
  float wih[12][1024];              // row = gate*4+jj                              (48 KB)
  float whh[12][512];               //                                              (24 KB)
  float hA[NB_][HP];                // LN'd emo                                     (32.5 KB)
  float hB[NB_][HP];                // LN'd spk_state                               (32.5 KB)
  double red[4][NB_][4];
  double stats[NB_][2], stats2[NB_][2];
};
union SmemU { PggS pgg; EgS eg; };  // ~143 KB < 160 KB/CU

__device__ void step_body(const Params& p, SmemU& smu, int t, int bid, int tid) {
  if (bid < 64) {
    // ================= pg(t) | head(t-2) on bid<16 =================
    PggS& sm = smu.pgg;
    const int jj0 = bid * 8;
    if (t < NS_) {
      if (t > 0 && tid < NB_) {
        double s = ldAd(&p.sums[sidx(0, (t - 1) & 3, tid, 0)]);
        double q = ldAd(&p.sums[sidx(0, (t - 1) & 3, tid, 1)]);
        double mu = s * (1.0 / NH_), var = q * (1.0 / NH_) - mu * mu;
        sm.stats[tid][0] = mu; sm.stats[tid][1] = 1.0 / sqrt(var + 1e-5);
      }
      __syncthreads();
      const float* prev = p.party_pre + (size_t)((t - 1) & 1) * NB_ * NH_;
      for (int idx = tid; idx < NB_ * NH_ / 4; idx += 256) {
        int b = idx >> 7, k = (idx & 127) * 4;
        f4 v;
        if (t == 0) v = *(const f4*)&p.init_party[k];
        else {
          f4 pv = ldA4(&prev[b * NH_ + k]);
          f4 g4 = *(const f4*)&p.ln_g[k], b4 = *(const f4*)&p.ln_b[k];
          double mu = sm.stats[b][0], rs = sm.stats[b][1];
          v.x = (float)(((double)pv.x - mu) * rs * g4.x + b4.x);
          v.y = (float)(((double)pv.y - mu) * rs * g4.y + b4.y);
          v.z = (float)(((double)pv.z - mu) * rs * g4.z + b4.z);
          v.w = (float)(((double)pv.w - mu) * rs * g4.w + b4.w);
        }
        *(f4*)&sm.hA[b][k] = v;
      }
      __syncthreads();
      {
        int jj = tid >> 5, kc = tid & 31;
        const f4* Wc = (const f4*)&sm.wctx[0][0];
        const f4* Wh = (const f4*)&sm.whh[0][0];
        const f4* H = (const f4*)&sm.hA[0][0];
        double ar[NB_] = {}, az[NB_] = {}, apn[NB_] = {}, aph[NB_] = {};
#pragma unroll
        for (int i = 0; i < 8; ++i) {
          int q = kc + 32 * i;
          f4 wr, wz, wn; int hq;
          if (i < 4) { wr = Wc[jj * 128 + q]; wz = Wc[(8 + jj) * 128 + q]; wn = Wc[(16 + jj) * 128 + q]; hq = q; }
          else { int qq = q - 128; wr = Wh[jj * 128 + qq]; wz = Wh[(8 + jj) * 128 + qq]; wn = Wh[(16 + jj) * 128 + qq]; hq = qq; }
#pragma unroll
          for (int b = 0; b < NB_; ++b) {
            f4 a = H[b * 130 + hq];
            ar[b] += dot4d(a, wr); az[b] += dot4d(a, wz);
            if (i < 4) apn[b] += dot4d(a, wn); else aph[b] += dot4d(a, wn);
          }
        }
#pragma unroll
        for (int b = 0; b < NB_; ++b) {
          double r = ar[b], z = az[b], pn = apn[b], ph = aph[b];
#pragma unroll
          for (int m = 1; m <= 16; m <<= 1) {
            r += __shfl_xor(r, m); z += __shfl_xor(z, m);
            pn += __shfl_xor(pn, m); ph += __shfl_xor(ph, m);
          }
          if (kc == 0) { sm.red[jj][b][0] = r; sm.red[jj][b][1] = z; sm.red[jj][b][2] = pn; sm.red[jj][b][3] = ph; }
        }
      }
      __syncthreads();
      if (tid < 128) {
        int b = tid >> 3, jj = tid & 7, j = jj0 + jj;
        const double* rd = sm.red[jj][b];
        const float* gx = p.gixp + (size_t)(b * NS_ + t) * 1536;
        double r = sigm_d(rd[0] + (double)gx[j] + (double)p.pg_bih[j] + (double)p.pg_bhh[j]);
        double z = sigm_d(rd[1] + (double)gx[512 + j] + (double)p.pg_bih[512 + j] + (double)p.pg_bhh[512 + j]);
        double inn = rd[2] + (double)gx[1024 + j] + (double)p.pg_bih[1024 + j];
        double hn  = rd[3] + (double)p.pg_bhh[1024 + j];
        double n = tanh(inn + r * hn);
        double hp = (double)sm.hA[b][j];
        double hv = (1.0 - z) * n + z * hp;
        float hf = (float)hv;
        stA1(&p.party_pre[(size_t)(t & 1) * NB_ * NH_ + b * NH_ + j], hf);
        double s1 = (double)hf, s2 = (double)hf * (double)hf;
#pragma unroll
        for (int m = 1; m <= 4; m <<= 1) { s1 += __shfl_xor(s1, m); s2 += __shfl_xor(s2, m); }
        if (jj == 0) {
          atomicAdd(&p.sums[sidx(0, t & 3, b, 0)], s1);
          atomicAdd(&p.sums[sidx(0, t & 3, b, 1)], s2);
        }
      }
    }
    // ---- head(t-2): restage hA with e_out, dot vs out_w1 (L2-cached), write h1buf ----
    if (bid < 16 && t >= 2 && t <= NS_ + 1) {
      __syncthreads();
      int th = t - 2, ct = bid;
      const float* er = p.e_out + (size_t)(th & 1) * NB_ * NH_;
      for (int idx = tid; idx < NB_ * NH_ / 4; idx += 256) {
        int b = idx >> 7, k = (idx & 127) * 4;
        *(f4*)&sm.hA[b][k] = ldA4(&er[b * NH_ + k]);
      }
      __syncthreads();
      double* redH = (double*)&sm.red[0][0][0];
      {
        int ci = tid >> 4, kc = tid & 15, c = ct * 16 + ci;
        const f4* W = (const f4*)(p.out_w1 + (size_t)c * 512);
        const f4* H = (const f4*)&sm.hA[0][0];
        double acc[NB_] = {};
#pragma unroll
        for (int i = 0; i < 8; ++i) {
          int q = kc + 16 * i;
          f4 w = W[q];
#pragma unroll
          for (int b = 0; b < NB_; ++b) acc[b] += dot4d(H[b * 130 + q], w);
        }
#pragma unroll
        for (int b = 0; b < NB_; ++b) {
          double v = acc[b];
#pragma unroll
          for (int m = 1; m <= 8; m <<= 1) v += __shfl_xor(v, m);
          if (kc == 0) redH[ci * 16 + b] = v;
        }
      }
      __syncthreads();
      {
        int b = tid >> 4, ci = tid & 15, c = ct * 16 + ci;
        double h1 = redH[ci * 16 + b] + (double)p.out_b1[c];
        stA1(&p.h1buf[(size_t)(th & 1) * NB_ * NH2_ + b * NH2_ + c], (float)fmax(h1, 0.0));
      }
    }
  } else if (bid < 128) {
    // ================= gg(t) | wb(t-1)+zero | score(t-3) on bid 127 =================
    PggS& sm = smu.pgg;
    const int i = bid - 64, wbB = i >> 2, kq = i & 3;
    const int jj0 = i * 8;
    if (t < NS_) {
      if (tid < NB_) {
        sm.spk[tid]  = p.spk[tid * NS_ + t];
        sm.spkp[tid] = (t > 0) ? p.spk[tid * NS_ + t - 1] : -1;
        if (t > 0) {
          double s = ldAd(&p.sums[sidx(1, (t - 1) & 3, tid, 0)]);
          double q = ldAd(&p.sums[sidx(1, (t - 1) & 3, tid, 1)]);
          double mu = s * (1.0 / NH_), var = q * (1.0 / NH_) - mu * mu;
          sm.stats[tid][0] = mu; sm.stats[tid][1] = 1.0 / sqrt(var + 1e-5);
        }
      }
      __syncthreads();
      const float* gprev = p.g_new + (size_t)((t - 1) & 1) * NB_ * NH_;
      for (int idx = tid; idx < NB_ * NH_ / 4; idx += 256) {
        int b = idx >> 7, k = (idx & 127) * 4;
        f4 v;
        if (sm.spk[b] == sm.spkp[b]) {
          f4 pv = ldA4(&gprev[b * NH_ + k]);
          f4 g4 = *(const f4*)&p.ln_g[k], b4 = *(const f4*)&p.ln_b[k];
          double mu = sm.stats[b][0], rs = sm.stats[b][1];
          v.x = (float)(((double)pv.x - mu) * rs * g4.x + b4.x);
          v.y = (float)(((double)pv.y - mu) * rs * g4.y + b4.y);
          v.z = (float)(((double)pv.z - mu) * rs * g4.z + b4.z);
          v.w = (float)(((double)pv.w - mu) * rs * g4.w + b4.w);
        } else {
          v = ldA4(&p.glob[(size_t)(b * NSP_ + sm.spk[b]) * NH_ + k]);
        }
        *(f4*)&sm.hA[b][k] = v;
      }
      __syncthreads();
      {
        int jj = tid >> 5, kc = tid & 31;
        const f4* Wc = (const f4*)&sm.wctx[0][0];
        const f4* Wh = (const f4*)&sm.whh[0][0];
        const f4* H = (const f4*)&sm.hA[0][0];
        double ar[NB_] = {}, az[NB_] = {}, apn[NB_] = {}, aph[NB_] = {};
#pragma unroll
        for (int ii = 0; ii < 8; ++ii) {
          int q = kc + 32 * ii;
          f4 wr, wz, wn; int hq;
          if (ii < 4) { wr = Wc[jj * 128 + q]; wz = Wc[(8 + jj) * 128 + q]; wn = Wc[(16 + jj) * 128 + q]; hq = q; }
          else { int qq = q - 128; wr = Wh[jj * 128 + qq]; wz = Wh[(8 + jj) * 128 + qq]; wn = Wh[(16 + jj) * 128 + qq]; hq = qq; }
#pragma unroll
          for (int b = 0; b < NB_; ++b) {
            f4 a = H[b * 130 + hq];
            ar[b] += dot4d(a, wr); az[b] += dot4d(a, wz);
            if (ii < 4) apn[b] += dot4d(a, wn); else aph[b] += dot4d(a, wn);
          }
        }
#pragma unroll
        for (int b = 0; b < NB_; ++b) {
          double r = ar[b], z = az[b], pn = apn[b], ph = aph[b];
#pragma unroll
          for (int m = 1; m <= 16; m <<= 1) {
            r += __shfl_xor(r, m); z += __shfl_xor(z, m);
            pn += __shfl_xor(pn, m); ph += __shfl_xor(ph, m);
          }
          if (kc == 0) { sm.red[jj][b][0] = r; sm.red[jj][b][1] = z; sm.red[jj][b][2] = pn; sm.red[jj][b][3] = ph; }
        }
      }
      __syncthreads();
      if (tid < 128) {
        int b = tid >> 3, jj = tid & 7, j = jj0 + jj;
        const double* rd = sm.red[jj][b];
        const float* gx = p.gixg + (size_t)(b * NS_ + t) * 1536;
        double r = sigm_d(rd[0] + (double)gx[j] + (double)p.gg_bih[j] + (double)p.gg_bhh[j]);
        double z = sigm_d(rd[1] + (double)gx[512 + j] + (double)p.gg_bih[512 + j] + (double)p.gg_bhh[512 + j]);
        double inn = rd[2] + (double)gx[1024 + j] + (double)p.gg_bih[1024 + j];
        double hn  = rd[3] + (double)p.gg_bhh[1024 + j];
        double n = tanh(inn + r * hn);
        double hp = (double)sm.hA[b][j];
        double hv = (1.0 - z) * n + z * hp;
        float hf = (float)hv;
        stA1(&p.g_new[(size_t)(t & 1) * NB_ * NH_ + b * NH_ + j], hf);
        double s1 = (double)hf, s2 = (double)hf * (double)hf;
#pragma unroll
        for (int m = 1; m <= 4; m <<= 1) { s1 += __shfl_xor(s1, m); s2 += __shfl_xor(s2, m); }
        if (jj == 0) {
          atomicAdd(&p.sums[sidx(1, t & 3, b, 0)], s1);
          atomicAdd(&p.sums[sidx(1, t & 3, b, 1)], s2);
        }
      }
    }
    // ---- sums slot rotation zeroing (one block per b) ----
    if ((i & 3) == 0 && tid == 0) {
      int b = wbB;
      stAd(&p.sums[sidx(0, (t + 2) & 3, b, 0)], 0.0); stAd(&p.sums[sidx(0, (t + 2) & 3, b, 1)], 0.0);
      stAd(&p.sums[sidx(1, (t + 2) & 3, b, 0)], 0.0); stAd(&p.sums[sidx(1, (t + 2) & 3, b, 1)], 0.0);
      stAd(&p.sums[sidx(2, (t + 1) & 3, b, 0)], 0.0); stAd(&p.sums[sidx(2, (t + 1) & 3, b, 1)], 0.0);
    }
    // ---- wb(t-1): this block owns (wbB, k-quarter kq) ----
    if (t >= 1 && t <= NS_ && tid < 64) {
      int tw = t - 1;
      int spv = p.spk[wbB * NS_ + tw];
      double s = ldAd(&p.sums[sidx(1, tw & 3, wbB, 0)]), q = ldAd(&p.sums[sidx(1, tw & 3, wbB, 1)]);
      double mu = s * (1.0 / NH_), var = q * (1.0 / NH_) - mu * mu, rs = 1.0 / sqrt(var + 1e-5);
      const float* gsrc = p.g_new + (size_t)(tw & 1) * NB_ * NH_;
      float* gd = p.glob + (size_t)(wbB * NSP_ + spv) * NH_;
      int k2 = kq * 64 + tid;
      float2 gv = ldA2(&gsrc[wbB * NH_ + k2 * 2]);
      double o0 = ((double)gv.x - mu) * rs * p.ln_g[k2 * 2] + p.ln_b[k2 * 2];
      double o1 = ((double)gv.y - mu) * rs * p.ln_g[k2 * 2 + 1] + p.ln_b[k2 * 2 + 1];
      stA2(&gd[k2 * 2], (float)o0, (float)o1);
    }
    // ---- score(t-3) on bid 127 ----
    if (bid == 127 && t >= 3 && t <= NS_ + 2) {
      int ts = t - 3;
      int b = tid >> 4, cg = tid & 15;
      const float* h1p = p.h1buf + (size_t)(ts & 1) * NB_ * NH2_;
      double s1 = 0, s2 = 0;
      float hv[16];
#pragma unroll
      for (int ii = 0; ii < 16; ++ii) {
        float v = ldA1(&h1p[b * NH2_ + cg * 16 + ii]);
        hv[ii] = v; s1 += (double)v; s2 += (double)v * (double)v;
      }
#pragma unroll
      for (int m = 1; m <= 8; m <<= 1) { s1 += __shfl_xor(s1, m); s2 += __shfl_xor(s2, m); }
      double mu = s1 * (1.0 / NH2_), var = s2 * (1.0 / NH2_) - mu * mu, rstd = 1.0 / sqrt(var + 1e-5);
      double d = 0;
#pragma unroll
      for (int ii = 0; ii < 16; ++ii) {
        int c = cg * 16 + ii;
        d += (((double)hv[ii] - mu) * rstd * p.out_ln_g[c] + (double)p.out_ln_b[c]) * (double)p.out_w2[c];
      }
#pragma unroll
      for (int m = 1; m <= 8; m <<= 1) d += __shfl_xor(d, m);
      if (cg == 0) p.out[b * NS_ + ts] = (float)sigm_d(d + (double)p.out_b2[0]);
    }
  } else {
    // ================= eg(t-1) (bid 128..255, 4 j-columns) =================
    EgS& sm = smu.eg;
    if (t >= 1 && t <= NS_) {
      const int te = t - 1;
      const int jj0 = (bid - 128) * 4;
      if (te > 0 && tid < NB_) {
        double s = ldAd(&p.sums[sidx(2, (te - 1) & 3, tid, 0)]);
        double q = ldAd(&p.sums[sidx(2, (te - 1) & 3, tid, 1)]);
        double mu = s * (1.0 / NH_), var = q * (1.0 / NH_) - mu * mu;
        sm.stats[tid][0] = mu; sm.stats[tid][1] = 1.0 / sqrt(var + 1e-5);
      }
      if (tid >= NB_ && tid < 2 * NB_) {
        int b = tid - NB_;
        double s = ldAd(&p.sums[sidx(1, te & 3, b, 0)]);
        double q = ldAd(&p.sums[sidx(1, te & 3, b, 1)]);
        double mu = s * (1.0 / NH_), var = q * (1.0 / NH_) - mu * mu;
        sm.stats2[b][0] = mu; sm.stats2[b][1] = 1.0 / sqrt(var + 1e-5);
      }
      __syncthreads();
      const float* eprev = p.e_out + (size_t)((te - 1) & 1) * NB_ * NH_;
      const float* gcur  = p.g_new + (size_t)(te & 1) * NB_ * NH_;
      for (int idx = tid; idx < NB_ * NH_ / 2; idx += 256) {
        int half = idx >= NB_ * NH_ / 4;
        int r4 = idx & (NB_ * NH_ / 4 - 1);
        int b = r4 >> 7, k = (r4 & 127) * 4;
        f4 g4 = *(const f4*)&p.ln_g[k], b4 = *(const f4*)&p.ln_b[k];
        if (!half) {
          f4 v;
          if (te == 0) v = *(const f4*)&p.init_emotion[k];
          else {
            f4 pv = ldA4(&eprev[b * NH_ + k]);
            double mu = sm.stats[b][0], rs = sm.stats[b][1];
            v.x = (float)(((double)pv.x - mu) * rs * g4.x + b4.x);
            v.y = (float)(((double)pv.y - mu) * rs * g4.y + b4.y);
            v.z = (float)(((double)pv.z - mu) * rs * g4.z + b4.z);
            v.w = (float)(((double)pv.w - mu) * rs * g4.w + b4.w);
          }
          *(f4*)&sm.hA[b][k] = v;
        } else {
          f4 pv = ldA4(&gcur[b * NH_ + k]);
          double mu = sm.stats2[b][0], rs = sm.stats2[b][1];
          f4 v;
          v.x = (float)(((double)pv.x - mu) * rs * g4.x + b4.x);
          v.y = (float)(((double)pv.y - mu) * rs * g4.y + b4.y);
          v.z = (float)(((double)pv.z - mu) * rs * g4.z + b4.z);
          v.w = (float)(((double)pv.w - mu) * rs * g4.w + b4.w);
          *(f4*)&sm.hB[b][k] = v;
        }
      }
      __syncthreads();
      if (tid < 128) {  // 12-i loop, jj range 4 (R11-validated ordering)
        int jj = tid >> 5, kc = tid & 31;
        const f4* Wi = (const f4*)&sm.wih[0][0];   // row stride 256 f4
        const f4* Wh = (const f4*)&sm.whh[0][0];   // row stride 128 f4
        const f4* HA = (const f4*)&sm.hA[0][0];
        const f4* HB = (const f4*)&sm.hB[0][0];
        double ar[NB_] = {}, az[NB_] = {}, apn[NB_] = {}, aph[NB_] = {};
#pragma unroll
        for (int ii = 0; ii < 12; ++ii) {
          int q = kc + 32 * ii;
          f4 wr, wz, wn; const f4* Ab; int hq;
          if (ii < 8) { wr = Wi[jj * 256 + q]; wz = Wi[(4 + jj) * 256 + q]; wn = Wi[(8 + jj) * 256 + q]; }
          else { int qq = q - 256; wr = Wh[jj * 128 + qq]; wz = Wh[(4 + jj) * 128 + qq]; wn = Wh[(8 + jj) * 128 + qq]; }
          if (ii < 4)      { Ab = HA; hq = q; }
          else if (ii < 8) { Ab = HB; hq = q - 128; }
          else             { Ab = HA; hq = q - 256; }
#pragma unroll
          for (int b = 0; b < NB_; ++b) {
            f4 a = Ab[b * 130 + hq];
            ar[b] += dot4d(a, wr); az[b] += dot4d(a, wz);
            if (ii < 8) apn[b] += dot4d(a, wn); else aph[b] += dot4d(a, wn);
          }
        }
#pragma unroll
        for (int b = 0; b < NB_; ++b) {
          double r = ar[b], z = az[b], pn = apn[b], ph = aph[b];
#pragma unroll
          for (int m = 1; m <= 16; m <<= 1) {
            r += __shfl_xor(r, m); z += __shfl_xor(z, m);
            pn += __shfl_xor(pn, m); ph += __shfl_xor(ph, m);
          }
          if (kc == 0) { sm.red[jj][b][0] = r; sm.red[jj][b][1] = z; sm.red[jj][b][2] = pn; sm.red[jj][b][3] = ph; }
        }
      }
      __syncthreads();
      if (tid < 64) {
        int b = tid >> 2, jj = tid & 3, j = jj0 + jj;
        const double* rd = sm.red[jj][b];
        double r = sigm_d(rd[0] + (double)p.eg_bih[j] + (double)p.eg_bhh[j]);
        double z = sigm_d(rd[1] + (double)p.eg_bih[512 + j] + (double)p.eg_bhh[512 + j]);
        double inn = rd[2] + (double)p.eg_bih[1024 + j];
        double hn  = rd[3] + (double)p.eg_bhh[1024 + j];
        double n = tanh(inn + r * hn);
        double hp = (double)sm.hA[b][j];
        double hv = (1.0 - z) * n + z * hp;
        float hf = (float)hv;
        stA1(&p.e_out[(size_t)(te & 1) * NB_ * NH_ + b * NH_ + j], hf);
        double s1 = (double)hf, s2 = (double)hf * (double)hf;
#pragma unroll
        for (int m = 1; m <= 2; m <<= 1) { s1 += __shfl_xor(s1, m); s2 += __shfl_xor(s2, m); }
        if (jj == 0) {
          atomicAdd(&p.sums[sidx(2, te & 3, b, 0)], s1);
          atomicAdd(&p.sums[sidx(2, te & 3, b, 1)], s2);
        }
      }
    }
  }
}

__global__ __launch_bounds__(256, 1) void seq_kernel(Params p) {
  __shared__ SmemU smu;
  const int bid = blockIdx.x, tid = threadIdx.x;
  // ---- one-time weight preload into LDS ----
  if (bid < 128) {
    PggS& sm = smu.pgg;
    const float* wih = bid < 64 ? p.pg_wih : p.gg_wih;
    const float* whh = bid < 64 ? p.pg_whh : p.gg_whh;
    int jj0 = (bid & 63) * 8;
    for (int i = tid; i < 24 * 128; i += 256) {
      int r = i >> 7, q = i & 127;
      int g = r >> 3, jj = r & 7;
      *(f4*)&sm.wctx[r][q * 4] = *(const f4*)&wih[(size_t)(g * 512 + jj0 + jj) * 1536 + 1024 + q * 4];
      *(f4*)&sm.whh[r][q * 4]  = *(const f4*)&whh[(size_t)(g * 512 + jj0 + jj) * 512 + q * 4];
    }
  } else {
    EgS& sm = smu.eg;
    int jj0 = (bid - 128) * 4;
    for (int i = tid; i < 12 * 256; i += 256) {
      int r = i >> 8, q = i & 255;
      int g = r >> 2, jj = r & 3;
      *(f4*)&sm.wih[r][q * 4] = *(const f4*)&p.eg_wih[(size_t)(g * 512 + jj0 + jj) * 1024 + q * 4];
    }
    for (int i = tid; i < 12 * 128; i += 256) {
      int r = i >> 7, q = i & 127;
      int g = r >> 2, jj = r & 3;
      *(f4*)&sm.whh[r][q * 4] = *(const f4*)&p.eg_whh[(size_t)(g * 512 + jj0 + jj) * 512 + q * 4];
    }
  }
  __syncthreads();
  for (int t = 0; t <= NS_ + 2; ++t) {
    step_body(p, smu, t, bid, tid);
    gbar_flags(p.flags, p.gen, bid, gridDim.x, (u32)(t + 1));
  }
}

// x-projection precompute: gix[gru][bs][row] = sum_k utt[bs][k] * wih[row][k], k<1024 (fp64 accum)
__global__ __launch_bounds__(512) void gix_kernel(const float* utt, const float* pgw,
                                                  const float* ggw, float* gix) {
  __shared__ float xs[16][1028];
  const int tid = threadIdx.x;
  long bs0 = (long)blockIdx.x * 16;
  for (int i = tid; i < 16 * 256; i += 512) {
    int bb = i >> 8, kf = i & 255;
    *(f4*)&xs[bb][kf * 4] = *(const f4*)(utt + (bs0 + bb) * 1024 + kf * 4);
  }
  __syncthreads();
  int R = blockIdx.y * 32 + (tid >> 4);
  int bi = tid & 15;
  const float* wrow = (R < 1536) ? pgw + (size_t)R * 1536 : ggw + (size_t)(R - 1536) * 1536;
  const f4* w4 = (const f4*)wrow;
  const f4* x4 = (const f4*)&xs[bi][0];
  double acc = 0;
  for (int k = 0; k < 256; ++k) acc += dot4d(x4[k], w4[k]);
  size_t base = (R < 1536) ? 0 : (size_t)8192 * 1536;
  int r = (R < 1536) ? R : R - 1536;
  gix[base + (size_t)(bs0 + bi) * 1536 + r] = (float)acc;
}

__global__ void init_kernel(float* glob, const float* init_global, double* sums,
                            u32* flags, u32* gen) {
  long stride = (long)gridDim.x * blockDim.x;
  long t0 = (long)blockIdx.x * blockDim.x + threadIdx.x;
  for (long i = t0; i < (long)NB_ * NSP_ * NH_; i += stride) {
    int sp = ((int)i >> 9) & (NSP_ - 1);
    int k = (int)i & (NH_ - 1);
    glob[i] = init_global[sp * NH_ + k];
  }
  for (long i = t0; i < 384; i += stride) sums[i] = 0.0;
  for (long i = t0; i < NBLK * 16; i += stride) flags[i] = 0u;
  if (t0 == 0) *gen = 0u;
}

extern "C" void kernel_launch(void* const* d_in, const int* in_sizes, int n_in,
                              void* d_out, int out_size, void* d_ws, size_t ws_size,
                              hipStream_t stream) {
  (void)in_sizes; (void)n_in; (void)out_size;
  Params p;
  p.utt    = (const float*)d_in[0];
  p.spk    = (const int*)d_in[1];
  p.init_party   = (const float*)d_in[2];
  const float* ig = (const float*)d_in[3];
  p.init_emotion = (const float*)d_in[4];
  p.pg_wih = (const float*)d_in[5];
  p.pg_whh = (const float*)d_in[6];
  p.pg_bih = (const float*)d_in[7];
  p.pg_bhh = (const float*)d_in[8];
  p.gg_wih = (const float*)d_in[9];
  p.gg_whh = (const float*)d_in[10];
  p.gg_bih = (const float*)d_in[11];
  p.gg_bhh = (const float*)d_in[12];
  p.eg_wih = (const float*)d_in[13];
  p.eg_whh = (const float*)d_in[14];
  p.eg_bih = (const float*)d_in[15];
  p.eg_bhh = (const float*)d_in[16];
  // 17..19 attention weights: softmax over length-1 axis == 1 -> provably unused
  p.ln_g   = (const float*)d_in[20];
  p.ln_b   = (const float*)d_in[21];
  p.out_w1 = (const float*)d_in[22];
  p.out_b1 = (const float*)d_in[23];
  p.out_ln_g = (const float*)d_in[24];
  p.out_ln_b = (const float*)d_in[25];
  p.out_w2 = (const float*)d_in[26];
  p.out_b2 = (const float*)d_in[27];

  char* w = (char*)d_ws;
  auto alloc = [&](size_t bytes) { char* r = w; w += (bytes + 255) & ~(size_t)255; return r; };
  float* gix       = (float*)alloc((size_t)2 * 8192 * 1536 * 4);   // ~100.7 MB
  float* party_pre = (float*)alloc((size_t)2 * NB_ * NH_ * 4);
  float* g_new     = (float*)alloc((size_t)2 * NB_ * NH_ * 4);
  float* e_out     = (float*)alloc((size_t)2 * NB_ * NH_ * 4);
  float* glob      = (float*)alloc((size_t)NB_ * NSP_ * NH_ * 4);
  float* h1buf     = (float*)alloc((size_t)2 * NB_ * NH2_ * 4);
  double* sums     = (double*)alloc(384 * 8);
  u32*   flags     = (u32*)alloc((size_t)NBLK * 16 * 4);
  u32*   gen       = (u32*)alloc(256);
  if ((size_t)(w - (char*)d_ws) > ws_size) return;  // ws too small -> loud failure (zeros)

  gix_kernel<<<dim3(512, 96), dim3(512), 0, stream>>>(p.utt, p.pg_wih, p.gg_wih, gix);
  init_kernel<<<dim3(64), dim3(256), 0, stream>>>(glob, ig, sums, flags, gen);

  p.gixp = gix; p.gixg = gix + (size_t)8192 * 1536;
  p.party_pre = party_pre; p.g_new = g_new; p.e_out = e_out; p.glob = glob;
  p.h1buf = h1buf; p.sums = sums; p.flags = flags; p.gen = gen; p.out = (float*)d_out;

  seq_kernel<<<dim3(NBLK), dim3(256), 0, stream>>>(p);
}

// Round 15
// 36270.779 us; speedup vs baseline: 2.3376x; 1.1431x over previous
//
#include <hip/hip_runtime.h>

typedef __attribute__((ext_vector_type(4))) float f4;
using u32 = unsigned int;
using u64 = unsigned long long;

constexpr int NB_ = 16;    // batch
constexpr int NS_ = 512;   // seq len
constexpr int ND_ = 1024;  // input dim
constexpr int NH_ = 512;   // hidden
constexpr int NSP_ = 8;    // speakers
constexpr int NH2_ = 256;  // head hidden
constexpr int HP = 520;    // padded fp32 LDS row (130 f4)
constexpr int NBLK = 225;  // persistent grid

struct Params {
  const float *utt;
  const float *pg_wih, *pg_whh, *gg_wih, *gg_whh, *eg_wih, *eg_whh, *out_w1;
  const float *gixp, *gixg;   // precomputed x-projections [B*S][1536] fp32
  const float *init_party, *init_emotion;
  const float *pg_bih, *pg_bhh, *gg_bih, *gg_bhh, *eg_bih, *eg_bhh;
  const float *ln_g, *ln_b, *out_b1, *out_ln_g, *out_ln_b, *out_w2, *out_b2;
  const int *spk;
  float *party_pre;  // [2][B][H] raw pg output (pre-LN), parity t&1
  float *g_new;      // [2][B][H] raw gg output, parity t&1
  float *e_out;      // [2][B][H] raw eg output, parity te&1
  float *glob;       // [B][SP][H] post-LN (or raw init) global states
  float *h1buf;      // [2][B][H2] relu(e@W1+b1), parity th&1
  u32 *flags;        // [NBLK * 16] arrival flags, one 64B line per block
  u32 *gen;          // release word
  float *out;        // [B][S]
};

__device__ __forceinline__ double sigm_d(double x) { return 1.0 / (1.0 + exp(-x)); }
__device__ __forceinline__ double dot4d(f4 a, f4 w) {
  return ((double)a.x * w.x + (double)a.y * w.y) + ((double)a.z * w.z + (double)a.w * w.w);
}

// ---- cross-block plumbing: relaxed agent-scope atomics (bypass per-XCD L2; no flushes) ----
__device__ __forceinline__ void stA1(float* p, float v) {
  __hip_atomic_store(p, v, __ATOMIC_RELAXED, __HIP_MEMORY_SCOPE_AGENT);
}
__device__ __forceinline__ float ldA1(const float* p) {
  return __hip_atomic_load((float*)p, __ATOMIC_RELAXED, __HIP_MEMORY_SCOPE_AGENT);
}
__device__ __forceinline__ void stA2(float* p, float a, float b) {
  union { float f[2]; u64 u; } x; x.f[0] = a; x.f[1] = b;
  __hip_atomic_store((u64*)p, x.u, __ATOMIC_RELAXED, __HIP_MEMORY_SCOPE_AGENT);
}
__device__ __forceinline__ float2 ldA2(const float* p) {
  u64 u = __hip_atomic_load((u64*)p, __ATOMIC_RELAXED, __HIP_MEMORY_SCOPE_AGENT);
  union { u64 u; float f[2]; } x; x.u = u;
  return make_float2(x.f[0], x.f[1]);
}
__device__ __forceinline__ f4 ldA4(const float* p) {
  float2 lo = ldA2(p), hi = ldA2(p + 2);
  f4 v; v.x = lo.x; v.y = lo.y; v.z = hi.x; v.w = hi.y;
  return v;
}

// Contention-free flag barrier (R12-validated): per-block arrival flag on its own 64B
// line (plain sc1 store, no RMW); block 0 scans all flags in parallel, publishes gen.
__device__ __forceinline__ void gbar_flags(u32* flags, u32* gen, int bid, int nb, u32 epoch) {
  __syncthreads();
  const int tid = threadIdx.x;
  if (bid == 0) {
    if (tid == 0)
      __hip_atomic_store(&flags[0], epoch, __ATOMIC_RELAXED, __HIP_MEMORY_SCOPE_AGENT);
    if (tid > 0 && tid < nb) {
      while (__hip_atomic_load(&flags[(size_t)tid * 16], __ATOMIC_RELAXED, __HIP_MEMORY_SCOPE_AGENT) < epoch)
        __builtin_amdgcn_s_sleep(1);
    }
    __syncthreads();
    if (tid == 0) {
      asm volatile("s_waitcnt vmcnt(0)" ::: "memory");
      __hip_atomic_store(gen, epoch, __ATOMIC_RELAXED, __HIP_MEMORY_SCOPE_AGENT);
    }
  } else {
    if (tid == 0) {
      asm volatile("s_waitcnt vmcnt(0) lgkmcnt(0)" ::: "memory");
      __hip_atomic_store(&flags[(size_t)bid * 16], epoch, __ATOMIC_RELAXED, __HIP_MEMORY_SCOPE_AGENT);
      while (__hip_atomic_load(gen, __ATOMIC_RELAXED, __HIP_MEMORY_SCOPE_AGENT) < epoch)
        __builtin_amdgcn_s_sleep(2);
    }
  }
  __syncthreads();
}

struct __align__(16) Smem {
  float hA[NB_][HP];
  float hB[NB_][HP];
  double red[8][NB_][4];
  double redH[16][NB_];
  double stats[NB_][2];
  double stats2[NB_][2];
  int spk[NB_], spkp[NB_];
};

// block-local per-b stats over sm row: 256 threads = (b 16, kc 16), 32 elems each, shfl-16
__device__ __forceinline__ void row_stats(const float (*h)[HP], double (*st)[2], int tid) {
  int b = tid >> 4, kc = tid & 15;
  double s1 = 0, s2 = 0;
#pragma unroll
  for (int i = 0; i < 32; ++i) {
    double x = (double)h[b][kc + i * 16];
    s1 += x; s2 += x * x;
  }
#pragma unroll
  for (int m = 1; m <= 8; m <<= 1) { s1 += __shfl_xor(s1, m); s2 += __shfl_xor(s2, m); }
  if (kc == 0) {
    double mu = s1 * (1.0 / NH_), var = s2 * (1.0 / NH_) - mu * mu;
    st[b][0] = mu; st[b][1] = 1.0 / sqrt(var + 1e-5);
  }
}

// One pipelined step t: pg(t)|gg(t)|eg(t-1)|wb(t-1)|head(t-2)|score(t-3).
__device__ void step_body(const Params& p, Smem& sm, int t, int bid, int tid) {
  // ---------------- wb(t-1): one block per b (192..207) ----------------
  if (bid >= 192 && bid < 208) {
    if (t >= 1 && t <= NS_) {
      int b = bid - 192, tw = t - 1;
      int spv = p.spk[b * NS_ + tw];
      const float* gsrc = p.g_new + (size_t)(tw & 1) * NB_ * NH_;
      float2 gv = ldA2(&gsrc[b * NH_ + tid * 2]);
      double s1 = (double)gv.x + (double)gv.y;
      double s2 = (double)gv.x * (double)gv.x + (double)gv.y * (double)gv.y;
#pragma unroll
      for (int m = 1; m <= 32; m <<= 1) { s1 += __shfl_xor(s1, m); s2 += __shfl_xor(s2, m); }
      int wid = tid >> 6;
      if ((tid & 63) == 0) { sm.redH[0][wid] = s1; sm.redH[1][wid] = s2; }
      __syncthreads();
      if (tid == 0) {
        double ts1 = sm.redH[0][0] + sm.redH[0][1] + sm.redH[0][2] + sm.redH[0][3];
        double ts2 = sm.redH[1][0] + sm.redH[1][1] + sm.redH[1][2] + sm.redH[1][3];
        double mu = ts1 * (1.0 / NH_), var = ts2 * (1.0 / NH_) - mu * mu;
        sm.stats[0][0] = mu; sm.stats[0][1] = 1.0 / sqrt(var + 1e-5);
      }
      __syncthreads();
      double mu = sm.stats[0][0], rs = sm.stats[0][1];
      float* gd = p.glob + (size_t)(b * NSP_ + spv) * NH_;
      int k2 = tid * 2;
      double o0 = ((double)gv.x - mu) * rs * p.ln_g[k2] + p.ln_b[k2];
      double o1 = ((double)gv.y - mu) * rs * p.ln_g[k2 + 1] + p.ln_b[k2 + 1];
      stA2(&gd[k2], (float)o0, (float)o1);
    }
  }
  // ---------------- head(t-2) (208..223) ----------------
  else if (bid >= 208 && bid < 224) {
    if (t >= 2 && t <= NS_ + 1) {
      int th = t - 2, ct = bid - 208;
      const float* er = p.e_out + (size_t)(th & 1) * NB_ * NH_;
      for (int idx = tid; idx < NB_ * NH_ / 4; idx += 256) {
        int b = idx >> 7, k = (idx & 127) * 4;
        *(f4*)&sm.hA[b][k] = ldA4(&er[b * NH_ + k]);
      }
      __syncthreads();
      {
        int ci = tid >> 4, kc = tid & 15, c = ct * 16 + ci;
        const f4* W = (const f4*)(p.out_w1 + (size_t)c * 512);
        const f4* H = (const f4*)&sm.hA[0][0];
        double acc[NB_] = {};
#pragma unroll
        for (int i = 0; i < 8; ++i) {
          int q = kc + 16 * i;
          f4 w = W[q];
#pragma unroll
          for (int b = 0; b < NB_; ++b) acc[b] += dot4d(H[b * 130 + q], w);
        }
#pragma unroll
        for (int b = 0; b < NB_; ++b) {
          double v = acc[b];
#pragma unroll
          for (int m = 1; m <= 8; m <<= 1) v += __shfl_xor(v, m);
          if (kc == 0) sm.redH[ci][b] = v;
        }
      }
      __syncthreads();
      {
        int b = tid >> 4, ci = tid & 15, c = ct * 16 + ci;
        double h1 = sm.redH[ci][b] + (double)p.out_b1[c];
        stA1(&p.h1buf[(size_t)(th & 1) * NB_ * NH2_ + b * NH2_ + c], (float)fmax(h1, 0.0));
      }
    }
  }
  // ---------------- score(t-3) (224) ----------------
  else if (bid == 224) {
    if (t >= 3 && t <= NS_ + 2) {
      int ts = t - 3;
      int b = tid >> 4, cg = tid & 15;
      const float* h1p = p.h1buf + (size_t)(ts & 1) * NB_ * NH2_;
      double s1 = 0, s2 = 0;
      float hv[16];
#pragma unroll
      for (int i = 0; i < 16; ++i) {
        float v = ldA1(&h1p[b * NH2_ + cg * 16 + i]);
        hv[i] = v; s1 += (double)v; s2 += (double)v * (double)v;
      }
#pragma unroll
      for (int m = 1; m <= 8; m <<= 1) { s1 += __shfl_xor(s1, m); s2 += __shfl_xor(s2, m); }
      double mu = s1 * (1.0 / NH2_), var = s2 * (1.0 / NH2_) - mu * mu, rstd = 1.0 / sqrt(var + 1e-5);
      double d = 0;
#pragma unroll
      for (int i = 0; i < 16; ++i) {
        int c = cg * 16 + i;
        d += (((double)hv[i] - mu) * rstd * p.out_ln_g[c] + (double)p.out_ln_b[c]) * (double)p.out_w2[c];
      }
#pragma unroll
      for (int m = 1; m <= 8; m <<= 1) d += __shfl_xor(d, m);
      if (cg == 0) p.out[b * NS_ + ts] = (float)sigm_d(d + (double)p.out_b2[0]);
    }
  }
  // ---------------- eg(t-1) (128..191) ----------------
  else if (bid >= 128) {
    if (t >= 1 && t <= NS_) {
      const int te = t - 1;
      const int jj0 = (bid - 128) * 8;
      const float* eprev = p.e_out + (size_t)((te - 1) & 1) * NB_ * NH_;
      const float* gcur  = p.g_new + (size_t)(te & 1) * NB_ * NH_;
      // pass 1: load raw
      for (int idx = tid; idx < NB_ * NH_ / 2; idx += 256) {
        int half = idx >= NB_ * NH_ / 4;
        int r4 = idx & (NB_ * NH_ / 4 - 1);
        int b = r4 >> 7, k = (r4 & 127) * 4;
        if (!half) {
          f4 v = (te == 0) ? *(const f4*)&p.init_emotion[k] : ldA4(&eprev[b * NH_ + k]);
          *(f4*)&sm.hA[b][k] = v;
        } else {
          *(f4*)&sm.hB[b][k] = ldA4(&gcur[b * NH_ + k]);
        }
      }
      __syncthreads();
      // pass 2: block-local stats (hA if te>0; hB always)
      {
        int b = tid >> 4, kc = tid & 15;
        double a1 = 0, a2 = 0, b1 = 0, b2 = 0;
#pragma unroll
        for (int i = 0; i < 32; ++i) {
          double xa = (double)sm.hA[b][kc + i * 16];
          double xb = (double)sm.hB[b][kc + i * 16];
          a1 += xa; a2 += xa * xa; b1 += xb; b2 += xb * xb;
        }
#pragma unroll
        for (int m = 1; m <= 8; m <<= 1) {
          a1 += __shfl_xor(a1, m); a2 += __shfl_xor(a2, m);
          b1 += __shfl_xor(b1, m); b2 += __shfl_xor(b2, m);
        }
        if (kc == 0) {
          double mu = a1 * (1.0 / NH_), var = a2 * (1.0 / NH_) - mu * mu;
          sm.stats[b][0] = mu; sm.stats[b][1] = 1.0 / sqrt(var + 1e-5);
          mu = b1 * (1.0 / NH_); var = b2 * (1.0 / NH_) - mu * mu;
          sm.stats2[b][0] = mu; sm.stats2[b][1] = 1.0 / sqrt(var + 1e-5);
        }
      }
      __syncthreads();
      // pass 3: LN in place
      for (int idx = tid; idx < NB_ * NH_ / 2; idx += 256) {
        int half = idx >= NB_ * NH_ / 4;
        int r4 = idx & (NB_ * NH_ / 4 - 1);
        int b = r4 >> 7, k = (r4 & 127) * 4;
        f4 g4 = *(const f4*)&p.ln_g[k], b4 = *(const f4*)&p.ln_b[k];
        if (!half) {
          if (te > 0) {
            f4 pv = *(f4*)&sm.hA[b][k];
            double mu = sm.stats[b][0], rs = sm.stats[b][1];
            f4 v;
            v.x = (float)(((double)pv.x - mu) * rs * g4.x + b4.x);
            v.y = (float)(((double)pv.y - mu) * rs * g4.y + b4.y);
            v.z = (float)(((double)pv.z - mu) * rs * g4.z + b4.z);
            v.w = (float)(((double)pv.w - mu) * rs * g4.w + b4.w);
            *(f4*)&sm.hA[b][k] = v;
          }
        } else {
          f4 pv = *(f4*)&sm.hB[b][k];
          double mu = sm.stats2[b][0], rs = sm.stats2[b][1];
          f4 v;
          v.x = (float)(((double)pv.x - mu) * rs * g4.x + b4.x);
          v.y = (float)(((double)pv.y - mu) * rs * g4.y + b4.y);
          v.z = (float)(((double)pv.z - mu) * rs * g4.z + b4.z);
          v.w = (float)(((double)pv.w - mu) * rs * g4.w + b4.w);
          *(f4*)&sm.hB[b][k] = v;
        }
      }
      __syncthreads();
      {
        int jj = tid >> 5, kc = tid & 31, j = jj0 + jj;
        const f4* Wr_w = (const f4*)(p.eg_wih + (size_t)j * 1024);
        const f4* Wz_w = (const f4*)(p.eg_wih + (size_t)(512 + j) * 1024);
        const f4* Wn_w = (const f4*)(p.eg_wih + (size_t)(1024 + j) * 1024);
        const f4* Wr_h = (const f4*)(p.eg_whh + (size_t)j * 512);
        const f4* Wz_h = (const f4*)(p.eg_whh + (size_t)(512 + j) * 512);
        const f4* Wn_h = (const f4*)(p.eg_whh + (size_t)(1024 + j) * 512);
        const f4* HA = (const f4*)&sm.hA[0][0];
        const f4* HB = (const f4*)&sm.hB[0][0];
        double ar[NB_] = {}, az[NB_] = {}, apn[NB_] = {}, aph[NB_] = {};
#pragma unroll
        for (int i = 0; i < 12; ++i) {
          int q = kc + 32 * i;
          f4 wr, wz, wn; const f4* Ab; int hq;
          if (i < 8) { wr = Wr_w[q]; wz = Wz_w[q]; wn = Wn_w[q]; }
          else       { wr = Wr_h[q - 256]; wz = Wz_h[q - 256]; wn = Wn_h[q - 256]; }
          if (i < 4)      { Ab = HA; hq = q; }
          else if (i < 8) { Ab = HB; hq = q - 128; }
          else            { Ab = HA; hq = q - 256; }
#pragma unroll
          for (int b = 0; b < NB_; ++b) {
            f4 a = Ab[b * 130 + hq];
            ar[b] += dot4d(a, wr); az[b] += dot4d(a, wz);
            if (i < 8) apn[b] += dot4d(a, wn); else aph[b] += dot4d(a, wn);
          }
        }
#pragma unroll
        for (int b = 0; b < NB_; ++b) {
          double r = ar[b], z = az[b], pn = apn[b], ph = aph[b];
#pragma unroll
          for (int m = 1; m <= 16; m <<= 1) {
            r += __shfl_xor(r, m); z += __shfl_xor(z, m);
            pn += __shfl_xor(pn, m); ph += __shfl_xor(ph, m);
          }
          if (kc == 0) { sm.red[jj][b][0] = r; sm.red[jj][b][1] = z; sm.red[jj][b][2] = pn; sm.red[jj][b][3] = ph; }
        }
      }
      __syncthreads();
      if (tid < 128) {
        int b = tid >> 3, jj = tid & 7, j = jj0 + jj;
        const double* rd = sm.red[jj][b];
        double r = sigm_d(rd[0] + (double)p.eg_bih[j] + (double)p.eg_bhh[j]);
        double z = sigm_d(rd[1] + (double)p.eg_bih[512 + j] + (double)p.eg_bhh[512 + j]);
        double inn = rd[2] + (double)p.eg_bih[1024 + j];
        double hn  = rd[3] + (double)p.eg_bhh[1024 + j];
        double n = tanh(inn + r * hn);
        double hp = (double)sm.hA[b][j];
        double hv = (1.0 - z) * n + z * hp;
        stA1(&p.e_out[(size_t)(te & 1) * NB_ * NH_ + b * NH_ + j], (float)hv);
      }
    }
  }
  // ---------------- pg(t) (0..63) | gg(t) (64..127) ----------------
  else {
    if (t < NS_) {
      const bool is_pg = bid < 64;
      const int jj0 = (is_pg ? bid : bid - 64) * 8;
      const float* wih = is_pg ? p.pg_wih : p.gg_wih;
      const float* whh = is_pg ? p.pg_whh : p.gg_whh;
      const float* bih = is_pg ? p.pg_bih : p.gg_bih;
      const float* bhh = is_pg ? p.pg_bhh : p.gg_bhh;
      const float* gix = is_pg ? p.gixp : p.gixg;

      if (!is_pg && tid < NB_) {
        sm.spk[tid]  = p.spk[tid * NS_ + t];
        sm.spkp[tid] = (t > 0) ? p.spk[tid * NS_ + t - 1] : -1;
      }
      __syncthreads();

      // pass 1: load raw state
      const float* prev = p.party_pre + (size_t)((t - 1) & 1) * NB_ * NH_;
      const float* gprev = p.g_new + (size_t)((t - 1) & 1) * NB_ * NH_;
      for (int idx = tid; idx < NB_ * NH_ / 4; idx += 256) {
        int b = idx >> 7, k = (idx & 127) * 4;
        f4 v;
        if (is_pg) {
          v = (t == 0) ? *(const f4*)&p.init_party[k] : ldA4(&prev[b * NH_ + k]);
        } else {
          v = (sm.spk[b] == sm.spkp[b]) ? ldA4(&gprev[b * NH_ + k])
                                        : ldA4(&p.glob[(size_t)(b * NSP_ + sm.spk[b]) * NH_ + k]);
        }
        *(f4*)&sm.hA[b][k] = v;
      }
      __syncthreads();
      // pass 2: block-local stats
      row_stats(sm.hA, sm.stats, tid);
      __syncthreads();
      // pass 3: LN in place (pg: t>0; gg: only spk-match rows)
      {
        bool any = is_pg ? (t > 0) : true;
        if (any) {
          for (int idx = tid; idx < NB_ * NH_ / 4; idx += 256) {
            int b = idx >> 7, k = (idx & 127) * 4;
            bool doln = is_pg ? (t > 0) : (sm.spk[b] == sm.spkp[b]);
            if (doln) {
              f4 pv = *(f4*)&sm.hA[b][k];
              f4 g4 = *(const f4*)&p.ln_g[k], b4 = *(const f4*)&p.ln_b[k];
              double mu = sm.stats[b][0], rs = sm.stats[b][1];
              f4 v;
              v.x = (float)(((double)pv.x - mu) * rs * g4.x + b4.x);
              v.y = (float)(((double)pv.y - mu) * rs * g4.y + b4.y);
              v.z = (float)(((double)pv.z - mu) * rs * g4.z + b4.z);
              v.w = (float)(((double)pv.w - mu) * rs * g4.w + b4.w);
              *(f4*)&sm.hA[b][k] = v;
            }
          }
        }
      }
      __syncthreads();

      {
        int jj = tid >> 5, kc = tid & 31, j = jj0 + jj;
        const f4* Wr_w = (const f4*)(wih + (size_t)j * 1536 + 1024);
        const f4* Wz_w = (const f4*)(wih + (size_t)(512 + j) * 1536 + 1024);
        const f4* Wn_w = (const f4*)(wih + (size_t)(1024 + j) * 1536 + 1024);
        const f4* Wr_h = (const f4*)(whh + (size_t)j * 512);
        const f4* Wz_h = (const f4*)(whh + (size_t)(512 + j) * 512);
        const f4* Wn_h = (const f4*)(whh + (size_t)(1024 + j) * 512);
        const f4* H = (const f4*)&sm.hA[0][0];
        double ar[NB_] = {}, az[NB_] = {}, apn[NB_] = {}, aph[NB_] = {};
#pragma unroll
        for (int i = 0; i < 8; ++i) {
          int q = kc + 32 * i;
          f4 wr, wz, wn; int hq;
          if (i < 4) { wr = Wr_w[q]; wz = Wz_w[q]; wn = Wn_w[q]; hq = q; }
          else       { wr = Wr_h[q - 128]; wz = Wz_h[q - 128]; wn = Wn_h[q - 128]; hq = q - 128; }
#pragma unroll
          for (int b = 0; b < NB_; ++b) {
            f4 a = H[b * 130 + hq];
            ar[b] += dot4d(a, wr); az[b] += dot4d(a, wz);
            if (i < 4) apn[b] += dot4d(a, wn); else aph[b] += dot4d(a, wn);
          }
        }
#pragma unroll
        for (int b = 0; b < NB_; ++b) {
          double r = ar[b], z = az[b], pn = apn[b], ph = aph[b];
#pragma unroll
          for (int m = 1; m <= 16; m <<= 1) {
            r += __shfl_xor(r, m); z += __shfl_xor(z, m);
            pn += __shfl_xor(pn, m); ph += __shfl_xor(ph, m);
          }
          if (kc == 0) { sm.red[jj][b][0] = r; sm.red[jj][b][1] = z; sm.red[jj][b][2] = pn; sm.red[jj][b][3] = ph; }
        }
      }
      __syncthreads();

      if (tid < 128) {
        int b = tid >> 3, jj = tid & 7, j = jj0 + jj;
        const double* rd = sm.red[jj][b];
        const float* gx = gix + (size_t)(b * NS_ + t) * 1536;
        double r = sigm_d(rd[0] + (double)gx[j] + (double)bih[j] + (double)bhh[j]);
        double z = sigm_d(rd[1] + (double)gx[512 + j] + (double)bih[512 + j] + (double)bhh[512 + j]);
        double inn = rd[2] + (double)gx[1024 + j] + (double)bih[1024 + j];
        double hn  = rd[3] + (double)bhh[1024 + j];
        double n = tanh(inn + r * hn);
        double hp = (double)sm.hA[b][j];
        double hv = (1.0 - z) * n + z * hp;
        float* dst = is_pg ? (p.party_pre + (size_t)(t & 1) * NB_ * NH_)
                           : (p.g_new + (size_t)(t & 1) * NB_ * NH_);
        stA1(&dst[b * NH_ + j], (float)hv);
      }
    }
  }
}

__global__ __launch_bounds__(256, 1) void seq_kernel(Params p) {
  __shared__ Smem sm;
  const int bid = blockIdx.x, tid = threadIdx.x;
  for (int t = 0; t <= NS_ + 2; ++t) {
    step_body(p, sm, t, bid, tid);
    gbar_flags(p.flags, p.gen, bid, gridDim.x, (u32)(t + 1));
  }
}

// x-projection precompute: gix[gru][bs][row] = sum_k utt[bs][k] * wih[row][k], k<1024 (fp64 accum)
__global__ __launch_bounds__(512) void gix_kernel(const float* utt, const float* pgw,
                                                  const float* ggw, float* gix) {
  __shared__ float xs[16][1028];
  const int tid = threadIdx.x;
  long bs0 = (long)blockIdx.x * 16;
  for (int i = tid; i < 16 * 256; i += 512) {
    int bb = i >> 8, kf = i & 255;
    *(f4*)&xs[bb][kf * 4] = *(const f4*)(utt + (bs0 + bb) * 1024 + kf * 4);
  }
  __syncthreads();
  int R = blockIdx.y * 32 + (tid >> 4);
  int bi = tid & 15;
  const float* wrow = (R < 1536) ? pgw + (size_t)R * 1536 : ggw + (size_t)(R - 1536) * 1536;
  const f4* w4 = (const f4*)wrow;
  const f4* x4 = (const f4*)&xs[bi][0];
  double acc = 0;
  for (int k = 0; k < 256; ++k) acc += dot4d(x4[k], w4[k]);
  size_t base = (R < 1536) ? 0 : (size_t)8192 * 1536;
  int r = (R < 1536) ? R : R - 1536;
  gix[base + (size_t)(bs0 + bi) * 1536 + r] = (float)acc;
}

__global__ void init_kernel(float* glob, const float* init_global, u32* flags, u32* gen) {
  long stride = (long)gridDim.x * blockDim.x;
  long t0 = (long)blockIdx.x * blockDim.x + threadIdx.x;
  for (long i = t0; i < (long)NB_ * NSP_ * NH_; i += stride) {
    int sp = ((int)i >> 9) & (NSP_ - 1);
    int k = (int)i & (NH_ - 1);
    glob[i] = init_global[sp * NH_ + k];
  }
  for (long i = t0; i < NBLK * 16; i += stride) flags[i] = 0u;
  if (t0 == 0) *gen = 0u;
}

extern "C" void kernel_launch(void* const* d_in, const int* in_sizes, int n_in,
                              void* d_out, int out_size, void* d_ws, size_t ws_size,
                              hipStream_t stream) {
  (void)in_sizes; (void)n_in; (void)out_size;
  Params p;
  p.utt    = (const float*)d_in[0];
  p.spk    = (const int*)d_in[1];
  p.init_party   = (const float*)d_in[2];
  const float* ig = (const float*)d_in[3];
  p.init_emotion = (const float*)d_in[4];
  p.pg_wih = (const float*)d_in[5];
  p.pg_whh = (const float*)d_in[6];
  p.pg_bih = (const float*)d_in[7];
  p.pg_bhh = (const float*)d_in[8];
  p.gg_wih = (const float*)d_in[9];
  p.gg_whh = (const float*)d_in[10];
  p.gg_bih = (const float*)d_in[11];
  p.gg_bhh = (const float*)d_in[12];
  p.eg_wih = (const float*)d_in[13];
  p.eg_whh = (const float*)d_in[14];
  p.eg_bih = (const float*)d_in[15];
  p.eg_bhh = (const float*)d_in[16];
  // 17..19 attention weights: softmax over length-1 axis == 1 -> provably unused
  p.ln_g   = (const float*)d_in[20];
  p.ln_b   = (const float*)d_in[21];
  p.out_w1 = (const float*)d_in[22];
  p.out_b1 = (const float*)d_in[23];
  p.out_ln_g = (const float*)d_in[24];
  p.out_ln_b = (const float*)d_in[25];
  p.out_w2 = (const float*)d_in[26];
  p.out_b2 = (const float*)d_in[27];

  char* w = (char*)d_ws;
  auto alloc = [&](size_t bytes) { char* r = w; w += (bytes + 255) & ~(size_t)255; return r; };
  float* gix       = (float*)alloc((size_t)2 * 8192 * 1536 * 4);   // ~100.7 MB
  float* party_pre = (float*)alloc((size_t)2 * NB_ * NH_ * 4);
  float* g_new     = (float*)alloc((size_t)2 * NB_ * NH_ * 4);
  float* e_out     = (float*)alloc((size_t)2 * NB_ * NH_ * 4);
  float* glob      = (float*)alloc((size_t)NB_ * NSP_ * NH_ * 4);
  float* h1buf     = (float*)alloc((size_t)2 * NB_ * NH2_ * 4);
  u32*   flags     = (u32*)alloc((size_t)NBLK * 16 * 4);
  u32*   gen       = (u32*)alloc(256);
  if ((size_t)(w - (char*)d_ws) > ws_size) return;  // ws too small -> loud failure (zeros)

  gix_kernel<<<dim3(512, 96), dim3(512), 0, stream>>>(p.utt, p.pg_wih, p.gg_wih, gix);
  init_kernel<<<dim3(64), dim3(256), 0, stream>>>(glob, ig, flags, gen);

  p.gixp = gix; p.gixg = gix + (size_t)8192 * 1536;
  p.party_pre = party_pre; p.g_new = g_new; p.e_out = e_out; p.glob = glob;
  p.h1buf = h1buf; p.flags = flags; p.gen = gen; p.out = (float*)d_out;

  seq_kernel<<<dim3(NBLK), dim3(256), 0, stream>>>(p);
}

// Round 16
// 31443.390 us; speedup vs baseline: 2.6965x; 1.1535x over previous
//
#include <hip/hip_runtime.h>

typedef __attribute__((ext_vector_type(4))) float f4;
using u32 = unsigned int;
using u64 = unsigned long long;

constexpr int NB_ = 16;    // batch
constexpr int NS_ = 512;   // seq len
constexpr int ND_ = 1024;  // input dim
constexpr int NH_ = 512;   // hidden
constexpr int NSP_ = 8;    // speakers
constexpr int NH2_ = 256;  // head hidden
constexpr int HP = 520;    // padded fp32 LDS row (130 f4)
constexpr int NBLK = 225;  // persistent grid

struct Params {
  const float *utt;
  const float *pg_wih, *pg_whh, *gg_wih, *gg_whh, *eg_wih, *eg_whh, *out_w1;
  const float *gixp, *gixg;   // precomputed x-projections [B*S][1536] fp32
  const float *init_party, *init_emotion;
  const float *pg_bih, *pg_bhh, *gg_bih, *gg_bhh, *eg_bih, *eg_bhh;
  const float *ln_g, *ln_b, *out_b1, *out_ln_g, *out_ln_b, *out_w2, *out_b2;
  const int *spk;
  float *party_pre;  // [2][B][H] raw pg output (pre-LN), parity t&1
  float *g_new;      // [2][B][H] raw gg output, parity t&1
  float *e_out;      // [2][B][H] raw eg output, parity te&1
  float *glob;       // [B][SP][H] post-LN (or raw init) global states
  float *h1buf;      // [2][B][H2] relu(e@W1+b1), parity th&1
  u32 *flags;        // [NBLK * 16] arrival flags, one 64B line per block
  u32 *gen;          // release word
  float *out;        // [B][S]
};

__device__ __forceinline__ double sigm_d(double x) { return 1.0 / (1.0 + exp(-x)); }
__device__ __forceinline__ double dot4d(f4 a, f4 w) {
  return ((double)a.x * w.x + (double)a.y * w.y) + ((double)a.z * w.z + (double)a.w * w.w);
}

// ---- cross-block plumbing: relaxed agent-scope atomics (bypass per-XCD L2; no flushes) ----
__device__ __forceinline__ void stA1(float* p, float v) {
  __hip_atomic_store(p, v, __ATOMIC_RELAXED, __HIP_MEMORY_SCOPE_AGENT);
}
__device__ __forceinline__ float ldA1(const float* p) {
  return __hip_atomic_load((float*)p, __ATOMIC_RELAXED, __HIP_MEMORY_SCOPE_AGENT);
}
__device__ __forceinline__ void stA2(float* p, float a, float b) {
  union { float f[2]; u64 u; } x; x.f[0] = a; x.f[1] = b;
  __hip_atomic_store((u64*)p, x.u, __ATOMIC_RELAXED, __HIP_MEMORY_SCOPE_AGENT);
}
__device__ __forceinline__ float2 ldA2(const float* p) {
  u64 u = __hip_atomic_load((u64*)p, __ATOMIC_RELAXED, __HIP_MEMORY_SCOPE_AGENT);
  union { u64 u; float f[2]; } x; x.u = u;
  return make_float2(x.f[0], x.f[1]);
}
__device__ __forceinline__ f4 ldA4(const float* p) {
  float2 lo = ldA2(p), hi = ldA2(p + 2);
  f4 v; v.x = lo.x; v.y = lo.y; v.z = hi.x; v.w = hi.y;
  return v;
}

// Contention-free flag barrier (R12-validated): per-block arrival flag on its own 64B
// line (plain sc1 store, no RMW); block 0 scans all flags in parallel, publishes gen.
__device__ __forceinline__ void gbar_flags(u32* flags, u32* gen, int bid, int nb, u32 epoch) {
  __syncthreads();
  const int tid = threadIdx.x;
  if (bid == 0) {
    if (tid == 0)
      __hip_atomic_store(&flags[0], epoch, __ATOMIC_RELAXED, __HIP_MEMORY_SCOPE_AGENT);
    if (tid > 0 && tid < nb) {
      while (__hip_atomic_load(&flags[(size_t)tid * 16], __ATOMIC_RELAXED, __HIP_MEMORY_SCOPE_AGENT) < epoch)
        __builtin_amdgcn_s_sleep(1);
    }
    __syncthreads();
    if (tid == 0) {
      asm volatile("s_waitcnt vmcnt(0)" ::: "memory");
      __hip_atomic_store(gen, epoch, __ATOMIC_RELAXED, __HIP_MEMORY_SCOPE_AGENT);
    }
  } else {
    if (tid == 0) {
      asm volatile("s_waitcnt vmcnt(0) lgkmcnt(0)" ::: "memory");
      __hip_atomic_store(&flags[(size_t)bid * 16], epoch, __ATOMIC_RELAXED, __HIP_MEMORY_SCOPE_AGENT);
      while (__hip_atomic_load(gen, __ATOMIC_RELAXED, __HIP_MEMORY_SCOPE_AGENT) < epoch)
        __builtin_amdgcn_s_sleep(2);
    }
  }
  __syncthreads();
}

struct __align__(16) Smem {
  float hA[NB_][HP];
  float hB[NB_][HP];
  double red[8][NB_][4];
  double redH[16][NB_];
  double stats[NB_][2];
  double stats2[NB_][2];
  int spk[NB_], spkp[NB_];
};

// block-local per-b stats over sm row: 256 threads = (b 16, kc 16), 32 elems each, shfl-16
__device__ __forceinline__ void row_stats(const float (*h)[HP], double (*st)[2], int tid) {
  int b = tid >> 4, kc = tid & 15;
  double s1 = 0, s2 = 0;
#pragma unroll
  for (int i = 0; i < 32; ++i) {
    double x = (double)h[b][kc + i * 16];
    s1 += x; s2 += x * x;
  }
#pragma unroll
  for (int m = 1; m <= 8; m <<= 1) { s1 += __shfl_xor(s1, m); s2 += __shfl_xor(s2, m); }
  if (kc == 0) {
    double mu = s1 * (1.0 / NH_), var = s2 * (1.0 / NH_) - mu * mu;
    st[b][0] = mu; st[b][1] = 1.0 / sqrt(var + 1e-5);
  }
}

// One pipelined step t: pg(t)|gg(t)|eg(t-1)|wb(t-1)|head(t-2)|score(t-3).
__device__ void step_body(const Params& p, Smem& sm, int t, int bid, int tid) {
  // ---------------- wb(t-1): one block per b (192..207) ----------------
  if (bid >= 192 && bid < 208) {
    if (t >= 1 && t <= NS_) {
      int b = bid - 192, tw = t - 1;
      int spv = p.spk[b * NS_ + tw];
      const float* gsrc = p.g_new + (size_t)(tw & 1) * NB_ * NH_;
      float2 gv = ldA2(&gsrc[b * NH_ + tid * 2]);
      double s1 = (double)gv.x + (double)gv.y;
      double s2 = (double)gv.x * (double)gv.x + (double)gv.y * (double)gv.y;
#pragma unroll
      for (int m = 1; m <= 32; m <<= 1) { s1 += __shfl_xor(s1, m); s2 += __shfl_xor(s2, m); }
      int wid = tid >> 6;
      if ((tid & 63) == 0) { sm.redH[0][wid] = s1; sm.redH[1][wid] = s2; }
      __syncthreads();
      if (tid == 0) {
        double ts1 = sm.redH[0][0] + sm.redH[0][1] + sm.redH[0][2] + sm.redH[0][3];
        double ts2 = sm.redH[1][0] + sm.redH[1][1] + sm.redH[1][2] + sm.redH[1][3];
        double mu = ts1 * (1.0 / NH_), var = ts2 * (1.0 / NH_) - mu * mu;
        sm.stats[0][0] = mu; sm.stats[0][1] = 1.0 / sqrt(var + 1e-5);
      }
      __syncthreads();
      double mu = sm.stats[0][0], rs = sm.stats[0][1];
      float* gd = p.glob + (size_t)(b * NSP_ + spv) * NH_;
      int k2 = tid * 2;
      double o0 = ((double)gv.x - mu) * rs * p.ln_g[k2] + p.ln_b[k2];
      double o1 = ((double)gv.y - mu) * rs * p.ln_g[k2 + 1] + p.ln_b[k2 + 1];
      stA2(&gd[k2], (float)o0, (float)o1);
    }
  }
  // ---------------- head(t-2) (208..223) ----------------
  else if (bid >= 208 && bid < 224) {
    if (t >= 2 && t <= NS_ + 1) {
      int th = t - 2, ct = bid - 208;
      const float* er = p.e_out + (size_t)(th & 1) * NB_ * NH_;
      for (int idx = tid; idx < NB_ * NH_ / 4; idx += 256) {
        int b = idx >> 7, k = (idx & 127) * 4;
        *(f4*)&sm.hA[b][k] = ldA4(&er[b * NH_ + k]);
      }
      __syncthreads();
      {
        int ci = tid >> 4, kc = tid & 15, c = ct * 16 + ci;
        const f4* W = (const f4*)(p.out_w1 + (size_t)c * 512);
        const f4* H = (const f4*)&sm.hA[0][0];
        double acc[NB_] = {};
#pragma unroll
        for (int i = 0; i < 8; ++i) {
          int q = kc + 16 * i;
          f4 w = W[q];
#pragma unroll
          for (int b = 0; b < NB_; ++b) acc[b] += dot4d(H[b * 130 + q], w);
        }
#pragma unroll
        for (int b = 0; b < NB_; ++b) {
          double v = acc[b];
#pragma unroll
          for (int m = 1; m <= 8; m <<= 1) v += __shfl_xor(v, m);
          if (kc == 0) sm.redH[ci][b] = v;
        }
      }
      __syncthreads();
      {
        int b = tid >> 4, ci = tid & 15, c = ct * 16 + ci;
        double h1 = sm.redH[ci][b] + (double)p.out_b1[c];
        stA1(&p.h1buf[(size_t)(th & 1) * NB_ * NH2_ + b * NH2_ + c], (float)fmax(h1, 0.0));
      }
    }
  }
  // ---------------- score(t-3) (224) ----------------
  else if (bid == 224) {
    if (t >= 3 && t <= NS_ + 2) {
      int ts = t - 3;
      int b = tid >> 4, cg = tid & 15;
      const float* h1p = p.h1buf + (size_t)(ts & 1) * NB_ * NH2_;
      double s1 = 0, s2 = 0;
      float hv[16];
#pragma unroll
      for (int i = 0; i < 16; ++i) {
        float v = ldA1(&h1p[b * NH2_ + cg * 16 + i]);
        hv[i] = v; s1 += (double)v; s2 += (double)v * (double)v;
      }
#pragma unroll
      for (int m = 1; m <= 8; m <<= 1) { s1 += __shfl_xor(s1, m); s2 += __shfl_xor(s2, m); }
      double mu = s1 * (1.0 / NH2_), var = s2 * (1.0 / NH2_) - mu * mu, rstd = 1.0 / sqrt(var + 1e-5);
      double d = 0;
#pragma unroll
      for (int i = 0; i < 16; ++i) {
        int c = cg * 16 + i;
        d += (((double)hv[i] - mu) * rstd * p.out_ln_g[c] + (double)p.out_ln_b[c]) * (double)p.out_w2[c];
      }
#pragma unroll
      for (int m = 1; m <= 8; m <<= 1) d += __shfl_xor(d, m);
      if (cg == 0) p.out[b * NS_ + ts] = (float)sigm_d(d + (double)p.out_b2[0]);
    }
  }
  // ---------------- eg(t-1) (128..191) ----------------
  else if (bid >= 128) {
    if (t >= 1 && t <= NS_) {
      const int te = t - 1;
      const int jj0 = (bid - 128) * 8;
      const float* eprev = p.e_out + (size_t)((te - 1) & 1) * NB_ * NH_;
      const float* gcur  = p.g_new + (size_t)(te & 1) * NB_ * NH_;
      // pass 1: load raw
      for (int idx = tid; idx < NB_ * NH_ / 2; idx += 256) {
        int half = idx >= NB_ * NH_ / 4;
        int r4 = idx & (NB_ * NH_ / 4 - 1);
        int b = r4 >> 7, k = (r4 & 127) * 4;
        if (!half) {
          f4 v = (te == 0) ? *(const f4*)&p.init_emotion[k] : ldA4(&eprev[b * NH_ + k]);
          *(f4*)&sm.hA[b][k] = v;
        } else {
          *(f4*)&sm.hB[b][k] = ldA4(&gcur[b * NH_ + k]);
        }
      }
      __syncthreads();
      // pass 2: block-local stats (hA if te>0; hB always)
      {
        int b = tid >> 4, kc = tid & 15;
        double a1 = 0, a2 = 0, b1 = 0, b2 = 0;
#pragma unroll
        for (int i = 0; i < 32; ++i) {
          double xa = (double)sm.hA[b][kc + i * 16];
          double xb = (double)sm.hB[b][kc + i * 16];
          a1 += xa; a2 += xa * xa; b1 += xb; b2 += xb * xb;
        }
#pragma unroll
        for (int m = 1; m <= 8; m <<= 1) {
          a1 += __shfl_xor(a1, m); a2 += __shfl_xor(a2, m);
          b1 += __shfl_xor(b1, m); b2 += __shfl_xor(b2, m);
        }
        if (kc == 0) {
          double mu = a1 * (1.0 / NH_), var = a2 * (1.0 / NH_) - mu * mu;
          sm.stats[b][0] = mu; sm.stats[b][1] = 1.0 / sqrt(var + 1e-5);
          mu = b1 * (1.0 / NH_); var = b2 * (1.0 / NH_) - mu * mu;
          sm.stats2[b][0] = mu; sm.stats2[b][1] = 1.0 / sqrt(var + 1e-5);
        }
      }
      __syncthreads();
      // pass 3: LN in place
      for (int idx = tid; idx < NB_ * NH_ / 2; idx += 256) {
        int half = idx >= NB_ * NH_ / 4;
        int r4 = idx & (NB_ * NH_ / 4 - 1);
        int b = r4 >> 7, k = (r4 & 127) * 4;
        f4 g4 = *(const f4*)&p.ln_g[k], b4 = *(const f4*)&p.ln_b[k];
        if (!half) {
          if (te > 0) {
            f4 pv = *(f4*)&sm.hA[b][k];
            double mu = sm.stats[b][0], rs = sm.stats[b][1];
            f4 v;
            v.x = (float)(((double)pv.x - mu) * rs * g4.x + b4.x);
            v.y = (float)(((double)pv.y - mu) * rs * g4.y + b4.y);
            v.z = (float)(((double)pv.z - mu) * rs * g4.z + b4.z);
            v.w = (float)(((double)pv.w - mu) * rs * g4.w + b4.w);
            *(f4*)&sm.hA[b][k] = v;
          }
        } else {
          f4 pv = *(f4*)&sm.hB[b][k];
          double mu = sm.stats2[b][0], rs = sm.stats2[b][1];
          f4 v;
          v.x = (float)(((double)pv.x - mu) * rs * g4.x + b4.x);
          v.y = (float)(((double)pv.y - mu) * rs * g4.y + b4.y);
          v.z = (float)(((double)pv.z - mu) * rs * g4.z + b4.z);
          v.w = (float)(((double)pv.w - mu) * rs * g4.w + b4.w);
          *(f4*)&sm.hB[b][k] = v;
        }
      }
      __syncthreads();
      {
        int jj = tid >> 5, kc = tid & 31, j = jj0 + jj;
        const f4* Wr_w = (const f4*)(p.eg_wih + (size_t)j * 1024);
        const f4* Wz_w = (const f4*)(p.eg_wih + (size_t)(512 + j) * 1024);
        const f4* Wn_w = (const f4*)(p.eg_wih + (size_t)(1024 + j) * 1024);
        const f4* Wr_h = (const f4*)(p.eg_whh + (size_t)j * 512);
        const f4* Wz_h = (const f4*)(p.eg_whh + (size_t)(512 + j) * 512);
        const f4* Wn_h = (const f4*)(p.eg_whh + (size_t)(1024 + j) * 512);
        const f4* HA = (const f4*)&sm.hA[0][0];
        const f4* HB = (const f4*)&sm.hB[0][0];
        // ---- pass A: r,z gates only (32 fp64 accumulators, spill-free) ----
        {
          double ar[NB_] = {}, az[NB_] = {};
#pragma unroll
          for (int i = 0; i < 12; ++i) {
            int q = kc + 32 * i;
            f4 wr, wz; const f4* Ab; int hq;
            if (i < 8) { wr = Wr_w[q]; wz = Wz_w[q]; }
            else       { wr = Wr_h[q - 256]; wz = Wz_h[q - 256]; }
            if (i < 4)      { Ab = HA; hq = q; }
            else if (i < 8) { Ab = HB; hq = q - 128; }
            else            { Ab = HA; hq = q - 256; }
#pragma unroll
            for (int b = 0; b < NB_; ++b) {
              f4 a = Ab[b * 130 + hq];
              ar[b] += dot4d(a, wr); az[b] += dot4d(a, wz);
            }
          }
#pragma unroll
          for (int b = 0; b < NB_; ++b) {
            double r = ar[b], z = az[b];
#pragma unroll
            for (int m = 1; m <= 16; m <<= 1) { r += __shfl_xor(r, m); z += __shfl_xor(z, m); }
            if (kc == 0) { sm.red[jj][b][0] = r; sm.red[jj][b][1] = z; }
          }
        }
        // ---- pass B: n gate (pn from wih, ph from whh) ----
        {
          double apn[NB_] = {}, aph[NB_] = {};
#pragma unroll
          for (int i = 0; i < 12; ++i) {
            int q = kc + 32 * i;
            f4 wn; const f4* Ab; int hq;
            if (i < 8) wn = Wn_w[q]; else wn = Wn_h[q - 256];
            if (i < 4)      { Ab = HA; hq = q; }
            else if (i < 8) { Ab = HB; hq = q - 128; }
            else            { Ab = HA; hq = q - 256; }
#pragma unroll
            for (int b = 0; b < NB_; ++b) {
              f4 a = Ab[b * 130 + hq];
              if (i < 8) apn[b] += dot4d(a, wn); else aph[b] += dot4d(a, wn);
            }
          }
#pragma unroll
          for (int b = 0; b < NB_; ++b) {
            double pn = apn[b], ph = aph[b];
#pragma unroll
            for (int m = 1; m <= 16; m <<= 1) { pn += __shfl_xor(pn, m); ph += __shfl_xor(ph, m); }
            if (kc == 0) { sm.red[jj][b][2] = pn; sm.red[jj][b][3] = ph; }
          }
        }
      }
      __syncthreads();
      if (tid < 128) {
        int b = tid >> 3, jj = tid & 7, j = jj0 + jj;
        const double* rd = sm.red[jj][b];
        double r = sigm_d(rd[0] + (double)p.eg_bih[j] + (double)p.eg_bhh[j]);
        double z = sigm_d(rd[1] + (double)p.eg_bih[512 + j] + (double)p.eg_bhh[512 + j]);
        double inn = rd[2] + (double)p.eg_bih[1024 + j];
        double hn  = rd[3] + (double)p.eg_bhh[1024 + j];
        double n = tanh(inn + r * hn);
        double hp = (double)sm.hA[b][j];
        double hv = (1.0 - z) * n + z * hp;
        stA1(&p.e_out[(size_t)(te & 1) * NB_ * NH_ + b * NH_ + j], (float)hv);
      }
    }
  }
  // ---------------- pg(t) (0..63) | gg(t) (64..127) ----------------
  else {
    if (t < NS_) {
      const bool is_pg = bid < 64;
      const int jj0 = (is_pg ? bid : bid - 64) * 8;
      const float* wih = is_pg ? p.pg_wih : p.gg_wih;
      const float* whh = is_pg ? p.pg_whh : p.gg_whh;
      const float* bih = is_pg ? p.pg_bih : p.gg_bih;
      const float* bhh = is_pg ? p.pg_bhh : p.gg_bhh;
      const float* gix = is_pg ? p.gixp : p.gixg;

      if (!is_pg && tid < NB_) {
        sm.spk[tid]  = p.spk[tid * NS_ + t];
        sm.spkp[tid] = (t > 0) ? p.spk[tid * NS_ + t - 1] : -1;
      }
      __syncthreads();

      // pass 1: load raw state
      const float* prev = p.party_pre + (size_t)((t - 1) & 1) * NB_ * NH_;
      const float* gprev = p.g_new + (size_t)((t - 1) & 1) * NB_ * NH_;
      for (int idx = tid; idx < NB_ * NH_ / 4; idx += 256) {
        int b = idx >> 7, k = (idx & 127) * 4;
        f4 v;
        if (is_pg) {
          v = (t == 0) ? *(const f4*)&p.init_party[k] : ldA4(&prev[b * NH_ + k]);
        } else {
          v = (sm.spk[b] == sm.spkp[b]) ? ldA4(&gprev[b * NH_ + k])
                                        : ldA4(&p.glob[(size_t)(b * NSP_ + sm.spk[b]) * NH_ + k]);
        }
        *(f4*)&sm.hA[b][k] = v;
      }
      __syncthreads();
      // pass 2: block-local stats
      row_stats(sm.hA, sm.stats, tid);
      __syncthreads();
      // pass 3: LN in place (pg: t>0; gg: only spk-match rows)
      {
        bool any = is_pg ? (t > 0) : true;
        if (any) {
          for (int idx = tid; idx < NB_ * NH_ / 4; idx += 256) {
            int b = idx >> 7, k = (idx & 127) * 4;
            bool doln = is_pg ? (t > 0) : (sm.spk[b] == sm.spkp[b]);
            if (doln) {
              f4 pv = *(f4*)&sm.hA[b][k];
              f4 g4 = *(const f4*)&p.ln_g[k], b4 = *(const f4*)&p.ln_b[k];
              double mu = sm.stats[b][0], rs = sm.stats[b][1];
              f4 v;
              v.x = (float)(((double)pv.x - mu) * rs * g4.x + b4.x);
              v.y = (float)(((double)pv.y - mu) * rs * g4.y + b4.y);
              v.z = (float)(((double)pv.z - mu) * rs * g4.z + b4.z);
              v.w = (float)(((double)pv.w - mu) * rs * g4.w + b4.w);
              *(f4*)&sm.hA[b][k] = v;
            }
          }
        }
      }
      __syncthreads();

      {
        int jj = tid >> 5, kc = tid & 31, j = jj0 + jj;
        const f4* Wr_w = (const f4*)(wih + (size_t)j * 1536 + 1024);
        const f4* Wz_w = (const f4*)(wih + (size_t)(512 + j) * 1536 + 1024);
        const f4* Wn_w = (const f4*)(wih + (size_t)(1024 + j) * 1536 + 1024);
        const f4* Wr_h = (const f4*)(whh + (size_t)j * 512);
        const f4* Wz_h = (const f4*)(whh + (size_t)(512 + j) * 512);
        const f4* Wn_h = (const f4*)(whh + (size_t)(1024 + j) * 512);
        const f4* H = (const f4*)&sm.hA[0][0];
        // ---- pass A: r,z gates (32 fp64 accumulators, spill-free) ----
        {
          double ar[NB_] = {}, az[NB_] = {};
#pragma unroll
          for (int i = 0; i < 8; ++i) {
            int q = kc + 32 * i;
            f4 wr, wz; int hq;
            if (i < 4) { wr = Wr_w[q]; wz = Wz_w[q]; hq = q; }
            else       { wr = Wr_h[q - 128]; wz = Wz_h[q - 128]; hq = q - 128; }
#pragma unroll
            for (int b = 0; b < NB_; ++b) {
              f4 a = H[b * 130 + hq];
              ar[b] += dot4d(a, wr); az[b] += dot4d(a, wz);
            }
          }
#pragma unroll
          for (int b = 0; b < NB_; ++b) {
            double r = ar[b], z = az[b];
#pragma unroll
            for (int m = 1; m <= 16; m <<= 1) { r += __shfl_xor(r, m); z += __shfl_xor(z, m); }
            if (kc == 0) { sm.red[jj][b][0] = r; sm.red[jj][b][1] = z; }
          }
        }
        // ---- pass B: n gate ----
        {
          double apn[NB_] = {}, aph[NB_] = {};
#pragma unroll
          for (int i = 0; i < 8; ++i) {
            int q = kc + 32 * i;
            f4 wn; int hq;
            if (i < 4) { wn = Wn_w[q]; hq = q; }
            else       { wn = Wn_h[q - 128]; hq = q - 128; }
#pragma unroll
            for (int b = 0; b < NB_; ++b) {
              f4 a = H[b * 130 + hq];
              if (i < 4) apn[b] += dot4d(a, wn); else aph[b] += dot4d(a, wn);
            }
          }
#pragma unroll
          for (int b = 0; b < NB_; ++b) {
            double pn = apn[b], ph = aph[b];
#pragma unroll
            for (int m = 1; m <= 16; m <<= 1) { pn += __shfl_xor(pn, m); ph += __shfl_xor(ph, m); }
            if (kc == 0) { sm.red[jj][b][2] = pn; sm.red[jj][b][3] = ph; }
          }
        }
      }
      __syncthreads();

      if (tid < 128) {
        int b = tid >> 3, jj = tid & 7, j = jj0 + jj;
        const double* rd = sm.red[jj][b];
        const float* gx = gix + (size_t)(b * NS_ + t) * 1536;
        double r = sigm_d(rd[0] + (double)gx[j] + (double)bih[j] + (double)bhh[j]);
        double z = sigm_d(rd[1] + (double)gx[512 + j] + (double)bih[512 + j] + (double)bhh[512 + j]);
        double inn = rd[2] + (double)gx[1024 + j] + (double)bih[1024 + j];
        double hn  = rd[3] + (double)bhh[1024 + j];
        double n = tanh(inn + r * hn);
        double hp = (double)sm.hA[b][j];
        double hv = (1.0 - z) * n + z * hp;
        float* dst = is_pg ? (p.party_pre + (size_t)(t & 1) * NB_ * NH_)
                           : (p.g_new + (size_t)(t & 1) * NB_ * NH_);
        stA1(&dst[b * NH_ + j], (float)hv);
      }
    }
  }
}

__global__ __launch_bounds__(256, 1) void seq_kernel(Params p) {
  __shared__ Smem sm;
  const int bid = blockIdx.x, tid = threadIdx.x;
  for (int t = 0; t <= NS_ + 2; ++t) {
    step_body(p, sm, t, bid, tid);
    gbar_flags(p.flags, p.gen, bid, gridDim.x, (u32)(t + 1));
  }
}

// x-projection precompute: gix[gru][bs][row] = sum_k utt[bs][k] * wih[row][k], k<1024 (fp64 accum)
__global__ __launch_bounds__(512) void gix_kernel(const float* utt, const float* pgw,
                                                  const float* ggw, float* gix) {
  __shared__ float xs[16][1028];
  const int tid = threadIdx.x;
  long bs0 = (long)blockIdx.x * 16;
  for (int i = tid; i < 16 * 256; i += 512) {
    int bb = i >> 8, kf = i & 255;
    *(f4*)&xs[bb][kf * 4] = *(const f4*)(utt + (bs0 + bb) * 1024 + kf * 4);
  }
  __syncthreads();
  int R = blockIdx.y * 32 + (tid >> 4);
  int bi = tid & 15;
  const float* wrow = (R < 1536) ? pgw + (size_t)R * 1536 : ggw + (size_t)(R - 1536) * 1536;
  const f4* w4 = (const f4*)wrow;
  const f4* x4 = (const f4*)&xs[bi][0];
  double acc = 0;
  for (int k = 0; k < 256; ++k) acc += dot4d(x4[k], w4[k]);
  size_t base = (R < 1536) ? 0 : (size_t)8192 * 1536;
  int r = (R < 1536) ? R : R - 1536;
  gix[base + (size_t)(bs0 + bi) * 1536 + r] = (float)acc;
}

__global__ void init_kernel(float* glob, const float* init_global, u32* flags, u32* gen) {
  long stride = (long)gridDim.x * blockDim.x;
  long t0 = (long)blockIdx.x * blockDim.x + threadIdx.x;
  for (long i = t0; i < (long)NB_ * NSP_ * NH_; i += stride) {
    int sp = ((int)i >> 9) & (NSP_ - 1);
    int k = (int)i & (NH_ - 1);
    glob[i] = init_global[sp * NH_ + k];
  }
  for (long i = t0; i < NBLK * 16; i += stride) flags[i] = 0u;
  if (t0 == 0) *gen = 0u;
}

extern "C" void kernel_launch(void* const* d_in, const int* in_sizes, int n_in,
                              void* d_out, int out_size, void* d_ws, size_t ws_size,
                              hipStream_t stream) {
  (void)in_sizes; (void)n_in; (void)out_size;
  Params p;
  p.utt    = (const float*)d_in[0];
  p.spk    = (const int*)d_in[1];
  p.init_party   = (const float*)d_in[2];
  const float* ig = (const float*)d_in[3];
  p.init_emotion = (const float*)d_in[4];
  p.pg_wih = (const float*)d_in[5];
  p.pg_whh = (const float*)d_in[6];
  p.pg_bih = (const float*)d_in[7];
  p.pg_bhh = (const float*)d_in[8];
  p.gg_wih = (const float*)d_in[9];
  p.gg_whh = (const float*)d_in[10];
  p.gg_bih = (const float*)d_in[11];
  p.gg_bhh = (const float*)d_in[12];
  p.eg_wih = (const float*)d_in[13];
  p.eg_whh = (const float*)d_in[14];
  p.eg_bih = (const float*)d_in[15];
  p.eg_bhh = (const float*)d_in[16];
  // 17..19 attention weights: softmax over length-1 axis == 1 -> provably unused
  p.ln_g   = (const float*)d_in[20];
  p.ln_b   = (const float*)d_in[21];
  p.out_w1 = (const float*)d_in[22];
  p.out_b1 = (const float*)d_in[23];
  p.out_ln_g = (const float*)d_in[24];
  p.out_ln_b = (const float*)d_in[25];
  p.out_w2 = (const float*)d_in[26];
  p.out_b2 = (const float*)d_in[27];

  char* w = (char*)d_ws;
  auto alloc = [&](size_t bytes) { char* r = w; w += (bytes + 255) & ~(size_t)255; return r; };
  float* gix       = (float*)alloc((size_t)2 * 8192 * 1536 * 4);   // ~100.7 MB
  float* party_pre = (float*)alloc((size_t)2 * NB_ * NH_ * 4);
  float* g_new     = (float*)alloc((size_t)2 * NB_ * NH_ * 4);
  float* e_out     = (float*)alloc((size_t)2 * NB_ * NH_ * 4);
  float* glob      = (float*)alloc((size_t)NB_ * NSP_ * NH_ * 4);
  float* h1buf     = (float*)alloc((size_t)2 * NB_ * NH2_ * 4);
  u32*   flags     = (u32*)alloc((size_t)NBLK * 16 * 4);
  u32*   gen       = (u32*)alloc(256);
  if ((size_t)(w - (char*)d_ws) > ws_size) return;  // ws too small -> loud failure (zeros)

  gix_kernel<<<dim3(512, 96), dim3(512), 0, stream>>>(p.utt, p.pg_wih, p.gg_wih, gix);
  init_kernel<<<dim3(64), dim3(256), 0, stream>>>(glob, ig, flags, gen);

  p.gixp = gix; p.gixg = gix + (size_t)8192 * 1536;
  p.party_pre = party_pre; p.g_new = g_new; p.e_out = e_out; p.glob = glob;
  p.h1buf = h1buf; p.flags = flags; p.gen = gen; p.out = (float*)d_out;

  seq_kernel<<<dim3(NBLK), dim3(256), 0, stream>>>(p);
}

// Round 17
// 27827.957 us; speedup vs baseline: 3.0468x; 1.1299x over previous
//
#include <hip/hip_runtime.h>

typedef __attribute__((ext_vector_type(4))) float f4;
using u32 = unsigned int;
using u64 = unsigned long long;

constexpr int NB_ = 16;    // batch
constexpr int NS_ = 512;   // seq len
constexpr int ND_ = 1024;  // input dim
constexpr int NH_ = 512;   // hidden
constexpr int NSP_ = 8;    // speakers
constexpr int NH2_ = 256;  // head hidden
constexpr int HP = 520;    // padded fp32 LDS row (130 f4)
constexpr int NBLK = 161;  // persistent grid: gg 64 | eg 64 | wb 16 | head 16 | score 1

struct Params {
  const float *utt;
  const float *gg_wih, *gg_whh, *eg_wih, *eg_whh, *out_w1;
  const float *gix;           // precomputed gg x-projection [B*S][1536] fp32
  const float *init_emotion;
  const float *gg_bih, *gg_bhh, *eg_bih, *eg_bhh;
  const float *ln_g, *ln_b, *out_b1, *out_ln_g, *out_ln_b, *out_w2, *out_b2;
  const int *spk;
  float *g_new;      // [2][B][H] raw gg output, parity t&1
  float *e_out;      // [2][B][H] raw eg output, parity te&1
  float *glob;       // [B][SP][H] post-LN (or raw init) global states
  float *h1buf;      // [2][B][H2] relu(e@W1+b1), parity th&1
  u32 *flags;        // [NBLK*16] arrival flags, one 64B line per block
  u32 *rel;          // [NBLK*16] per-block release lines (distributed release)
  float *out;        // [B][S]
};

__device__ __forceinline__ double sigm_d(double x) { return 1.0 / (1.0 + exp(-x)); }
__device__ __forceinline__ double dot4d(f4 a, f4 w) {
  return ((double)a.x * w.x + (double)a.y * w.y) + ((double)a.z * w.z + (double)a.w * w.w);
}

// ---- cross-block plumbing: relaxed agent-scope atomics (bypass per-XCD L2; no flushes) ----
__device__ __forceinline__ void stA1(float* p, float v) {
  __hip_atomic_store(p, v, __ATOMIC_RELAXED, __HIP_MEMORY_SCOPE_AGENT);
}
__device__ __forceinline__ float ldA1(const float* p) {
  return __hip_atomic_load((float*)p, __ATOMIC_RELAXED, __HIP_MEMORY_SCOPE_AGENT);
}
__device__ __forceinline__ void stA2(float* p, float a, float b) {
  union { float f[2]; u64 u; } x; x.f[0] = a; x.f[1] = b;
  __hip_atomic_store((u64*)p, x.u, __ATOMIC_RELAXED, __HIP_MEMORY_SCOPE_AGENT);
}
__device__ __forceinline__ float2 ldA2(const float* p) {
  u64 u = __hip_atomic_load((u64*)p, __ATOMIC_RELAXED, __HIP_MEMORY_SCOPE_AGENT);
  union { u64 u; float f[2]; } x; x.u = u;
  return make_float2(x.f[0], x.f[1]);
}
__device__ __forceinline__ f4 ldA4(const float* p) {
  float2 lo = ldA2(p), hi = ldA2(p + 2);
  f4 v; v.x = lo.x; v.y = lo.y; v.z = hi.x; v.w = hi.y;
  return v;
}

// Barrier v3 — fully distributed: per-block arrival flag (own line, plain sc1 store) +
// per-block RELEASE line (block 0 fans out the epoch with one store per block, issued by
// 161 parallel threads). No shared line is ever polled by more than one block.
__device__ __forceinline__ void gbar3(u32* flags, u32* rel, int bid, int nb, u32 epoch) {
  __syncthreads();
  const int tid = threadIdx.x;
  if (bid == 0) {
    if (tid > 0 && tid < nb) {
      while (__hip_atomic_load(&flags[(size_t)tid * 16], __ATOMIC_RELAXED, __HIP_MEMORY_SCOPE_AGENT) < epoch)
        __builtin_amdgcn_s_sleep(1);
    }
    __syncthreads();
    if (tid < nb) {
      asm volatile("s_waitcnt vmcnt(0)" ::: "memory");
      __hip_atomic_store(&rel[(size_t)tid * 16], epoch, __ATOMIC_RELAXED, __HIP_MEMORY_SCOPE_AGENT);
    }
  } else {
    if (tid == 0) {
      asm volatile("s_waitcnt vmcnt(0) lgkmcnt(0)" ::: "memory");
      __hip_atomic_store(&flags[(size_t)bid * 16], epoch, __ATOMIC_RELAXED, __HIP_MEMORY_SCOPE_AGENT);
      while (__hip_atomic_load(&rel[(size_t)bid * 16], __ATOMIC_RELAXED, __HIP_MEMORY_SCOPE_AGENT) < epoch)
        __builtin_amdgcn_s_sleep(2);
    }
  }
  __syncthreads();
}

struct __align__(16) Smem {
  float hA[NB_][HP];
  float hB[NB_][HP];
  double red[8][NB_][4];
  double redH[16][NB_];
  double stats[NB_][2];
  double stats2[NB_][2];
  int spk[NB_], spkp[NB_];
};

// block-local per-b stats over sm row: 256 threads = (b 16, kc 16), 32 elems each, shfl-16
__device__ __forceinline__ void row_stats(const float (*h)[HP], double (*st)[2], int tid) {
  int b = tid >> 4, kc = tid & 15;
  double s1 = 0, s2 = 0;
#pragma unroll
  for (int i = 0; i < 32; ++i) {
    double x = (double)h[b][kc + i * 16];
    s1 += x; s2 += x * x;
  }
#pragma unroll
  for (int m = 1; m <= 8; m <<= 1) { s1 += __shfl_xor(s1, m); s2 += __shfl_xor(s2, m); }
  if (kc == 0) {
    double mu = s1 * (1.0 / NH_), var = s2 * (1.0 / NH_) - mu * mu;
    st[b][0] = mu; st[b][1] = 1.0 / sqrt(var + 1e-5);
  }
}

// One pipelined step t: gg(t)|eg(t-1)|wb(t-1)|head(t-2)|score(t-3).
// (party GRU + attention are provably dead: party feeds only itself, never the output path.)
__device__ void step_body(const Params& p, Smem& sm, int t, int bid, int tid) {
  // ---------------- gg(t) (0..63) ----------------
  if (bid < 64) {
    if (t < NS_) {
      const int jj0 = bid * 8;
      if (tid < NB_) {
        sm.spk[tid]  = p.spk[tid * NS_ + t];
        sm.spkp[tid] = (t > 0) ? p.spk[tid * NS_ + t - 1] : -1;
      }
      __syncthreads();
      // pass 1: load raw state (g_new(t-1) if same speaker, else stored glob)
      const float* gprev = p.g_new + (size_t)((t - 1) & 1) * NB_ * NH_;
      for (int idx = tid; idx < NB_ * NH_ / 4; idx += 256) {
        int b = idx >> 7, k = (idx & 127) * 4;
        f4 v = (sm.spk[b] == sm.spkp[b]) ? ldA4(&gprev[b * NH_ + k])
                                         : ldA4(&p.glob[(size_t)(b * NSP_ + sm.spk[b]) * NH_ + k]);
        *(f4*)&sm.hA[b][k] = v;
      }
      __syncthreads();
      row_stats(sm.hA, sm.stats, tid);
      __syncthreads();
      // pass 3: LN in place (only speaker-match rows; glob rows already post-LN)
      for (int idx = tid; idx < NB_ * NH_ / 4; idx += 256) {
        int b = idx >> 7, k = (idx & 127) * 4;
        if (sm.spk[b] == sm.spkp[b]) {
          f4 pv = *(f4*)&sm.hA[b][k];
          f4 g4 = *(const f4*)&p.ln_g[k], b4 = *(const f4*)&p.ln_b[k];
          double mu = sm.stats[b][0], rs = sm.stats[b][1];
          f4 v;
          v.x = (float)(((double)pv.x - mu) * rs * g4.x + b4.x);
          v.y = (float)(((double)pv.y - mu) * rs * g4.y + b4.y);
          v.z = (float)(((double)pv.z - mu) * rs * g4.z + b4.z);
          v.w = (float)(((double)pv.w - mu) * rs * g4.w + b4.w);
          *(f4*)&sm.hA[b][k] = v;
        }
      }
      __syncthreads();
      {
        int jj = tid >> 5, kc = tid & 31, j = jj0 + jj;
        const f4* Wr_w = (const f4*)(p.gg_wih + (size_t)j * 1536 + 1024);
        const f4* Wz_w = (const f4*)(p.gg_wih + (size_t)(512 + j) * 1536 + 1024);
        const f4* Wn_w = (const f4*)(p.gg_wih + (size_t)(1024 + j) * 1536 + 1024);
        const f4* Wr_h = (const f4*)(p.gg_whh + (size_t)j * 512);
        const f4* Wz_h = (const f4*)(p.gg_whh + (size_t)(512 + j) * 512);
        const f4* Wn_h = (const f4*)(p.gg_whh + (size_t)(1024 + j) * 512);
        const f4* H = (const f4*)&sm.hA[0][0];
        // pass A: r,z gates (32 fp64 accumulators)
        {
          double ar[NB_] = {}, az[NB_] = {};
#pragma unroll
          for (int i = 0; i < 8; ++i) {
            int q = kc + 32 * i;
            f4 wr, wz; int hq;
            if (i < 4) { wr = Wr_w[q]; wz = Wz_w[q]; hq = q; }
            else       { wr = Wr_h[q - 128]; wz = Wz_h[q - 128]; hq = q - 128; }
#pragma unroll
            for (int b = 0; b < NB_; ++b) {
              f4 a = H[b * 130 + hq];
              ar[b] += dot4d(a, wr); az[b] += dot4d(a, wz);
            }
          }
#pragma unroll
          for (int b = 0; b < NB_; ++b) {
            double r = ar[b], z = az[b];
#pragma unroll
            for (int m = 1; m <= 16; m <<= 1) { r += __shfl_xor(r, m); z += __shfl_xor(z, m); }
            if (kc == 0) { sm.red[jj][b][0] = r; sm.red[jj][b][1] = z; }
          }
        }
        // pass B: n gate
        {
          double apn[NB_] = {}, aph[NB_] = {};
#pragma unroll
          for (int i = 0; i < 8; ++i) {
            int q = kc + 32 * i;
            f4 wn; int hq;
            if (i < 4) { wn = Wn_w[q]; hq = q; }
            else       { wn = Wn_h[q - 128]; hq = q - 128; }
#pragma unroll
            for (int b = 0; b < NB_; ++b) {
              f4 a = H[b * 130 + hq];
              if (i < 4) apn[b] += dot4d(a, wn); else aph[b] += dot4d(a, wn);
            }
          }
#pragma unroll
          for (int b = 0; b < NB_; ++b) {
            double pn = apn[b], ph = aph[b];
#pragma unroll
            for (int m = 1; m <= 16; m <<= 1) { pn += __shfl_xor(pn, m); ph += __shfl_xor(ph, m); }
            if (kc == 0) { sm.red[jj][b][2] = pn; sm.red[jj][b][3] = ph; }
          }
        }
      }
      __syncthreads();
      if (tid < 128) {
        int b = tid >> 3, jj = tid & 7, j = jj0 + jj;
        const double* rd = sm.red[jj][b];
        const float* gx = p.gix + (size_t)(b * NS_ + t) * 1536;
        double r = sigm_d(rd[0] + (double)gx[j] + (double)p.gg_bih[j] + (double)p.gg_bhh[j]);
        double z = sigm_d(rd[1] + (double)gx[512 + j] + (double)p.gg_bih[512 + j] + (double)p.gg_bhh[512 + j]);
        double inn = rd[2] + (double)gx[1024 + j] + (double)p.gg_bih[1024 + j];
        double hn  = rd[3] + (double)p.gg_bhh[1024 + j];
        double n = tanh(inn + r * hn);
        double hp = (double)sm.hA[b][j];
        double hv = (1.0 - z) * n + z * hp;
        stA1(&p.g_new[(size_t)(t & 1) * NB_ * NH_ + b * NH_ + j], (float)hv);
      }
    }
  }
  // ---------------- eg(t-1) (64..127) ----------------
  else if (bid < 128) {
    if (t >= 1 && t <= NS_) {
      const int te = t - 1;
      const int jj0 = (bid - 64) * 8;
      const float* eprev = p.e_out + (size_t)((te - 1) & 1) * NB_ * NH_;
      const float* gcur  = p.g_new + (size_t)(te & 1) * NB_ * NH_;
      for (int idx = tid; idx < NB_ * NH_ / 2; idx += 256) {
        int half = idx >= NB_ * NH_ / 4;
        int r4 = idx & (NB_ * NH_ / 4 - 1);
        int b = r4 >> 7, k = (r4 & 127) * 4;
        if (!half) {
          f4 v = (te == 0) ? *(const f4*)&p.init_emotion[k] : ldA4(&eprev[b * NH_ + k]);
          *(f4*)&sm.hA[b][k] = v;
        } else {
          *(f4*)&sm.hB[b][k] = ldA4(&gcur[b * NH_ + k]);
        }
      }
      __syncthreads();
      {
        int b = tid >> 4, kc = tid & 15;
        double a1 = 0, a2 = 0, b1 = 0, b2 = 0;
#pragma unroll
        for (int i = 0; i < 32; ++i) {
          double xa = (double)sm.hA[b][kc + i * 16];
          double xb = (double)sm.hB[b][kc + i * 16];
          a1 += xa; a2 += xa * xa; b1 += xb; b2 += xb * xb;
        }
#pragma unroll
        for (int m = 1; m <= 8; m <<= 1) {
          a1 += __shfl_xor(a1, m); a2 += __shfl_xor(a2, m);
          b1 += __shfl_xor(b1, m); b2 += __shfl_xor(b2, m);
        }
        if (kc == 0) {
          double mu = a1 * (1.0 / NH_), var = a2 * (1.0 / NH_) - mu * mu;
          sm.stats[b][0] = mu; sm.stats[b][1] = 1.0 / sqrt(var + 1e-5);
          mu = b1 * (1.0 / NH_); var = b2 * (1.0 / NH_) - mu * mu;
          sm.stats2[b][0] = mu; sm.stats2[b][1] = 1.0 / sqrt(var + 1e-5);
        }
      }
      __syncthreads();
      for (int idx = tid; idx < NB_ * NH_ / 2; idx += 256) {
        int half = idx >= NB_ * NH_ / 4;
        int r4 = idx & (NB_ * NH_ / 4 - 1);
        int b = r4 >> 7, k = (r4 & 127) * 4;
        f4 g4 = *(const f4*)&p.ln_g[k], b4 = *(const f4*)&p.ln_b[k];
        if (!half) {
          if (te > 0) {
            f4 pv = *(f4*)&sm.hA[b][k];
            double mu = sm.stats[b][0], rs = sm.stats[b][1];
            f4 v;
            v.x = (float)(((double)pv.x - mu) * rs * g4.x + b4.x);
            v.y = (float)(((double)pv.y - mu) * rs * g4.y + b4.y);
            v.z = (float)(((double)pv.z - mu) * rs * g4.z + b4.z);
            v.w = (float)(((double)pv.w - mu) * rs * g4.w + b4.w);
            *(f4*)&sm.hA[b][k] = v;
          }
        } else {
          f4 pv = *(f4*)&sm.hB[b][k];
          double mu = sm.stats2[b][0], rs = sm.stats2[b][1];
          f4 v;
          v.x = (float)(((double)pv.x - mu) * rs * g4.x + b4.x);
          v.y = (float)(((double)pv.y - mu) * rs * g4.y + b4.y);
          v.z = (float)(((double)pv.z - mu) * rs * g4.z + b4.z);
          v.w = (float)(((double)pv.w - mu) * rs * g4.w + b4.w);
          *(f4*)&sm.hB[b][k] = v;
        }
      }
      __syncthreads();
      {
        int jj = tid >> 5, kc = tid & 31, j = jj0 + jj;
        const f4* Wr_w = (const f4*)(p.eg_wih + (size_t)j * 1024);
        const f4* Wz_w = (const f4*)(p.eg_wih + (size_t)(512 + j) * 1024);
        const f4* Wn_w = (const f4*)(p.eg_wih + (size_t)(1024 + j) * 1024);
        const f4* Wr_h = (const f4*)(p.eg_whh + (size_t)j * 512);
        const f4* Wz_h = (const f4*)(p.eg_whh + (size_t)(512 + j) * 512);
        const f4* Wn_h = (const f4*)(p.eg_whh + (size_t)(1024 + j) * 512);
        const f4* HA = (const f4*)&sm.hA[0][0];
        const f4* HB = (const f4*)&sm.hB[0][0];
        // pass A: r,z
        {
          double ar[NB_] = {}, az[NB_] = {};
#pragma unroll
          for (int i = 0; i < 12; ++i) {
            int q = kc + 32 * i;
            f4 wr, wz; const f4* Ab; int hq;
            if (i < 8) { wr = Wr_w[q]; wz = Wz_w[q]; }
            else       { wr = Wr_h[q - 256]; wz = Wz_h[q - 256]; }
            if (i < 4)      { Ab = HA; hq = q; }
            else if (i < 8) { Ab = HB; hq = q - 128; }
            else            { Ab = HA; hq = q - 256; }
#pragma unroll
            for (int b = 0; b < NB_; ++b) {
              f4 a = Ab[b * 130 + hq];
              ar[b] += dot4d(a, wr); az[b] += dot4d(a, wz);
            }
          }
#pragma unroll
          for (int b = 0; b < NB_; ++b) {
            double r = ar[b], z = az[b];
#pragma unroll
            for (int m = 1; m <= 16; m <<= 1) { r += __shfl_xor(r, m); z += __shfl_xor(z, m); }
            if (kc == 0) { sm.red[jj][b][0] = r; sm.red[jj][b][1] = z; }
          }
        }
        // pass B: n
        {
          double apn[NB_] = {}, aph[NB_] = {};
#pragma unroll
          for (int i = 0; i < 12; ++i) {
            int q = kc + 32 * i;
            f4 wn; const f4* Ab; int hq;
            if (i < 8) wn = Wn_w[q]; else wn = Wn_h[q - 256];
            if (i < 4)      { Ab = HA; hq = q; }
            else if (i < 8) { Ab = HB; hq = q - 128; }
            else            { Ab = HA; hq = q - 256; }
#pragma unroll
            for (int b = 0; b < NB_; ++b) {
              f4 a = Ab[b * 130 + hq];
              if (i < 8) apn[b] += dot4d(a, wn); else aph[b] += dot4d(a, wn);
            }
          }
#pragma unroll
          for (int b = 0; b < NB_; ++b) {
            double pn = apn[b], ph = aph[b];
#pragma unroll
            for (int m = 1; m <= 16; m <<= 1) { pn += __shfl_xor(pn, m); ph += __shfl_xor(ph, m); }
            if (kc == 0) { sm.red[jj][b][2] = pn; sm.red[jj][b][3] = ph; }
          }
        }
      }
      __syncthreads();
      if (tid < 128) {
        int b = tid >> 3, jj = tid & 7, j = jj0 + jj;
        const double* rd = sm.red[jj][b];
        double r = sigm_d(rd[0] + (double)p.eg_bih[j] + (double)p.eg_bhh[j]);
        double z = sigm_d(rd[1] + (double)p.eg_bih[512 + j] + (double)p.eg_bhh[512 + j]);
        double inn = rd[2] + (double)p.eg_bih[1024 + j];
        double hn  = rd[3] + (double)p.eg_bhh[1024 + j];
        double n = tanh(inn + r * hn);
        double hp = (double)sm.hA[b][j];
        double hv = (1.0 - z) * n + z * hp;
        stA1(&p.e_out[(size_t)(te & 1) * NB_ * NH_ + b * NH_ + j], (float)hv);
      }
    }
  }
  // ---------------- wb(t-1): one block per b (128..143) ----------------
  else if (bid < 144) {
    if (t >= 1 && t <= NS_) {
      int b = bid - 128, tw = t - 1;
      int spv = p.spk[b * NS_ + tw];
      const float* gsrc = p.g_new + (size_t)(tw & 1) * NB_ * NH_;
      float2 gv = ldA2(&gsrc[b * NH_ + tid * 2]);
      double s1 = (double)gv.x + (double)gv.y;
      double s2 = (double)gv.x * (double)gv.x + (double)gv.y * (double)gv.y;
#pragma unroll
      for (int m = 1; m <= 32; m <<= 1) { s1 += __shfl_xor(s1, m); s2 += __shfl_xor(s2, m); }
      int wid = tid >> 6;
      if ((tid & 63) == 0) { sm.redH[0][wid] = s1; sm.redH[1][wid] = s2; }
      __syncthreads();
      if (tid == 0) {
        double ts1 = sm.redH[0][0] + sm.redH[0][1] + sm.redH[0][2] + sm.redH[0][3];
        double ts2 = sm.redH[1][0] + sm.redH[1][1] + sm.redH[1][2] + sm.redH[1][3];
        double mu = ts1 * (1.0 / NH_), var = ts2 * (1.0 / NH_) - mu * mu;
        sm.stats[0][0] = mu; sm.stats[0][1] = 1.0 / sqrt(var + 1e-5);
      }
      __syncthreads();
      double mu = sm.stats[0][0], rs = sm.stats[0][1];
      float* gd = p.glob + (size_t)(b * NSP_ + spv) * NH_;
      int k2 = tid * 2;
      double o0 = ((double)gv.x - mu) * rs * p.ln_g[k2] + p.ln_b[k2];
      double o1 = ((double)gv.y - mu) * rs * p.ln_g[k2 + 1] + p.ln_b[k2 + 1];
      stA2(&gd[k2], (float)o0, (float)o1);
    }
  }
  // ---------------- head(t-2) (144..159) ----------------
  else if (bid < 160) {
    if (t >= 2 && t <= NS_ + 1) {
      int th = t - 2, ct = bid - 144;
      const float* er = p.e_out + (size_t)(th & 1) * NB_ * NH_;
      for (int idx = tid; idx < NB_ * NH_ / 4; idx += 256) {
        int b = idx >> 7, k = (idx & 127) * 4;
        *(f4*)&sm.hA[b][k] = ldA4(&er[b * NH_ + k]);
      }
      __syncthreads();
      {
        int ci = tid >> 4, kc = tid & 15, c = ct * 16 + ci;
        const f4* W = (const f4*)(p.out_w1 + (size_t)c * 512);
        const f4* H = (const f4*)&sm.hA[0][0];
        double acc[NB_] = {};
#pragma unroll
        for (int i = 0; i < 8; ++i) {
          int q = kc + 16 * i;
          f4 w = W[q];
#pragma unroll
          for (int b = 0; b < NB_; ++b) acc[b] += dot4d(H[b * 130 + q], w);
        }
#pragma unroll
        for (int b = 0; b < NB_; ++b) {
          double v = acc[b];
#pragma unroll
          for (int m = 1; m <= 8; m <<= 1) v += __shfl_xor(v, m);
          if (kc == 0) sm.redH[ci][b] = v;
        }
      }
      __syncthreads();
      {
        int b = tid >> 4, ci = tid & 15, c = ct * 16 + ci;
        double h1 = sm.redH[ci][b] + (double)p.out_b1[c];
        stA1(&p.h1buf[(size_t)(th & 1) * NB_ * NH2_ + b * NH2_ + c], (float)fmax(h1, 0.0));
      }
    }
  }
  // ---------------- score(t-3) (160) ----------------
  else {
    if (t >= 3 && t <= NS_ + 2) {
      int ts = t - 3;
      int b = tid >> 4, cg = tid & 15;
      const float* h1p = p.h1buf + (size_t)(ts & 1) * NB_ * NH2_;
      double s1 = 0, s2 = 0;
      float hv[16];
#pragma unroll
      for (int i = 0; i < 16; ++i) {
        float v = ldA1(&h1p[b * NH2_ + cg * 16 + i]);
        hv[i] = v; s1 += (double)v; s2 += (double)v * (double)v;
      }
#pragma unroll
      for (int m = 1; m <= 8; m <<= 1) { s1 += __shfl_xor(s1, m); s2 += __shfl_xor(s2, m); }
      double mu = s1 * (1.0 / NH2_), var = s2 * (1.0 / NH2_) - mu * mu, rstd = 1.0 / sqrt(var + 1e-5);
      double d = 0;
#pragma unroll
      for (int i = 0; i < 16; ++i) {
        int c = cg * 16 + i;
        d += (((double)hv[i] - mu) * rstd * p.out_ln_g[c] + (double)p.out_ln_b[c]) * (double)p.out_w2[c];
      }
#pragma unroll
      for (int m = 1; m <= 8; m <<= 1) d += __shfl_xor(d, m);
      if (cg == 0) p.out[b * NS_ + ts] = (float)sigm_d(d + (double)p.out_b2[0]);
    }
  }
}

__global__ __launch_bounds__(256, 1) void seq_kernel(Params p) {
  __shared__ Smem sm;
  const int bid = blockIdx.x, tid = threadIdx.x;
  for (int t = 0; t <= NS_ + 2; ++t) {
    step_body(p, sm, t, bid, tid);
    gbar3(p.flags, p.rel, bid, gridDim.x, (u32)(t + 1));
  }
}

// gg x-projection precompute: gix[bs][row] = sum_k utt[bs][k] * gg_wih[row][k], k<1024 (fp64)
__global__ __launch_bounds__(512) void gix_kernel(const float* utt, const float* ggw, float* gix) {
  __shared__ float xs[16][1028];
  const int tid = threadIdx.x;
  long bs0 = (long)blockIdx.x * 16;
  for (int i = tid; i < 16 * 256; i += 512) {
    int bb = i >> 8, kf = i & 255;
    *(f4*)&xs[bb][kf * 4] = *(const f4*)(utt + (bs0 + bb) * 1024 + kf * 4);
  }
  __syncthreads();
  int R = blockIdx.y * 32 + (tid >> 4);
  int bi = tid & 15;
  const f4* w4 = (const f4*)(ggw + (size_t)R * 1536);
  const f4* x4 = (const f4*)&xs[bi][0];
  double acc = 0;
  for (int k = 0; k < 256; ++k) acc += dot4d(x4[k], w4[k]);
  gix[(size_t)(bs0 + bi) * 1536 + R] = (float)acc;
}

__global__ void init_kernel(float* glob, const float* init_global, u32* flags, u32* rel) {
  long stride = (long)gridDim.x * blockDim.x;
  long t0 = (long)blockIdx.x * blockDim.x + threadIdx.x;
  for (long i = t0; i < (long)NB_ * NSP_ * NH_; i += stride) {
    int sp = ((int)i >> 9) & (NSP_ - 1);
    int k = (int)i & (NH_ - 1);
    glob[i] = init_global[sp * NH_ + k];
  }
  for (long i = t0; i < NBLK * 16; i += stride) { flags[i] = 0u; rel[i] = 0u; }
}

extern "C" void kernel_launch(void* const* d_in, const int* in_sizes, int n_in,
                              void* d_out, int out_size, void* d_ws, size_t ws_size,
                              hipStream_t stream) {
  (void)in_sizes; (void)n_in; (void)out_size;
  Params p;
  p.utt    = (const float*)d_in[0];
  p.spk    = (const int*)d_in[1];
  // d_in[2] init_party: DEAD (party GRU feeds only itself, never the output path)
  const float* ig = (const float*)d_in[3];
  p.init_emotion = (const float*)d_in[4];
  // d_in[5..8] pg_*: DEAD (party GRU)
  p.gg_wih = (const float*)d_in[9];
  p.gg_whh = (const float*)d_in[10];
  p.gg_bih = (const float*)d_in[11];
  p.gg_bhh = (const float*)d_in[12];
  p.eg_wih = (const float*)d_in[13];
  p.eg_whh = (const float*)d_in[14];
  p.eg_bih = (const float*)d_in[15];
  p.eg_bhh = (const float*)d_in[16];
  // 17..19 attention weights: softmax over length-1 axis == 1 -> provably unused
  p.ln_g   = (const float*)d_in[20];
  p.ln_b   = (const float*)d_in[21];
  p.out_w1 = (const float*)d_in[22];
  p.out_b1 = (const float*)d_in[23];
  p.out_ln_g = (const float*)d_in[24];
  p.out_ln_b = (const float*)d_in[25];
  p.out_w2 = (const float*)d_in[26];
  p.out_b2 = (const float*)d_in[27];

  char* w = (char*)d_ws;
  auto alloc = [&](size_t bytes) { char* r = w; w += (bytes + 255) & ~(size_t)255; return r; };
  float* gix   = (float*)alloc((size_t)8192 * 1536 * 4);   // ~50.3 MB
  float* g_new = (float*)alloc((size_t)2 * NB_ * NH_ * 4);
  float* e_out = (float*)alloc((size_t)2 * NB_ * NH_ * 4);
  float* glob  = (float*)alloc((size_t)NB_ * NSP_ * NH_ * 4);
  float* h1buf = (float*)alloc((size_t)2 * NB_ * NH2_ * 4);
  u32*   flags = (u32*)alloc((size_t)NBLK * 16 * 4);
  u32*   rel   = (u32*)alloc((size_t)NBLK * 16 * 4);
  if ((size_t)(w - (char*)d_ws) > ws_size) return;  // ws too small -> loud failure (zeros)

  gix_kernel<<<dim3(512, 48), dim3(512), 0, stream>>>(p.utt, p.gg_wih, gix);
  init_kernel<<<dim3(64), dim3(256), 0, stream>>>(glob, ig, flags, rel);

  p.gix = gix;
  p.g_new = g_new; p.e_out = e_out; p.glob = glob;
  p.h1buf = h1buf; p.flags = flags; p.rel = rel; p.out = (float*)d_out;

  seq_kernel<<<dim3(NBLK), dim3(256), 0, stream>>>(p);
}

// Round 18
// 23260.054 us; speedup vs baseline: 3.6451x; 1.1964x over previous
//
#include <hip/hip_runtime.h>

typedef __attribute__((ext_vector_type(4))) float f4;
using u32 = unsigned int;
using u64 = unsigned long long;

constexpr int NB_ = 16;    // batch
constexpr int NS_ = 512;   // seq len
constexpr int ND_ = 1024;  // input dim
constexpr int NH_ = 512;   // hidden
constexpr int NSP_ = 8;    // speakers
constexpr int NH2_ = 256;  // head hidden
constexpr int HP = 520;    // padded fp32 LDS row (130 f4)
constexpr int NBLK = 161;  // persistent grid: gg 64 | eg 64 | wb 16 | head 16 | score 1

struct Params {
  const float *utt;
  const float *gg_wih, *gg_whh, *eg_wih, *eg_whh, *out_w1;
  const float *gix;           // precomputed gg x-projection [B*S][1536] fp32
  const float *init_emotion;
  const float *gg_bih, *gg_bhh, *eg_bih, *eg_bhh;
  const float *ln_g, *ln_b, *out_b1, *out_ln_g, *out_ln_b, *out_w2, *out_b2;
  const int *spk;
  float *g_new;      // [2][B][H] raw gg output, parity t&1
  float *e_out;      // [2][B][H] raw eg output, parity te&1
  float *glob;       // [B][SP][H] post-LN (or raw init) global states
  float *h1buf;      // [2][B][H2] relu(e@W1+b1), parity th&1
  u32 *flags;        // [NBLK*16] arrival flags, one 64B line per block
  u32 *rel;          // [NBLK*16] per-block release lines (distributed release)
  float *out;        // [B][S]
};

__device__ __forceinline__ double sigm_d(double x) { return 1.0 / (1.0 + exp(-x)); }
__device__ __forceinline__ double dot4d(f4 a, f4 w) {
  return ((double)a.x * w.x + (double)a.y * w.y) + ((double)a.z * w.z + (double)a.w * w.w);
}

// ---- cross-block plumbing: relaxed agent-scope atomics (bypass per-XCD L2; no flushes) ----
__device__ __forceinline__ void stA1(float* p, float v) {
  __hip_atomic_store(p, v, __ATOMIC_RELAXED, __HIP_MEMORY_SCOPE_AGENT);
}
__device__ __forceinline__ float ldA1(const float* p) {
  return __hip_atomic_load((float*)p, __ATOMIC_RELAXED, __HIP_MEMORY_SCOPE_AGENT);
}
__device__ __forceinline__ void stA2(float* p, float a, float b) {
  union { float f[2]; u64 u; } x; x.f[0] = a; x.f[1] = b;
  __hip_atomic_store((u64*)p, x.u, __ATOMIC_RELAXED, __HIP_MEMORY_SCOPE_AGENT);
}
__device__ __forceinline__ float2 ldA2(const float* p) {
  u64 u = __hip_atomic_load((u64*)p, __ATOMIC_RELAXED, __HIP_MEMORY_SCOPE_AGENT);
  union { u64 u; float f[2]; } x; x.u = u;
  return make_float2(x.f[0], x.f[1]);
}
__device__ __forceinline__ f4 ldA4(const float* p) {
  float2 lo = ldA2(p), hi = ldA2(p + 2);
  f4 v; v.x = lo.x; v.y = lo.y; v.z = hi.x; v.w = hi.y;
  return v;
}

// Barrier v3 — fully distributed: per-block arrival flag (own line, plain sc1 store) +
// per-block RELEASE line (block 0 fans out the epoch, one store per block, parallel threads).
__device__ __forceinline__ void gbar3(u32* flags, u32* rel, int bid, int nb, u32 epoch) {
  __syncthreads();
  const int tid = threadIdx.x;
  if (bid == 0) {
    if (tid > 0 && tid < nb) {
      while (__hip_atomic_load(&flags[(size_t)tid * 16], __ATOMIC_RELAXED, __HIP_MEMORY_SCOPE_AGENT) < epoch)
        __builtin_amdgcn_s_sleep(1);
    }
    __syncthreads();
    if (tid < nb) {
      asm volatile("s_waitcnt vmcnt(0)" ::: "memory");
      __hip_atomic_store(&rel[(size_t)tid * 16], epoch, __ATOMIC_RELAXED, __HIP_MEMORY_SCOPE_AGENT);
    }
  } else {
    if (tid == 0) {
      asm volatile("s_waitcnt vmcnt(0) lgkmcnt(0)" ::: "memory");
      __hip_atomic_store(&flags[(size_t)bid * 16], epoch, __ATOMIC_RELAXED, __HIP_MEMORY_SCOPE_AGENT);
      while (__hip_atomic_load(&rel[(size_t)bid * 16], __ATOMIC_RELAXED, __HIP_MEMORY_SCOPE_AGENT) < epoch)
        __builtin_amdgcn_s_sleep(2);
    }
  }
  __syncthreads();
}

struct __align__(16) Smem {
  float hA[NB_][HP];
  float hB[NB_][HP];
  double red[8][NB_][4];
  double redH[16][NB_];
  double stats[NB_][2];
  double stats2[NB_][2];
  int spk[NB_], spkp[NB_];
};

// block-local per-b stats over sm row: 256 threads = (b 16, kc 16), 32 elems each, shfl-16
__device__ __forceinline__ void row_stats(const float (*h)[HP], double (*st)[2], int tid) {
  int b = tid >> 4, kc = tid & 15;
  double s1 = 0, s2 = 0;
#pragma unroll
  for (int i = 0; i < 32; ++i) {
    double x = (double)h[b][kc + i * 16];
    s1 += x; s2 += x * x;
  }
#pragma unroll
  for (int m = 1; m <= 8; m <<= 1) { s1 += __shfl_xor(s1, m); s2 += __shfl_xor(s2, m); }
  if (kc == 0) {
    double mu = s1 * (1.0 / NH_), var = s2 * (1.0 / NH_) - mu * mu;
    st[b][0] = mu; st[b][1] = 1.0 / sqrt(var + 1e-5);
  }
}

// One pipelined step t: gg(t)|eg(t-1)|wb(t-1)|head(t-2)|score(t-3).
__device__ void step_body(const Params& p, Smem& sm, int t, int bid, int tid) {
  // ---------------- gg(t) (0..63) ----------------
  if (bid < 64) {
    if (t < NS_) {
      const int jj0 = bid * 8;
      if (tid < NB_) {
        sm.spk[tid]  = p.spk[tid * NS_ + t];
        sm.spkp[tid] = (t > 0) ? p.spk[tid * NS_ + t - 1] : -1;
      }
      __syncthreads();
      const float* gprev = p.g_new + (size_t)((t - 1) & 1) * NB_ * NH_;
      for (int idx = tid; idx < NB_ * NH_ / 4; idx += 256) {
        int b = idx >> 7, k = (idx & 127) * 4;
        f4 v = (sm.spk[b] == sm.spkp[b]) ? ldA4(&gprev[b * NH_ + k])
                                         : ldA4(&p.glob[(size_t)(b * NSP_ + sm.spk[b]) * NH_ + k]);
        *(f4*)&sm.hA[b][k] = v;
      }
      __syncthreads();
      row_stats(sm.hA, sm.stats, tid);
      __syncthreads();
      for (int idx = tid; idx < NB_ * NH_ / 4; idx += 256) {
        int b = idx >> 7, k = (idx & 127) * 4;
        if (sm.spk[b] == sm.spkp[b]) {
          f4 pv = *(f4*)&sm.hA[b][k];
          f4 g4 = *(const f4*)&p.ln_g[k], b4 = *(const f4*)&p.ln_b[k];
          double mu = sm.stats[b][0], rs = sm.stats[b][1];
          f4 v;
          v.x = (float)(((double)pv.x - mu) * rs * g4.x + b4.x);
          v.y = (float)(((double)pv.y - mu) * rs * g4.y + b4.y);
          v.z = (float)(((double)pv.z - mu) * rs * g4.z + b4.z);
          v.w = (float)(((double)pv.w - mu) * rs * g4.w + b4.w);
          *(f4*)&sm.hA[b][k] = v;
        }
      }
      __syncthreads();
      {
        int jj = tid >> 5, kc = tid & 31, j = jj0 + jj;
        const f4* Wr_w = (const f4*)(p.gg_wih + (size_t)j * 1536 + 1024);
        const f4* Wz_w = (const f4*)(p.gg_wih + (size_t)(512 + j) * 1536 + 1024);
        const f4* Wn_w = (const f4*)(p.gg_wih + (size_t)(1024 + j) * 1536 + 1024);
        const f4* Wr_h = (const f4*)(p.gg_whh + (size_t)j * 512);
        const f4* Wz_h = (const f4*)(p.gg_whh + (size_t)(512 + j) * 512);
        const f4* Wn_h = (const f4*)(p.gg_whh + (size_t)(1024 + j) * 512);
        const f4* H = (const f4*)&sm.hA[0][0];
        // pass A: r,z gates — ROLLED i-loop (spill-free codegen)
        {
          double ar[NB_] = {}, az[NB_] = {};
#pragma unroll 1
          for (int i = 0; i < 8; ++i) {
            int q = kc + 32 * i;
            f4 wr, wz; int hq;
            if (i < 4) { wr = Wr_w[q]; wz = Wz_w[q]; hq = q; }
            else       { wr = Wr_h[q - 128]; wz = Wz_h[q - 128]; hq = q - 128; }
#pragma unroll
            for (int b = 0; b < NB_; ++b) {
              f4 a = H[b * 130 + hq];
              ar[b] += dot4d(a, wr); az[b] += dot4d(a, wz);
            }
          }
#pragma unroll
          for (int b = 0; b < NB_; ++b) {
            double r = ar[b], z = az[b];
#pragma unroll
            for (int m = 1; m <= 16; m <<= 1) { r += __shfl_xor(r, m); z += __shfl_xor(z, m); }
            if (kc == 0) { sm.red[jj][b][0] = r; sm.red[jj][b][1] = z; }
          }
        }
        // pass B: n gate — ROLLED i-loop
        {
          double apn[NB_] = {}, aph[NB_] = {};
#pragma unroll 1
          for (int i = 0; i < 8; ++i) {
            int q = kc + 32 * i;
            f4 wn; int hq;
            if (i < 4) { wn = Wn_w[q]; hq = q; }
            else       { wn = Wn_h[q - 128]; hq = q - 128; }
#pragma unroll
            for (int b = 0; b < NB_; ++b) {
              f4 a = H[b * 130 + hq];
              if (i < 4) apn[b] += dot4d(a, wn); else aph[b] += dot4d(a, wn);
            }
          }
#pragma unroll
          for (int b = 0; b < NB_; ++b) {
            double pn = apn[b], ph = aph[b];
#pragma unroll
            for (int m = 1; m <= 16; m <<= 1) { pn += __shfl_xor(pn, m); ph += __shfl_xor(ph, m); }
            if (kc == 0) { sm.red[jj][b][2] = pn; sm.red[jj][b][3] = ph; }
          }
        }
      }
      __syncthreads();
      if (tid < 128) {
        int b = tid >> 3, jj = tid & 7, j = jj0 + jj;
        const double* rd = sm.red[jj][b];
        const float* gx = p.gix + (size_t)(b * NS_ + t) * 1536;
        double r = sigm_d(rd[0] + (double)gx[j] + (double)p.gg_bih[j] + (double)p.gg_bhh[j]);
        double z = sigm_d(rd[1] + (double)gx[512 + j] + (double)p.gg_bih[512 + j] + (double)p.gg_bhh[512 + j]);
        double inn = rd[2] + (double)gx[1024 + j] + (double)p.gg_bih[1024 + j];
        double hn  = rd[3] + (double)p.gg_bhh[1024 + j];
        double n = tanh(inn + r * hn);
        double hp = (double)sm.hA[b][j];
        double hv = (1.0 - z) * n + z * hp;
        stA1(&p.g_new[(size_t)(t & 1) * NB_ * NH_ + b * NH_ + j], (float)hv);
      }
    }
  }
  // ---------------- eg(t-1) (64..127) ----------------
  else if (bid < 128) {
    if (t >= 1 && t <= NS_) {
      const int te = t - 1;
      const int jj0 = (bid - 64) * 8;
      const float* eprev = p.e_out + (size_t)((te - 1) & 1) * NB_ * NH_;
      const float* gcur  = p.g_new + (size_t)(te & 1) * NB_ * NH_;
      for (int idx = tid; idx < NB_ * NH_ / 2; idx += 256) {
        int half = idx >= NB_ * NH_ / 4;
        int r4 = idx & (NB_ * NH_ / 4 - 1);
        int b = r4 >> 7, k = (r4 & 127) * 4;
        if (!half) {
          f4 v = (te == 0) ? *(const f4*)&p.init_emotion[k] : ldA4(&eprev[b * NH_ + k]);
          *(f4*)&sm.hA[b][k] = v;
        } else {
          *(f4*)&sm.hB[b][k] = ldA4(&gcur[b * NH_ + k]);
        }
      }
      __syncthreads();
      {
        int b = tid >> 4, kc = tid & 15;
        double a1 = 0, a2 = 0, b1 = 0, b2 = 0;
#pragma unroll
        for (int i = 0; i < 32; ++i) {
          double xa = (double)sm.hA[b][kc + i * 16];
          double xb = (double)sm.hB[b][kc + i * 16];
          a1 += xa; a2 += xa * xa; b1 += xb; b2 += xb * xb;
        }
#pragma unroll
        for (int m = 1; m <= 8; m <<= 1) {
          a1 += __shfl_xor(a1, m); a2 += __shfl_xor(a2, m);
          b1 += __shfl_xor(b1, m); b2 += __shfl_xor(b2, m);
        }
        if (kc == 0) {
          double mu = a1 * (1.0 / NH_), var = a2 * (1.0 / NH_) - mu * mu;
          sm.stats[b][0] = mu; sm.stats[b][1] = 1.0 / sqrt(var + 1e-5);
          mu = b1 * (1.0 / NH_); var = b2 * (1.0 / NH_) - mu * mu;
          sm.stats2[b][0] = mu; sm.stats2[b][1] = 1.0 / sqrt(var + 1e-5);
        }
      }
      __syncthreads();
      for (int idx = tid; idx < NB_ * NH_ / 2; idx += 256) {
        int half = idx >= NB_ * NH_ / 4;
        int r4 = idx & (NB_ * NH_ / 4 - 1);
        int b = r4 >> 7, k = (r4 & 127) * 4;
        f4 g4 = *(const f4*)&p.ln_g[k], b4 = *(const f4*)&p.ln_b[k];
        if (!half) {
          if (te > 0) {
            f4 pv = *(f4*)&sm.hA[b][k];
            double mu = sm.stats[b][0], rs = sm.stats[b][1];
            f4 v;
            v.x = (float)(((double)pv.x - mu) * rs * g4.x + b4.x);
            v.y = (float)(((double)pv.y - mu) * rs * g4.y + b4.y);
            v.z = (float)(((double)pv.z - mu) * rs * g4.z + b4.z);
            v.w = (float)(((double)pv.w - mu) * rs * g4.w + b4.w);
            *(f4*)&sm.hA[b][k] = v;
          }
        } else {
          f4 pv = *(f4*)&sm.hB[b][k];
          double mu = sm.stats2[b][0], rs = sm.stats2[b][1];
          f4 v;
          v.x = (float)(((double)pv.x - mu) * rs * g4.x + b4.x);
          v.y = (float)(((double)pv.y - mu) * rs * g4.y + b4.y);
          v.z = (float)(((double)pv.z - mu) * rs * g4.z + b4.z);
          v.w = (float)(((double)pv.w - mu) * rs * g4.w + b4.w);
          *(f4*)&sm.hB[b][k] = v;
        }
      }
      __syncthreads();
      {
        int jj = tid >> 5, kc = tid & 31, j = jj0 + jj;
        const f4* Wr_w = (const f4*)(p.eg_wih + (size_t)j * 1024);
        const f4* Wz_w = (const f4*)(p.eg_wih + (size_t)(512 + j) * 1024);
        const f4* Wn_w = (const f4*)(p.eg_wih + (size_t)(1024 + j) * 1024);
        const f4* Wr_h = (const f4*)(p.eg_whh + (size_t)j * 512);
        const f4* Wz_h = (const f4*)(p.eg_whh + (size_t)(512 + j) * 512);
        const f4* Wn_h = (const f4*)(p.eg_whh + (size_t)(1024 + j) * 512);
        const f4* HA = (const f4*)&sm.hA[0][0];
        const f4* HB = (const f4*)&sm.hB[0][0];
        // pass A: r,z — ROLLED i-loop
        {
          double ar[NB_] = {}, az[NB_] = {};
#pragma unroll 1
          for (int i = 0; i < 12; ++i) {
            int q = kc + 32 * i;
            f4 wr, wz; const f4* Ab; int hq;
            if (i < 8) { wr = Wr_w[q]; wz = Wz_w[q]; }
            else       { wr = Wr_h[q - 256]; wz = Wz_h[q - 256]; }
            if (i < 4)      { Ab = HA; hq = q; }
            else if (i < 8) { Ab = HB; hq = q - 128; }
            else            { Ab = HA; hq = q - 256; }
#pragma unroll
            for (int b = 0; b < NB_; ++b) {
              f4 a = Ab[b * 130 + hq];
              ar[b] += dot4d(a, wr); az[b] += dot4d(a, wz);
            }
          }
#pragma unroll
          for (int b = 0; b < NB_; ++b) {
            double r = ar[b], z = az[b];
#pragma unroll
            for (int m = 1; m <= 16; m <<= 1) { r += __shfl_xor(r, m); z += __shfl_xor(z, m); }
            if (kc == 0) { sm.red[jj][b][0] = r; sm.red[jj][b][1] = z; }
          }
        }
        // pass B: n — ROLLED i-loop
        {
          double apn[NB_] = {}, aph[NB_] = {};
#pragma unroll 1
          for (int i = 0; i < 12; ++i) {
            int q = kc + 32 * i;
            f4 wn; const f4* Ab; int hq;
            if (i < 8) wn = Wn_w[q]; else wn = Wn_h[q - 256];
            if (i < 4)      { Ab = HA; hq = q; }
            else if (i < 8) { Ab = HB; hq = q - 128; }
            else            { Ab = HA; hq = q - 256; }
#pragma unroll
            for (int b = 0; b < NB_; ++b) {
              f4 a = Ab[b * 130 + hq];
              if (i < 8) apn[b] += dot4d(a, wn); else aph[b] += dot4d(a, wn);
            }
          }
#pragma unroll
          for (int b = 0; b < NB_; ++b) {
            double pn = apn[b], ph = aph[b];
#pragma unroll
            for (int m = 1; m <= 16; m <<= 1) { pn += __shfl_xor(pn, m); ph += __shfl_xor(ph, m); }
            if (kc == 0) { sm.red[jj][b][2] = pn; sm.red[jj][b][3] = ph; }
          }
        }
      }
      __syncthreads();
      if (tid < 128) {
        int b = tid >> 3, jj = tid & 7, j = jj0 + jj;
        const double* rd = sm.red[jj][b];
        double r = sigm_d(rd[0] + (double)p.eg_bih[j] + (double)p.eg_bhh[j]);
        double z = sigm_d(rd[1] + (double)p.eg_bih[512 + j] + (double)p.eg_bhh[512 + j]);
        double inn = rd[2] + (double)p.eg_bih[1024 + j];
        double hn  = rd[3] + (double)p.eg_bhh[1024 + j];
        double n = tanh(inn + r * hn);
        double hp = (double)sm.hA[b][j];
        double hv = (1.0 - z) * n + z * hp;
        stA1(&p.e_out[(size_t)(te & 1) * NB_ * NH_ + b * NH_ + j], (float)hv);
      }
    }
  }
  // ---------------- wb(t-1): one block per b (128..143) ----------------
  else if (bid < 144) {
    if (t >= 1 && t <= NS_) {
      int b = bid - 128, tw = t - 1;
      int spv = p.spk[b * NS_ + tw];
      const float* gsrc = p.g_new + (size_t)(tw & 1) * NB_ * NH_;
      float2 gv = ldA2(&gsrc[b * NH_ + tid * 2]);
      double s1 = (double)gv.x + (double)gv.y;
      double s2 = (double)gv.x * (double)gv.x + (double)gv.y * (double)gv.y;
#pragma unroll
      for (int m = 1; m <= 32; m <<= 1) { s1 += __shfl_xor(s1, m); s2 += __shfl_xor(s2, m); }
      int wid = tid >> 6;
      if ((tid & 63) == 0) { sm.redH[0][wid] = s1; sm.redH[1][wid] = s2; }
      __syncthreads();
      if (tid == 0) {
        double ts1 = sm.redH[0][0] + sm.redH[0][1] + sm.redH[0][2] + sm.redH[0][3];
        double ts2 = sm.redH[1][0] + sm.redH[1][1] + sm.redH[1][2] + sm.redH[1][3];
        double mu = ts1 * (1.0 / NH_), var = ts2 * (1.0 / NH_) - mu * mu;
        sm.stats[0][0] = mu; sm.stats[0][1] = 1.0 / sqrt(var + 1e-5);
      }
      __syncthreads();
      double mu = sm.stats[0][0], rs = sm.stats[0][1];
      float* gd = p.glob + (size_t)(b * NSP_ + spv) * NH_;
      int k2 = tid * 2;
      double o0 = ((double)gv.x - mu) * rs * p.ln_g[k2] + p.ln_b[k2];
      double o1 = ((double)gv.y - mu) * rs * p.ln_g[k2 + 1] + p.ln_b[k2 + 1];
      stA2(&gd[k2], (float)o0, (float)o1);
    }
  }
  // ---------------- head(t-2) (144..159) ----------------
  else if (bid < 160) {
    if (t >= 2 && t <= NS_ + 1) {
      int th = t - 2, ct = bid - 144;
      const float* er = p.e_out + (size_t)(th & 1) * NB_ * NH_;
      for (int idx = tid; idx < NB_ * NH_ / 4; idx += 256) {
        int b = idx >> 7, k = (idx & 127) * 4;
        *(f4*)&sm.hA[b][k] = ldA4(&er[b * NH_ + k]);
      }
      __syncthreads();
      {
        int ci = tid >> 4, kc = tid & 15, c = ct * 16 + ci;
        const f4* W = (const f4*)(p.out_w1 + (size_t)c * 512);
        const f4* H = (const f4*)&sm.hA[0][0];
        double acc[NB_] = {};
#pragma unroll 1
        for (int i = 0; i < 8; ++i) {
          int q = kc + 16 * i;
          f4 w = W[q];
#pragma unroll
          for (int b = 0; b < NB_; ++b) acc[b] += dot4d(H[b * 130 + q], w);
        }
#pragma unroll
        for (int b = 0; b < NB_; ++b) {
          double v = acc[b];
#pragma unroll
          for (int m = 1; m <= 8; m <<= 1) v += __shfl_xor(v, m);
          if (kc == 0) sm.redH[ci][b] = v;
        }
      }
      __syncthreads();
      {
        int b = tid >> 4, ci = tid & 15, c = ct * 16 + ci;
        double h1 = sm.redH[ci][b] + (double)p.out_b1[c];
        stA1(&p.h1buf[(size_t)(th & 1) * NB_ * NH2_ + b * NH2_ + c], (float)fmax(h1, 0.0));
      }
    }
  }
  // ---------------- score(t-3) (160) ----------------
  else {
    if (t >= 3 && t <= NS_ + 2) {
      int ts = t - 3;
      int b = tid >> 4, cg = tid & 15;
      const float* h1p = p.h1buf + (size_t)(ts & 1) * NB_ * NH2_;
      double s1 = 0, s2 = 0;
      float hv[16];
#pragma unroll
      for (int i = 0; i < 16; ++i) {
        float v = ldA1(&h1p[b * NH2_ + cg * 16 + i]);
        hv[i] = v; s1 += (double)v; s2 += (double)v * (double)v;
      }
#pragma unroll
      for (int m = 1; m <= 8; m <<= 1) { s1 += __shfl_xor(s1, m); s2 += __shfl_xor(s2, m); }
      double mu = s1 * (1.0 / NH2_), var = s2 * (1.0 / NH2_) - mu * mu, rstd = 1.0 / sqrt(var + 1e-5);
      double d = 0;
#pragma unroll
      for (int i = 0; i < 16; ++i) {
        int c = cg * 16 + i;
        d += (((double)hv[i] - mu) * rstd * p.out_ln_g[c] + (double)p.out_ln_b[c]) * (double)p.out_w2[c];
      }
#pragma unroll
      for (int m = 1; m <= 8; m <<= 1) d += __shfl_xor(d, m);
      if (cg == 0) p.out[b * NS_ + ts] = (float)sigm_d(d + (double)p.out_b2[0]);
    }
  }
}

__global__ __launch_bounds__(256, 1) void seq_kernel(Params p) {
  __shared__ Smem sm;
  const int bid = blockIdx.x, tid = threadIdx.x;
  for (int t = 0; t <= NS_ + 2; ++t) {
    step_body(p, sm, t, bid, tid);
    gbar3(p.flags, p.rel, bid, gridDim.x, (u32)(t + 1));
  }
}

// gg x-projection precompute: gix[bs][row] = sum_k utt[bs][k] * gg_wih[row][k], k<1024 (fp64)
__global__ __launch_bounds__(512) void gix_kernel(const float* utt, const float* ggw, float* gix) {
  __shared__ float xs[16][1028];
  const int tid = threadIdx.x;
  long bs0 = (long)blockIdx.x * 16;
  for (int i = tid; i < 16 * 256; i += 512) {
    int bb = i >> 8, kf = i & 255;
    *(f4*)&xs[bb][kf * 4] = *(const f4*)(utt + (bs0 + bb) * 1024 + kf * 4);
  }
  __syncthreads();
  int R = blockIdx.y * 32 + (tid >> 4);
  int bi = tid & 15;
  const f4* w4 = (const f4*)(ggw + (size_t)R * 1536);
  const f4* x4 = (const f4*)&xs[bi][0];
  double acc = 0;
  for (int k = 0; k < 256; ++k) acc += dot4d(x4[k], w4[k]);
  gix[(size_t)(bs0 + bi) * 1536 + R] = (float)acc;
}

__global__ void init_kernel(float* glob, const float* init_global, u32* flags, u32* rel) {
  long stride = (long)gridDim.x * blockDim.x;
  long t0 = (long)blockIdx.x * blockDim.x + threadIdx.x;
  for (long i = t0; i < (long)NB_ * NSP_ * NH_; i += stride) {
    int sp = ((int)i >> 9) & (NSP_ - 1);
    int k = (int)i & (NH_ - 1);
    glob[i] = init_global[sp * NH_ + k];
  }
  for (long i = t0; i < NBLK * 16; i += stride) { flags[i] = 0u; rel[i] = 0u; }
}

extern "C" void kernel_launch(void* const* d_in, const int* in_sizes, int n_in,
                              void* d_out, int out_size, void* d_ws, size_t ws_size,
                              hipStream_t stream) {
  (void)in_sizes; (void)n_in; (void)out_size;
  Params p;
  p.utt    = (const float*)d_in[0];
  p.spk    = (const int*)d_in[1];
  // d_in[2] init_party: DEAD (party GRU feeds only itself, never the output path)
  const float* ig = (const float*)d_in[3];
  p.init_emotion = (const float*)d_in[4];
  // d_in[5..8] pg_*: DEAD (party GRU)
  p.gg_wih = (const float*)d_in[9];
  p.gg_whh = (const float*)d_in[10];
  p.gg_bih = (const float*)d_in[11];
  p.gg_bhh = (const float*)d_in[12];
  p.eg_wih = (const float*)d_in[13];
  p.eg_whh = (const float*)d_in[14];
  p.eg_bih = (const float*)d_in[15];
  p.eg_bhh = (const float*)d_in[16];
  // 17..19 attention weights: softmax over length-1 axis == 1 -> provably unused
  p.ln_g   = (const float*)d_in[20];
  p.ln_b   = (const float*)d_in[21];
  p.out_w1 = (const float*)d_in[22];
  p.out_b1 = (const float*)d_in[23];
  p.out_ln_g = (const float*)d_in[24];
  p.out_ln_b = (const float*)d_in[25];
  p.out_w2 = (const float*)d_in[26];
  p.out_b2 = (const float*)d_in[27];

  char* w = (char*)d_ws;
  auto alloc = [&](size_t bytes) { char* r = w; w += (bytes + 255) & ~(size_t)255; return r; };
  float* gix   = (float*)alloc((size_t)8192 * 1536 * 4);   // ~50.3 MB
  float* g_new = (float*)alloc((size_t)2 * NB_ * NH_ * 4);
  float* e_out = (float*)alloc((size_t)2 * NB_ * NH_ * 4);
  float* glob  = (float*)alloc((size_t)NB_ * NSP_ * NH_ * 4);
  float* h1buf = (float*)alloc((size_t)2 * NB_ * NH2_ * 4);
  u32*   flags = (u32*)alloc((size_t)NBLK * 16 * 4);
  u32*   rel   = (u32*)alloc((size_t)NBLK * 16 * 4);
  if ((size_t)(w - (char*)d_ws) > ws_size) return;  // ws too small -> loud failure (zeros)

  gix_kernel<<<dim3(512, 48), dim3(512), 0, stream>>>(p.utt, p.gg_wih, gix);
  init_kernel<<<dim3(64), dim3(256), 0, stream>>>(glob, ig, flags, rel);

  p.gix = gix;
  p.g_new = g_new; p.e_out = e_out; p.glob = glob;
  p.h1buf = h1buf; p.flags = flags; p.rel = rel; p.out = (float*)d_out;

  seq_kernel<<<dim3(NBLK), dim3(256), 0, stream>>>(p);
}

// Round 19
// 22511.029 us; speedup vs baseline: 3.7664x; 1.0333x over previous
//
#include <hip/hip_runtime.h>

typedef __attribute__((ext_vector_type(4))) float f4;
using u32 = unsigned int;
using u64 = unsigned long long;

constexpr int NB_ = 16;    // total batch
constexpr int BP_ = 8;     // batch per domain
constexpr int NS_ = 512;   // seq len
constexpr int ND_ = 1024;  // input dim
constexpr int NH_ = 512;   // hidden
constexpr int NSP_ = 8;    // speakers
constexpr int NH2_ = 256;  // head hidden
constexpr int HP = 520;    // padded fp32 LDS row (130 f4)
constexpr int DBLK = 81;   // blocks per domain: gg 32 | eg 32 | wb 8 | head 8 | score 1
constexpr int NBLK = 162;  // two independent domains

struct Params {
  const float *utt;
  const float *gg_wih, *gg_whh, *eg_wih, *eg_whh, *out_w1;
  const float *gix;           // precomputed gg x-projection [B*S][1536] fp32
  const float *init_emotion;
  const float *gg_bih, *gg_bhh, *eg_bih, *eg_bhh;
  const float *ln_g, *ln_b, *out_b1, *out_ln_g, *out_ln_b, *out_w2, *out_b2;
  const int *spk;
  float *g_new;      // [2][B][H] raw gg output, parity t&1
  float *e_out;      // [2][B][H] raw eg output, parity te&1
  float *glob;       // [B][SP][H] post-LN (or raw init) global states
  float *h1buf;      // [2][B][H2] relu(e@W1+b1), parity th&1
  u32 *flags;        // [2][DBLK*16] arrival flags, one 64B line per block
  u32 *rel;          // [2][DBLK*16] per-block release lines
  float *out;        // [B][S]
};

__device__ __forceinline__ double sigm_d(double x) { return 1.0 / (1.0 + exp(-x)); }
__device__ __forceinline__ double dot4d(f4 a, f4 w) {
  return ((double)a.x * w.x + (double)a.y * w.y) + ((double)a.z * w.z + (double)a.w * w.w);
}

// ---- cross-block plumbing: relaxed agent-scope atomics (bypass per-XCD L2; no flushes) ----
__device__ __forceinline__ void stA1(float* p, float v) {
  __hip_atomic_store(p, v, __ATOMIC_RELAXED, __HIP_MEMORY_SCOPE_AGENT);
}
__device__ __forceinline__ float ldA1(const float* p) {
  return __hip_atomic_load((float*)p, __ATOMIC_RELAXED, __HIP_MEMORY_SCOPE_AGENT);
}
__device__ __forceinline__ void stA2(float* p, float a, float b) {
  union { float f[2]; u64 u; } x; x.f[0] = a; x.f[1] = b;
  __hip_atomic_store((u64*)p, x.u, __ATOMIC_RELAXED, __HIP_MEMORY_SCOPE_AGENT);
}
__device__ __forceinline__ float2 ldA2(const float* p) {
  u64 u = __hip_atomic_load((u64*)p, __ATOMIC_RELAXED, __HIP_MEMORY_SCOPE_AGENT);
  union { u64 u; float f[2]; } x; x.u = u;
  return make_float2(x.f[0], x.f[1]);
}
__device__ __forceinline__ f4 ldA4(const float* p) {
  float2 lo = ldA2(p), hi = ldA2(p + 2);
  f4 v; v.x = lo.x; v.y = lo.y; v.z = hi.x; v.w = hi.y;
  return v;
}

// Distributed flag barrier over one domain's DBLK blocks (R17-validated pattern).
__device__ __forceinline__ void gbar3(u32* flags, u32* rel, int lid, int nb, u32 epoch) {
  __syncthreads();
  const int tid = threadIdx.x;
  if (lid == 0) {
    if (tid > 0 && tid < nb) {
      while (__hip_atomic_load(&flags[(size_t)tid * 16], __ATOMIC_RELAXED, __HIP_MEMORY_SCOPE_AGENT) < epoch)
        __builtin_amdgcn_s_sleep(1);
    }
    __syncthreads();
    if (tid < nb) {
      asm volatile("s_waitcnt vmcnt(0)" ::: "memory");
      __hip_atomic_store(&rel[(size_t)tid * 16], epoch, __ATOMIC_RELAXED, __HIP_MEMORY_SCOPE_AGENT);
    }
  } else {
    if (tid == 0) {
      asm volatile("s_waitcnt vmcnt(0) lgkmcnt(0)" ::: "memory");
      __hip_atomic_store(&flags[(size_t)lid * 16], epoch, __ATOMIC_RELAXED, __HIP_MEMORY_SCOPE_AGENT);
      while (__hip_atomic_load(&rel[(size_t)lid * 16], __ATOMIC_RELAXED, __HIP_MEMORY_SCOPE_AGENT) < epoch)
        __builtin_amdgcn_s_sleep(2);
    }
  }
  __syncthreads();
}

struct __align__(16) Smem {
  float hA[BP_][HP];
  float hB[BP_][HP];
  double red[16][BP_][4];
  double redH[32][BP_];
  double stats[BP_][2];
  double stats2[BP_][2];
  int spk[BP_], spkp[BP_];
};

// block-local per-b stats: 256 threads = (b 8, kc 32), 16 elems each, shfl over 32 lanes
__device__ __forceinline__ void row_stats8(const float (*h)[HP], double (*st)[2], int tid) {
  int b = tid >> 5, kc = tid & 31;
  double s1 = 0, s2 = 0;
#pragma unroll
  for (int i = 0; i < 16; ++i) {
    double x = (double)h[b][kc + i * 32];
    s1 += x; s2 += x * x;
  }
#pragma unroll
  for (int m = 1; m <= 16; m <<= 1) { s1 += __shfl_xor(s1, m); s2 += __shfl_xor(s2, m); }
  if (kc == 0) {
    double mu = s1 * (1.0 / NH_), var = s2 * (1.0 / NH_) - mu * mu;
    st[b][0] = mu; st[b][1] = 1.0 / sqrt(var + 1e-5);
  }
}

// One pipelined step t within domain d (8 dialogues b0=d*8..+8):
// gg(t)|eg(t-1)|wb(t-1)|head(t-2)|score(t-3).
__device__ void step_body(const Params& p, Smem& sm, int t, int d, int lid, int tid) {
  const int b0 = d * BP_;
  // ---------------- gg(t) (lid 0..31, 16 j each) ----------------
  if (lid < 32) {
    if (t < NS_) {
      const int jj0 = lid * 16;
      if (tid < BP_) {
        sm.spk[tid]  = p.spk[(b0 + tid) * NS_ + t];
        sm.spkp[tid] = (t > 0) ? p.spk[(b0 + tid) * NS_ + t - 1] : -1;
      }
      __syncthreads();
      const float* gprev = p.g_new + (size_t)((t - 1) & 1) * NB_ * NH_;
      for (int idx = tid; idx < BP_ * NH_ / 4; idx += 256) {
        int b = idx >> 7, k = (idx & 127) * 4;
        f4 v = (sm.spk[b] == sm.spkp[b])
                   ? ldA4(&gprev[(b0 + b) * NH_ + k])
                   : ldA4(&p.glob[(size_t)((b0 + b) * NSP_ + sm.spk[b]) * NH_ + k]);
        *(f4*)&sm.hA[b][k] = v;
      }
      __syncthreads();
      row_stats8(sm.hA, sm.stats, tid);
      __syncthreads();
      for (int idx = tid; idx < BP_ * NH_ / 4; idx += 256) {
        int b = idx >> 7, k = (idx & 127) * 4;
        if (sm.spk[b] == sm.spkp[b]) {
          f4 pv = *(f4*)&sm.hA[b][k];
          f4 g4 = *(const f4*)&p.ln_g[k], b4 = *(const f4*)&p.ln_b[k];
          double mu = sm.stats[b][0], rs = sm.stats[b][1];
          f4 v;
          v.x = (float)(((double)pv.x - mu) * rs * g4.x + b4.x);
          v.y = (float)(((double)pv.y - mu) * rs * g4.y + b4.y);
          v.z = (float)(((double)pv.z - mu) * rs * g4.z + b4.z);
          v.w = (float)(((double)pv.w - mu) * rs * g4.w + b4.w);
          *(f4*)&sm.hA[b][k] = v;
        }
      }
      __syncthreads();
      {
        int jj = tid >> 4, kc = tid & 15, j = jj0 + jj;
        const f4* Wr_w = (const f4*)(p.gg_wih + (size_t)j * 1536 + 1024);
        const f4* Wz_w = (const f4*)(p.gg_wih + (size_t)(512 + j) * 1536 + 1024);
        const f4* Wn_w = (const f4*)(p.gg_wih + (size_t)(1024 + j) * 1536 + 1024);
        const f4* Wr_h = (const f4*)(p.gg_whh + (size_t)j * 512);
        const f4* Wz_h = (const f4*)(p.gg_whh + (size_t)(512 + j) * 512);
        const f4* Wn_h = (const f4*)(p.gg_whh + (size_t)(1024 + j) * 512);
        const f4* H = (const f4*)&sm.hA[0][0];
        // pass A: r,z — ROLLED i-loop (spill-free)
        {
          double ar[BP_] = {}, az[BP_] = {};
#pragma unroll 1
          for (int i = 0; i < 16; ++i) {
            int q = kc + 16 * i;
            f4 wr, wz; int hq;
            if (i < 8) { wr = Wr_w[q]; wz = Wz_w[q]; hq = q; }
            else       { hq = q - 128; wr = Wr_h[hq]; wz = Wz_h[hq]; }
#pragma unroll
            for (int b = 0; b < BP_; ++b) {
              f4 a = H[b * 130 + hq];
              ar[b] += dot4d(a, wr); az[b] += dot4d(a, wz);
            }
          }
#pragma unroll
          for (int b = 0; b < BP_; ++b) {
            double r = ar[b], z = az[b];
#pragma unroll
            for (int m = 1; m <= 8; m <<= 1) { r += __shfl_xor(r, m); z += __shfl_xor(z, m); }
            if (kc == 0) { sm.red[jj][b][0] = r; sm.red[jj][b][1] = z; }
          }
        }
        // pass B: n — ROLLED i-loop
        {
          double apn[BP_] = {}, aph[BP_] = {};
#pragma unroll 1
          for (int i = 0; i < 16; ++i) {
            int q = kc + 16 * i;
            f4 wn; int hq;
            if (i < 8) { wn = Wn_w[q]; hq = q; }
            else       { hq = q - 128; wn = Wn_h[hq]; }
#pragma unroll
            for (int b = 0; b < BP_; ++b) {
              f4 a = H[b * 130 + hq];
              if (i < 8) apn[b] += dot4d(a, wn); else aph[b] += dot4d(a, wn);
            }
          }
#pragma unroll
          for (int b = 0; b < BP_; ++b) {
            double pn = apn[b], ph = aph[b];
#pragma unroll
            for (int m = 1; m <= 8; m <<= 1) { pn += __shfl_xor(pn, m); ph += __shfl_xor(ph, m); }
            if (kc == 0) { sm.red[jj][b][2] = pn; sm.red[jj][b][3] = ph; }
          }
        }
      }
      __syncthreads();
      if (tid < 128) {
        int b = tid >> 4, jj = tid & 15, j = jj0 + jj;
        const double* rd = sm.red[jj][b];
        const float* gx = p.gix + (size_t)((b0 + b) * NS_ + t) * 1536;
        double r = sigm_d(rd[0] + (double)gx[j] + (double)p.gg_bih[j] + (double)p.gg_bhh[j]);
        double z = sigm_d(rd[1] + (double)gx[512 + j] + (double)p.gg_bih[512 + j] + (double)p.gg_bhh[512 + j]);
        double inn = rd[2] + (double)gx[1024 + j] + (double)p.gg_bih[1024 + j];
        double hn  = rd[3] + (double)p.gg_bhh[1024 + j];
        double n = tanh(inn + r * hn);
        double hp = (double)sm.hA[b][j];
        double hv = (1.0 - z) * n + z * hp;
        stA1(&p.g_new[(size_t)(t & 1) * NB_ * NH_ + (b0 + b) * NH_ + j], (float)hv);
      }
    }
  }
  // ---------------- eg(t-1) (lid 32..63, 16 j each) ----------------
  else if (lid < 64) {
    if (t >= 1 && t <= NS_) {
      const int te = t - 1;
      const int jj0 = (lid - 32) * 16;
      const float* eprev = p.e_out + (size_t)((te - 1) & 1) * NB_ * NH_;
      const float* gcur  = p.g_new + (size_t)(te & 1) * NB_ * NH_;
      for (int idx = tid; idx < BP_ * NH_ / 2; idx += 256) {
        int half = idx >= BP_ * NH_ / 4;
        int r4 = idx & (BP_ * NH_ / 4 - 1);
        int b = r4 >> 7, k = (r4 & 127) * 4;
        if (!half) {
          f4 v = (te == 0) ? *(const f4*)&p.init_emotion[k] : ldA4(&eprev[(b0 + b) * NH_ + k]);
          *(f4*)&sm.hA[b][k] = v;
        } else {
          *(f4*)&sm.hB[b][k] = ldA4(&gcur[(b0 + b) * NH_ + k]);
        }
      }
      __syncthreads();
      {
        int b = tid >> 5, kc = tid & 31;
        double a1 = 0, a2 = 0, b1 = 0, b2 = 0;
#pragma unroll
        for (int i = 0; i < 16; ++i) {
          double xa = (double)sm.hA[b][kc + i * 32];
          double xb = (double)sm.hB[b][kc + i * 32];
          a1 += xa; a2 += xa * xa; b1 += xb; b2 += xb * xb;
        }
#pragma unroll
        for (int m = 1; m <= 16; m <<= 1) {
          a1 += __shfl_xor(a1, m); a2 += __shfl_xor(a2, m);
          b1 += __shfl_xor(b1, m); b2 += __shfl_xor(b2, m);
        }
        if (kc == 0) {
          double mu = a1 * (1.0 / NH_), var = a2 * (1.0 / NH_) - mu * mu;
          sm.stats[b][0] = mu; sm.stats[b][1] = 1.0 / sqrt(var + 1e-5);
          mu = b1 * (1.0 / NH_); var = b2 * (1.0 / NH_) - mu * mu;
          sm.stats2[b][0] = mu; sm.stats2[b][1] = 1.0 / sqrt(var + 1e-5);
        }
      }
      __syncthreads();
      for (int idx = tid; idx < BP_ * NH_ / 2; idx += 256) {
        int half = idx >= BP_ * NH_ / 4;
        int r4 = idx & (BP_ * NH_ / 4 - 1);
        int b = r4 >> 7, k = (r4 & 127) * 4;
        f4 g4 = *(const f4*)&p.ln_g[k], b4 = *(const f4*)&p.ln_b[k];
        if (!half) {
          if (te > 0) {
            f4 pv = *(f4*)&sm.hA[b][k];
            double mu = sm.stats[b][0], rs = sm.stats[b][1];
            f4 v;
            v.x = (float)(((double)pv.x - mu) * rs * g4.x + b4.x);
            v.y = (float)(((double)pv.y - mu) * rs * g4.y + b4.y);
            v.z = (float)(((double)pv.z - mu) * rs * g4.z + b4.z);
            v.w = (float)(((double)pv.w - mu) * rs * g4.w + b4.w);
            *(f4*)&sm.hA[b][k] = v;
          }
        } else {
          f4 pv = *(f4*)&sm.hB[b][k];
          double mu = sm.stats2[b][0], rs = sm.stats2[b][1];
          f4 v;
          v.x = (float)(((double)pv.x - mu) * rs * g4.x + b4.x);
          v.y = (float)(((double)pv.y - mu) * rs * g4.y + b4.y);
          v.z = (float)(((double)pv.z - mu) * rs * g4.z + b4.z);
          v.w = (float)(((double)pv.w - mu) * rs * g4.w + b4.w);
          *(f4*)&sm.hB[b][k] = v;
        }
      }
      __syncthreads();
      {
        int jj = tid >> 4, kc = tid & 15, j = jj0 + jj;
        const f4* Wr_w = (const f4*)(p.eg_wih + (size_t)j * 1024);
        const f4* Wz_w = (const f4*)(p.eg_wih + (size_t)(512 + j) * 1024);
        const f4* Wn_w = (const f4*)(p.eg_wih + (size_t)(1024 + j) * 1024);
        const f4* Wr_h = (const f4*)(p.eg_whh + (size_t)j * 512);
        const f4* Wz_h = (const f4*)(p.eg_whh + (size_t)(512 + j) * 512);
        const f4* Wn_h = (const f4*)(p.eg_whh + (size_t)(1024 + j) * 512);
        const f4* HA = (const f4*)&sm.hA[0][0];
        const f4* HB = (const f4*)&sm.hB[0][0];
        // pass A: r,z — ROLLED i-loop
        {
          double ar[BP_] = {}, az[BP_] = {};
#pragma unroll 1
          for (int i = 0; i < 24; ++i) {
            int q = kc + 16 * i;
            f4 wr, wz; const f4* Ab; int hq;
            if (i < 16) { wr = Wr_w[q]; wz = Wz_w[q]; }
            else        { wr = Wr_h[q - 256]; wz = Wz_h[q - 256]; }
            if (i < 8)       { Ab = HA; hq = q; }
            else if (i < 16) { Ab = HB; hq = q - 128; }
            else             { Ab = HA; hq = q - 256; }
#pragma unroll
            for (int b = 0; b < BP_; ++b) {
              f4 a = Ab[b * 130 + hq];
              ar[b] += dot4d(a, wr); az[b] += dot4d(a, wz);
            }
          }
#pragma unroll
          for (int b = 0; b < BP_; ++b) {
            double r = ar[b], z = az[b];
#pragma unroll
            for (int m = 1; m <= 8; m <<= 1) { r += __shfl_xor(r, m); z += __shfl_xor(z, m); }
            if (kc == 0) { sm.red[jj][b][0] = r; sm.red[jj][b][1] = z; }
          }
        }
        // pass B: n — ROLLED i-loop
        {
          double apn[BP_] = {}, aph[BP_] = {};
#pragma unroll 1
          for (int i = 0; i < 24; ++i) {
            int q = kc + 16 * i;
            f4 wn; const f4* Ab; int hq;
            if (i < 16) wn = Wn_w[q]; else wn = Wn_h[q - 256];
            if (i < 8)       { Ab = HA; hq = q; }
            else if (i < 16) { Ab = HB; hq = q - 128; }
            else             { Ab = HA; hq = q - 256; }
#pragma unroll
            for (int b = 0; b < BP_; ++b) {
              f4 a = Ab[b * 130 + hq];
              if (i < 16) apn[b] += dot4d(a, wn); else aph[b] += dot4d(a, wn);
            }
          }
#pragma unroll
          for (int b = 0; b < BP_; ++b) {
            double pn = apn[b], ph = aph[b];
#pragma unroll
            for (int m = 1; m <= 8; m <<= 1) { pn += __shfl_xor(pn, m); ph += __shfl_xor(ph, m); }
            if (kc == 0) { sm.red[jj][b][2] = pn; sm.red[jj][b][3] = ph; }
          }
        }
      }
      __syncthreads();
      if (tid < 128) {
        int b = tid >> 4, jj = tid & 15, j = jj0 + jj;
        const double* rd = sm.red[jj][b];
        double r = sigm_d(rd[0] + (double)p.eg_bih[j] + (double)p.eg_bhh[j]);
        double z = sigm_d(rd[1] + (double)p.eg_bih[512 + j] + (double)p.eg_bhh[512 + j]);
        double inn = rd[2] + (double)p.eg_bih[1024 + j];
        double hn  = rd[3] + (double)p.eg_bhh[1024 + j];
        double n = tanh(inn + r * hn);
        double hp = (double)sm.hA[b][j];
        double hv = (1.0 - z) * n + z * hp;
        stA1(&p.e_out[(size_t)(te & 1) * NB_ * NH_ + (b0 + b) * NH_ + j], (float)hv);
      }
    }
  }
  // ---------------- wb(t-1): one block per local b (lid 64..71) ----------------
  else if (lid < 72) {
    if (t >= 1 && t <= NS_) {
      int b = b0 + (lid - 64), tw = t - 1;
      int spv = p.spk[b * NS_ + tw];
      const float* gsrc = p.g_new + (size_t)(tw & 1) * NB_ * NH_;
      float2 gv = ldA2(&gsrc[b * NH_ + tid * 2]);
      double s1 = (double)gv.x + (double)gv.y;
      double s2 = (double)gv.x * (double)gv.x + (double)gv.y * (double)gv.y;
#pragma unroll
      for (int m = 1; m <= 32; m <<= 1) { s1 += __shfl_xor(s1, m); s2 += __shfl_xor(s2, m); }
      int wid = tid >> 6;
      if ((tid & 63) == 0) { sm.redH[0][wid] = s1; sm.redH[1][wid] = s2; }
      __syncthreads();
      if (tid == 0) {
        double ts1 = sm.redH[0][0] + sm.redH[0][1] + sm.redH[0][2] + sm.redH[0][3];
        double ts2 = sm.redH[1][0] + sm.redH[1][1] + sm.redH[1][2] + sm.redH[1][3];
        double mu = ts1 * (1.0 / NH_), var = ts2 * (1.0 / NH_) - mu * mu;
        sm.stats[0][0] = mu; sm.stats[0][1] = 1.0 / sqrt(var + 1e-5);
      }
      __syncthreads();
      double mu = sm.stats[0][0], rs = sm.stats[0][1];
      float* gd = p.glob + (size_t)(b * NSP_ + spv) * NH_;
      int k2 = tid * 2;
      double o0 = ((double)gv.x - mu) * rs * p.ln_g[k2] + p.ln_b[k2];
      double o1 = ((double)gv.y - mu) * rs * p.ln_g[k2 + 1] + p.ln_b[k2 + 1];
      stA2(&gd[k2], (float)o0, (float)o1);
    }
  }
  // ---------------- head(t-2) (lid 72..79, 32 c each) ----------------
  else if (lid < 80) {
    if (t >= 2 && t <= NS_ + 1) {
      int th = t - 2, ct = lid - 72;
      const float* er = p.e_out + (size_t)(th & 1) * NB_ * NH_;
      for (int idx = tid; idx < BP_ * NH_ / 4; idx += 256) {
        int b = idx >> 7, k = (idx & 127) * 4;
        *(f4*)&sm.hA[b][k] = ldA4(&er[(b0 + b) * NH_ + k]);
      }
      __syncthreads();
      {
        int ci = tid >> 3, kc = tid & 7, c = ct * 32 + ci;
        const f4* W = (const f4*)(p.out_w1 + (size_t)c * 512);
        const f4* H = (const f4*)&sm.hA[0][0];
        double acc[BP_] = {};
#pragma unroll 1
        for (int i = 0; i < 16; ++i) {
          int q = kc + 8 * i;
          f4 w = W[q];
#pragma unroll
          for (int b = 0; b < BP_; ++b) acc[b] += dot4d(H[b * 130 + q], w);
        }
#pragma unroll
        for (int b = 0; b < BP_; ++b) {
          double v = acc[b];
#pragma unroll
          for (int m = 1; m <= 4; m <<= 1) v += __shfl_xor(v, m);
          if (kc == 0) sm.redH[ci][b] = v;
        }
      }
      __syncthreads();
      {
        int b = tid >> 5, ci = tid & 31, c = ct * 32 + ci;
        double h1 = sm.redH[ci][b] + (double)p.out_b1[c];
        stA1(&p.h1buf[(size_t)(th & 1) * NB_ * NH2_ + (b0 + b) * NH2_ + c], (float)fmax(h1, 0.0));
      }
    }
  }
  // ---------------- score(t-3) (lid 80) ----------------
  else {
    if (t >= 3 && t <= NS_ + 2 && tid < 128) {
      int ts = t - 3;
      int b = tid >> 4, cg = tid & 15;
      const float* h1p = p.h1buf + (size_t)(ts & 1) * NB_ * NH2_;
      double s1 = 0, s2 = 0;
      float hv[16];
#pragma unroll
      for (int i = 0; i < 16; ++i) {
        float v = ldA1(&h1p[(b0 + b) * NH2_ + cg * 16 + i]);
        hv[i] = v; s1 += (double)v; s2 += (double)v * (double)v;
      }
#pragma unroll
      for (int m = 1; m <= 8; m <<= 1) { s1 += __shfl_xor(s1, m); s2 += __shfl_xor(s2, m); }
      double mu = s1 * (1.0 / NH2_), var = s2 * (1.0 / NH2_) - mu * mu, rstd = 1.0 / sqrt(var + 1e-5);
      double d = 0;
#pragma unroll
      for (int i = 0; i < 16; ++i) {
        int c = cg * 16 + i;
        d += (((double)hv[i] - mu) * rstd * p.out_ln_g[c] + (double)p.out_ln_b[c]) * (double)p.out_w2[c];
      }
#pragma unroll
      for (int m = 1; m <= 8; m <<= 1) d += __shfl_xor(d, m);
      if (cg == 0) p.out[(b0 + b) * NS_ + ts] = (float)sigm_d(d + (double)p.out_b2[0]);
    }
  }
}

__global__ __launch_bounds__(256, 1) void seq_kernel(Params p) {
  const int bid = blockIdx.x, tid = threadIdx.x;
  const int d = bid / DBLK, lid = bid - d * DBLK;
  __shared__ Smem sm;
  u32* flags = p.flags + (size_t)d * DBLK * 16;
  u32* rel   = p.rel   + (size_t)d * DBLK * 16;
  for (int t = 0; t <= NS_ + 2; ++t) {
    step_body(p, sm, t, d, lid, tid);
    gbar3(flags, rel, lid, DBLK, (u32)(t + 1));
  }
}

// gg x-projection precompute: gix[bs][row] = sum_k utt[bs][k] * gg_wih[row][k], k<1024 (fp64)
__global__ __launch_bounds__(512) void gix_kernel(const float* utt, const float* ggw, float* gix) {
  __shared__ float xs[16][1028];
  const int tid = threadIdx.x;
  long bs0 = (long)blockIdx.x * 16;
  for (int i = tid; i < 16 * 256; i += 512) {
    int bb = i >> 8, kf = i & 255;
    *(f4*)&xs[bb][kf * 4] = *(const f4*)(utt + (bs0 + bb) * 1024 + kf * 4);
  }
  __syncthreads();
  int R = blockIdx.y * 32 + (tid >> 4);
  int bi = tid & 15;
  const f4* w4 = (const f4*)(ggw + (size_t)R * 1536);
  const f4* x4 = (const f4*)&xs[bi][0];
  double acc = 0;
  for (int k = 0; k < 256; ++k) acc += dot4d(x4[k], w4[k]);
  gix[(size_t)(bs0 + bi) * 1536 + R] = (float)acc;
}

__global__ void init_kernel(float* glob, const float* init_global, u32* flags, u32* rel) {
  long stride = (long)gridDim.x * blockDim.x;
  long t0 = (long)blockIdx.x * blockDim.x + threadIdx.x;
  for (long i = t0; i < (long)NB_ * NSP_ * NH_; i += stride) {
    int sp = ((int)i >> 9) & (NSP_ - 1);
    int k = (int)i & (NH_ - 1);
    glob[i] = init_global[sp * NH_ + k];
  }
  for (long i = t0; i < (long)NBLK * 16; i += stride) { flags[i] = 0u; rel[i] = 0u; }
}

extern "C" void kernel_launch(void* const* d_in, const int* in_sizes, int n_in,
                              void* d_out, int out_size, void* d_ws, size_t ws_size,
                              hipStream_t stream) {
  (void)in_sizes; (void)n_in; (void)out_size;
  Params p;
  p.utt    = (const float*)d_in[0];
  p.spk    = (const int*)d_in[1];
  // d_in[2] init_party: DEAD (party GRU feeds only itself, never the output path)
  const float* ig = (const float*)d_in[3];
  p.init_emotion = (const float*)d_in[4];
  // d_in[5..8] pg_*: DEAD (party GRU)
  p.gg_wih = (const float*)d_in[9];
  p.gg_whh = (const float*)d_in[10];
  p.gg_bih = (const float*)d_in[11];
  p.gg_bhh = (const float*)d_in[12];
  p.eg_wih = (const float*)d_in[13];
  p.eg_whh = (const float*)d_in[14];
  p.eg_bih = (const float*)d_in[15];
  p.eg_bhh = (const float*)d_in[16];
  // 17..19 attention weights: softmax over length-1 axis == 1 -> provably unused
  p.ln_g   = (const float*)d_in[20];
  p.ln_b   = (const float*)d_in[21];
  p.out_w1 = (const float*)d_in[22];
  p.out_b1 = (const float*)d_in[23];
  p.out_ln_g = (const float*)d_in[24];
  p.out_ln_b = (const float*)d_in[25];
  p.out_w2 = (const float*)d_in[26];
  p.out_b2 = (const float*)d_in[27];

  char* w = (char*)d_ws;
  auto alloc = [&](size_t bytes) { char* r = w; w += (bytes + 255) & ~(size_t)255; return r; };
  float* gix   = (float*)alloc((size_t)8192 * 1536 * 4);   // ~50.3 MB
  float* g_new = (float*)alloc((size_t)2 * NB_ * NH_ * 4);
  float* e_out = (float*)alloc((size_t)2 * NB_ * NH_ * 4);
  float* glob  = (float*)alloc((size_t)NB_ * NSP_ * NH_ * 4);
  float* h1buf = (float*)alloc((size_t)2 * NB_ * NH2_ * 4);
  u32*   flags = (u32*)alloc((size_t)NBLK * 16 * 4);
  u32*   rel   = (u32*)alloc((size_t)NBLK * 16 * 4);
  if ((size_t)(w - (char*)d_ws) > ws_size) return;  // ws too small -> loud failure (zeros)

  gix_kernel<<<dim3(512, 48), dim3(512), 0, stream>>>(p.utt, p.gg_wih, gix);
  init_kernel<<<dim3(64), dim3(256), 0, stream>>>(glob, ig, flags, rel);

  p.gix = gix;
  p.g_new = g_new; p.e_out = e_out; p.glob = glob;
  p.h1buf = h1buf; p.flags = flags; p.rel = rel; p.out = (float*)d_out;

  seq_kernel<<<dim3(NBLK), dim3(256), 0, stream>>>(p);
}

// Round 20
// 15842.114 us; speedup vs baseline: 5.3519x; 1.4210x over previous
//
#include <hip/hip_runtime.h>

typedef __attribute__((ext_vector_type(4))) float f4;
using u32 = unsigned int;
using u64 = unsigned long long;

constexpr int NB_ = 16;    // total batch
constexpr int BP_ = 8;     // batch per domain
constexpr int NS_ = 512;   // seq len
constexpr int ND_ = 1024;  // input dim
constexpr int NH_ = 512;   // hidden
constexpr int NSP_ = 8;    // speakers
constexpr int NH2_ = 256;  // head hidden
constexpr int HP = 520;    // padded fp32 LDS row (130 f4)
constexpr int DBLK = 81;   // blocks per domain: gg 32 | eg 32 | wb 8 | head 8 | score 1
constexpr int NBLK = 162;  // two independent domains

struct Params {
  const float *utt;
  const float *gg_wih, *gg_whh, *eg_wih, *eg_whh, *out_w1;
  const float *gix;           // precomputed gg x-projection [B*S][1536] fp32
  const float *init_emotion;
  const float *gg_bih, *gg_bhh, *eg_bih, *eg_bhh;
  const float *ln_g, *ln_b, *out_b1, *out_ln_g, *out_ln_b, *out_w2, *out_b2;
  const int *spk;
  float *g_new;      // [2][B][H] raw gg output, parity t&1
  float *e_out;      // [2][B][H] raw eg output, parity te&1
  float *glob;       // [B][SP][H] post-LN (or raw init) global states
  float *h1buf;      // [2][B][H2] relu(e@W1+b1), parity th&1
  u32 *flags;        // [2][DBLK*16] arrival flags, one 64B line per block
  u32 *rel;          // [2][DBLK*16] per-block release lines
  float *out;        // [B][S]
};

__device__ __forceinline__ double sigm_d(double x) { return 1.0 / (1.0 + exp(-x)); }
__device__ __forceinline__ double dot4d(f4 a, f4 w) {
  return ((double)a.x * w.x + (double)a.y * w.y) + ((double)a.z * w.z + (double)a.w * w.w);
}

// ---- cross-block plumbing: relaxed agent-scope atomics (bypass per-XCD L2; no flushes) ----
__device__ __forceinline__ void stA1(float* p, float v) {
  __hip_atomic_store(p, v, __ATOMIC_RELAXED, __HIP_MEMORY_SCOPE_AGENT);
}
__device__ __forceinline__ float ldA1(const float* p) {
  return __hip_atomic_load((float*)p, __ATOMIC_RELAXED, __HIP_MEMORY_SCOPE_AGENT);
}
__device__ __forceinline__ void stA2(float* p, float a, float b) {
  union { float f[2]; u64 u; } x; x.f[0] = a; x.f[1] = b;
  __hip_atomic_store((u64*)p, x.u, __ATOMIC_RELAXED, __HIP_MEMORY_SCOPE_AGENT);
}
__device__ __forceinline__ float2 ldA2(const float* p) {
  u64 u = __hip_atomic_load((u64*)p, __ATOMIC_RELAXED, __HIP_MEMORY_SCOPE_AGENT);
  union { u64 u; float f[2]; } x; x.u = u;
  return make_float2(x.f[0], x.f[1]);
}
__device__ __forceinline__ f4 ldA4(const float* p) {
  float2 lo = ldA2(p), hi = ldA2(p + 2);
  f4 v; v.x = lo.x; v.y = lo.y; v.z = hi.x; v.w = hi.y;
  return v;
}

// Distributed flag barrier over one domain's DBLK blocks (R17-validated pattern).
__device__ __forceinline__ void gbar3(u32* flags, u32* rel, int lid, int nb, u32 epoch) {
  __syncthreads();
  const int tid = threadIdx.x;
  if (lid == 0) {
    if (tid > 0 && tid < nb) {
      while (__hip_atomic_load(&flags[(size_t)tid * 16], __ATOMIC_RELAXED, __HIP_MEMORY_SCOPE_AGENT) < epoch)
        __builtin_amdgcn_s_sleep(1);
    }
    __syncthreads();
    if (tid < nb) {
      asm volatile("s_waitcnt vmcnt(0)" ::: "memory");
      __hip_atomic_store(&rel[(size_t)tid * 16], epoch, __ATOMIC_RELAXED, __HIP_MEMORY_SCOPE_AGENT);
    }
  } else {
    if (tid == 0) {
      asm volatile("s_waitcnt vmcnt(0) lgkmcnt(0)" ::: "memory");
      __hip_atomic_store(&flags[(size_t)lid * 16], epoch, __ATOMIC_RELAXED, __HIP_MEMORY_SCOPE_AGENT);
      while (__hip_atomic_load(&rel[(size_t)lid * 16], __ATOMIC_RELAXED, __HIP_MEMORY_SCOPE_AGENT) < epoch)
        __builtin_amdgcn_s_sleep(2);
    }
  }
  __syncthreads();
}

struct __align__(16) Smem {
  float hA[BP_][HP];
  float hB[BP_][HP];
  double red[16][BP_][4];
  double redH[32][BP_];
  double stats[BP_][2];
  double stats2[BP_][2];
  int spk[BP_], spkp[BP_];
};

// block-local per-b stats: 256 threads = (b 8, kc 32), 16 elems each, shfl over 32 lanes
__device__ __forceinline__ void row_stats8(const float (*h)[HP], double (*st)[2], int tid) {
  int b = tid >> 5, kc = tid & 31;
  double s1 = 0, s2 = 0;
#pragma unroll
  for (int i = 0; i < 16; ++i) {
    double x = (double)h[b][kc + i * 32];
    s1 += x; s2 += x * x;
  }
#pragma unroll
  for (int m = 1; m <= 16; m <<= 1) { s1 += __shfl_xor(s1, m); s2 += __shfl_xor(s2, m); }
  if (kc == 0) {
    double mu = s1 * (1.0 / NH_), var = s2 * (1.0 / NH_) - mu * mu;
    st[b][0] = mu; st[b][1] = 1.0 / sqrt(var + 1e-5);
  }
}

// One pipelined step t within domain d (8 dialogues b0=d*8..+8):
// gg(t)|eg(t-1)|wb(t-1)|head(t-2)|score(t-3).
__device__ void step_body(const Params& p, Smem& sm, int t, int d, int lid, int tid) {
  const int b0 = d * BP_;
  // ---------------- gg(t) (lid 0..31, 16 j each) ----------------
  if (lid < 32) {
    if (t < NS_) {
      const int jj0 = lid * 16;
      if (tid < BP_) {
        sm.spk[tid]  = p.spk[(b0 + tid) * NS_ + t];
        sm.spkp[tid] = (t > 0) ? p.spk[(b0 + tid) * NS_ + t - 1] : -1;
      }
      __syncthreads();
      const float* gprev = p.g_new + (size_t)((t - 1) & 1) * NB_ * NH_;
      for (int idx = tid; idx < BP_ * NH_ / 4; idx += 256) {
        int b = idx >> 7, k = (idx & 127) * 4;
        f4 v = (sm.spk[b] == sm.spkp[b])
                   ? ldA4(&gprev[(b0 + b) * NH_ + k])
                   : ldA4(&p.glob[(size_t)((b0 + b) * NSP_ + sm.spk[b]) * NH_ + k]);
        *(f4*)&sm.hA[b][k] = v;
      }
      __syncthreads();
      row_stats8(sm.hA, sm.stats, tid);
      __syncthreads();
      for (int idx = tid; idx < BP_ * NH_ / 4; idx += 256) {
        int b = idx >> 7, k = (idx & 127) * 4;
        if (sm.spk[b] == sm.spkp[b]) {
          f4 pv = *(f4*)&sm.hA[b][k];
          f4 g4 = *(const f4*)&p.ln_g[k], b4 = *(const f4*)&p.ln_b[k];
          double mu = sm.stats[b][0], rs = sm.stats[b][1];
          f4 v;
          v.x = (float)(((double)pv.x - mu) * rs * g4.x + b4.x);
          v.y = (float)(((double)pv.y - mu) * rs * g4.y + b4.y);
          v.z = (float)(((double)pv.z - mu) * rs * g4.z + b4.z);
          v.w = (float)(((double)pv.w - mu) * rs * g4.w + b4.w);
          *(f4*)&sm.hA[b][k] = v;
        }
      }
      __syncthreads();
      {
        int jj = tid >> 4, kc = tid & 15, j = jj0 + jj;
        const f4* Wr_w = (const f4*)(p.gg_wih + (size_t)j * 1536 + 1024);
        const f4* Wz_w = (const f4*)(p.gg_wih + (size_t)(512 + j) * 1536 + 1024);
        const f4* Wn_w = (const f4*)(p.gg_wih + (size_t)(1024 + j) * 1536 + 1024);
        const f4* Wr_h = (const f4*)(p.gg_whh + (size_t)j * 512);
        const f4* Wz_h = (const f4*)(p.gg_whh + (size_t)(512 + j) * 512);
        const f4* Wn_h = (const f4*)(p.gg_whh + (size_t)(1024 + j) * 512);
        const f4* H = (const f4*)&sm.hA[0][0];
        // SINGLE merged pass: r,z,n (32 fp64 acc, spill-free at BP_=8), unroll 2
        double ar[BP_] = {}, az[BP_] = {}, apn[BP_] = {}, aph[BP_] = {};
#pragma unroll 2
        for (int i = 0; i < 16; ++i) {
          int q = kc + 16 * i;
          f4 wr, wz, wn; int hq;
          if (i < 8) { wr = Wr_w[q]; wz = Wz_w[q]; wn = Wn_w[q]; hq = q; }
          else       { hq = q - 128; wr = Wr_h[hq]; wz = Wz_h[hq]; wn = Wn_h[hq]; }
#pragma unroll
          for (int b = 0; b < BP_; ++b) {
            f4 a = H[b * 130 + hq];
            ar[b] += dot4d(a, wr); az[b] += dot4d(a, wz);
            if (i < 8) apn[b] += dot4d(a, wn); else aph[b] += dot4d(a, wn);
          }
        }
#pragma unroll
        for (int b = 0; b < BP_; ++b) {
          double r = ar[b], z = az[b], pn = apn[b], ph = aph[b];
#pragma unroll
          for (int m = 1; m <= 8; m <<= 1) {
            r += __shfl_xor(r, m); z += __shfl_xor(z, m);
            pn += __shfl_xor(pn, m); ph += __shfl_xor(ph, m);
          }
          if (kc == 0) { sm.red[jj][b][0] = r; sm.red[jj][b][1] = z; sm.red[jj][b][2] = pn; sm.red[jj][b][3] = ph; }
        }
      }
      __syncthreads();
      if (tid < 128) {
        int b = tid >> 4, jj = tid & 15, j = jj0 + jj;
        const double* rd = sm.red[jj][b];
        const float* gx = p.gix + (size_t)((b0 + b) * NS_ + t) * 1536;
        double r = sigm_d(rd[0] + (double)gx[j] + (double)p.gg_bih[j] + (double)p.gg_bhh[j]);
        double z = sigm_d(rd[1] + (double)gx[512 + j] + (double)p.gg_bih[512 + j] + (double)p.gg_bhh[512 + j]);
        double inn = rd[2] + (double)gx[1024 + j] + (double)p.gg_bih[1024 + j];
        double hn  = rd[3] + (double)p.gg_bhh[1024 + j];
        double n = tanh(inn + r * hn);
        double hp = (double)sm.hA[b][j];
        double hv = (1.0 - z) * n + z * hp;
        stA1(&p.g_new[(size_t)(t & 1) * NB_ * NH_ + (b0 + b) * NH_ + j], (float)hv);
      }
    }
  }
  // ---------------- eg(t-1) (lid 32..63, 16 j each) ----------------
  else if (lid < 64) {
    if (t >= 1 && t <= NS_) {
      const int te = t - 1;
      const int jj0 = (lid - 32) * 16;
      const float* eprev = p.e_out + (size_t)((te - 1) & 1) * NB_ * NH_;
      const float* gcur  = p.g_new + (size_t)(te & 1) * NB_ * NH_;
      for (int idx = tid; idx < BP_ * NH_ / 2; idx += 256) {
        int half = idx >= BP_ * NH_ / 4;
        int r4 = idx & (BP_ * NH_ / 4 - 1);
        int b = r4 >> 7, k = (r4 & 127) * 4;
        if (!half) {
          f4 v = (te == 0) ? *(const f4*)&p.init_emotion[k] : ldA4(&eprev[(b0 + b) * NH_ + k]);
          *(f4*)&sm.hA[b][k] = v;
        } else {
          *(f4*)&sm.hB[b][k] = ldA4(&gcur[(b0 + b) * NH_ + k]);
        }
      }
      __syncthreads();
      {
        int b = tid >> 5, kc = tid & 31;
        double a1 = 0, a2 = 0, b1 = 0, b2 = 0;
#pragma unroll
        for (int i = 0; i < 16; ++i) {
          double xa = (double)sm.hA[b][kc + i * 32];
          double xb = (double)sm.hB[b][kc + i * 32];
          a1 += xa; a2 += xa * xa; b1 += xb; b2 += xb * xb;
        }
#pragma unroll
        for (int m = 1; m <= 16; m <<= 1) {
          a1 += __shfl_xor(a1, m); a2 += __shfl_xor(a2, m);
          b1 += __shfl_xor(b1, m); b2 += __shfl_xor(b2, m);
        }
        if (kc == 0) {
          double mu = a1 * (1.0 / NH_), var = a2 * (1.0 / NH_) - mu * mu;
          sm.stats[b][0] = mu; sm.stats[b][1] = 1.0 / sqrt(var + 1e-5);
          mu = b1 * (1.0 / NH_); var = b2 * (1.0 / NH_) - mu * mu;
          sm.stats2[b][0] = mu; sm.stats2[b][1] = 1.0 / sqrt(var + 1e-5);
        }
      }
      __syncthreads();
      for (int idx = tid; idx < BP_ * NH_ / 2; idx += 256) {
        int half = idx >= BP_ * NH_ / 4;
        int r4 = idx & (BP_ * NH_ / 4 - 1);
        int b = r4 >> 7, k = (r4 & 127) * 4;
        f4 g4 = *(const f4*)&p.ln_g[k], b4 = *(const f4*)&p.ln_b[k];
        if (!half) {
          if (te > 0) {
            f4 pv = *(f4*)&sm.hA[b][k];
            double mu = sm.stats[b][0], rs = sm.stats[b][1];
            f4 v;
            v.x = (float)(((double)pv.x - mu) * rs * g4.x + b4.x);
            v.y = (float)(((double)pv.y - mu) * rs * g4.y + b4.y);
            v.z = (float)(((double)pv.z - mu) * rs * g4.z + b4.z);
            v.w = (float)(((double)pv.w - mu) * rs * g4.w + b4.w);
            *(f4*)&sm.hA[b][k] = v;
          }
        } else {
          f4 pv = *(f4*)&sm.hB[b][k];
          double mu = sm.stats2[b][0], rs = sm.stats2[b][1];
          f4 v;
          v.x = (float)(((double)pv.x - mu) * rs * g4.x + b4.x);
          v.y = (float)(((double)pv.y - mu) * rs * g4.y + b4.y);
          v.z = (float)(((double)pv.z - mu) * rs * g4.z + b4.z);
          v.w = (float)(((double)pv.w - mu) * rs * g4.w + b4.w);
          *(f4*)&sm.hB[b][k] = v;
        }
      }
      __syncthreads();
      {
        int jj = tid >> 4, kc = tid & 15, j = jj0 + jj;
        const f4* Wr_w = (const f4*)(p.eg_wih + (size_t)j * 1024);
        const f4* Wz_w = (const f4*)(p.eg_wih + (size_t)(512 + j) * 1024);
        const f4* Wn_w = (const f4*)(p.eg_wih + (size_t)(1024 + j) * 1024);
        const f4* Wr_h = (const f4*)(p.eg_whh + (size_t)j * 512);
        const f4* Wz_h = (const f4*)(p.eg_whh + (size_t)(512 + j) * 512);
        const f4* Wn_h = (const f4*)(p.eg_whh + (size_t)(1024 + j) * 512);
        const f4* HA = (const f4*)&sm.hA[0][0];
        const f4* HB = (const f4*)&sm.hB[0][0];
        // SINGLE merged pass: r,z,n (32 fp64 acc), unroll 2
        double ar[BP_] = {}, az[BP_] = {}, apn[BP_] = {}, aph[BP_] = {};
#pragma unroll 2
        for (int i = 0; i < 24; ++i) {
          int q = kc + 16 * i;
          f4 wr, wz, wn; const f4* Ab; int hq;
          if (i < 16) { wr = Wr_w[q]; wz = Wz_w[q]; wn = Wn_w[q]; }
          else        { wr = Wr_h[q - 256]; wz = Wz_h[q - 256]; wn = Wn_h[q - 256]; }
          if (i < 8)       { Ab = HA; hq = q; }
          else if (i < 16) { Ab = HB; hq = q - 128; }
          else             { Ab = HA; hq = q - 256; }
#pragma unroll
          for (int b = 0; b < BP_; ++b) {
            f4 a = Ab[b * 130 + hq];
            ar[b] += dot4d(a, wr); az[b] += dot4d(a, wz);
            if (i < 16) apn[b] += dot4d(a, wn); else aph[b] += dot4d(a, wn);
          }
        }
#pragma unroll
        for (int b = 0; b < BP_; ++b) {
          double r = ar[b], z = az[b], pn = apn[b], ph = aph[b];
#pragma unroll
          for (int m = 1; m <= 8; m <<= 1) {
            r += __shfl_xor(r, m); z += __shfl_xor(z, m);
            pn += __shfl_xor(pn, m); ph += __shfl_xor(ph, m);
          }
          if (kc == 0) { sm.red[jj][b][0] = r; sm.red[jj][b][1] = z; sm.red[jj][b][2] = pn; sm.red[jj][b][3] = ph; }
        }
      }
      __syncthreads();
      if (tid < 128) {
        int b = tid >> 4, jj = tid & 15, j = jj0 + jj;
        const double* rd = sm.red[jj][b];
        double r = sigm_d(rd[0] + (double)p.eg_bih[j] + (double)p.eg_bhh[j]);
        double z = sigm_d(rd[1] + (double)p.eg_bih[512 + j] + (double)p.eg_bhh[512 + j]);
        double inn = rd[2] + (double)p.eg_bih[1024 + j];
        double hn  = rd[3] + (double)p.eg_bhh[1024 + j];
        double n = tanh(inn + r * hn);
        double hp = (double)sm.hA[b][j];
        double hv = (1.0 - z) * n + z * hp;
        stA1(&p.e_out[(size_t)(te & 1) * NB_ * NH_ + (b0 + b) * NH_ + j], (float)hv);
      }
    }
  }
  // ---------------- wb(t-1): one block per local b (lid 64..71) ----------------
  else if (lid < 72) {
    if (t >= 1 && t <= NS_) {
      int b = b0 + (lid - 64), tw = t - 1;
      int spv = p.spk[b * NS_ + tw];
      const float* gsrc = p.g_new + (size_t)(tw & 1) * NB_ * NH_;
      float2 gv = ldA2(&gsrc[b * NH_ + tid * 2]);
      double s1 = (double)gv.x + (double)gv.y;
      double s2 = (double)gv.x * (double)gv.x + (double)gv.y * (double)gv.y;
#pragma unroll
      for (int m = 1; m <= 32; m <<= 1) { s1 += __shfl_xor(s1, m); s2 += __shfl_xor(s2, m); }
      int wid = tid >> 6;
      if ((tid & 63) == 0) { sm.redH[0][wid] = s1; sm.redH[1][wid] = s2; }
      __syncthreads();
      if (tid == 0) {
        double ts1 = sm.redH[0][0] + sm.redH[0][1] + sm.redH[0][2] + sm.redH[0][3];
        double ts2 = sm.redH[1][0] + sm.redH[1][1] + sm.redH[1][2] + sm.redH[1][3];
        double mu = ts1 * (1.0 / NH_), var = ts2 * (1.0 / NH_) - mu * mu;
        sm.stats[0][0] = mu; sm.stats[0][1] = 1.0 / sqrt(var + 1e-5);
      }
      __syncthreads();
      double mu = sm.stats[0][0], rs = sm.stats[0][1];
      float* gd = p.glob + (size_t)(b * NSP_ + spv) * NH_;
      int k2 = tid * 2;
      double o0 = ((double)gv.x - mu) * rs * p.ln_g[k2] + p.ln_b[k2];
      double o1 = ((double)gv.y - mu) * rs * p.ln_g[k2 + 1] + p.ln_b[k2 + 1];
      stA2(&gd[k2], (float)o0, (float)o1);
    }
  }
  // ---------------- head(t-2) (lid 72..79, 32 c each) ----------------
  else if (lid < 80) {
    if (t >= 2 && t <= NS_ + 1) {
      int th = t - 2, ct = lid - 72;
      const float* er = p.e_out + (size_t)(th & 1) * NB_ * NH_;
      for (int idx = tid; idx < BP_ * NH_ / 4; idx += 256) {
        int b = idx >> 7, k = (idx & 127) * 4;
        *(f4*)&sm.hA[b][k] = ldA4(&er[(b0 + b) * NH_ + k]);
      }
      __syncthreads();
      {
        int ci = tid >> 3, kc = tid & 7, c = ct * 32 + ci;
        const f4* W = (const f4*)(p.out_w1 + (size_t)c * 512);
        const f4* H = (const f4*)&sm.hA[0][0];
        double acc[BP_] = {};
#pragma unroll 2
        for (int i = 0; i < 16; ++i) {
          int q = kc + 8 * i;
          f4 w = W[q];
#pragma unroll
          for (int b = 0; b < BP_; ++b) acc[b] += dot4d(H[b * 130 + q], w);
        }
#pragma unroll
        for (int b = 0; b < BP_; ++b) {
          double v = acc[b];
#pragma unroll
          for (int m = 1; m <= 4; m <<= 1) v += __shfl_xor(v, m);
          if (kc == 0) sm.redH[ci][b] = v;
        }
      }
      __syncthreads();
      {
        int b = tid >> 5, ci = tid & 31, c = ct * 32 + ci;
        double h1 = sm.redH[ci][b] + (double)p.out_b1[c];
        stA1(&p.h1buf[(size_t)(th & 1) * NB_ * NH2_ + (b0 + b) * NH2_ + c], (float)fmax(h1, 0.0));
      }
    }
  }
  // ---------------- score(t-3) (lid 80) ----------------
  else {
    if (t >= 3 && t <= NS_ + 2 && tid < 128) {
      int ts = t - 3;
      int b = tid >> 4, cg = tid & 15;
      const float* h1p = p.h1buf + (size_t)(ts & 1) * NB_ * NH2_;
      double s1 = 0, s2 = 0;
      float hv[16];
#pragma unroll
      for (int i = 0; i < 16; ++i) {
        float v = ldA1(&h1p[(b0 + b) * NH2_ + cg * 16 + i]);
        hv[i] = v; s1 += (double)v; s2 += (double)v * (double)v;
      }
#pragma unroll
      for (int m = 1; m <= 8; m <<= 1) { s1 += __shfl_xor(s1, m); s2 += __shfl_xor(s2, m); }
      double mu = s1 * (1.0 / NH2_), var = s2 * (1.0 / NH2_) - mu * mu, rstd = 1.0 / sqrt(var + 1e-5);
      double d = 0;
#pragma unroll
      for (int i = 0; i < 16; ++i) {
        int c = cg * 16 + i;
        d += (((double)hv[i] - mu) * rstd * p.out_ln_g[c] + (double)p.out_ln_b[c]) * (double)p.out_w2[c];
      }
#pragma unroll
      for (int m = 1; m <= 8; m <<= 1) d += __shfl_xor(d, m);
      if (cg == 0) p.out[(b0 + b) * NS_ + ts] = (float)sigm_d(d + (double)p.out_b2[0]);
    }
  }
}

__global__ __launch_bounds__(256, 1) void seq_kernel(Params p) {
  const int bid = blockIdx.x, tid = threadIdx.x;
  const int d = bid / DBLK, lid = bid - d * DBLK;
  __shared__ Smem sm;
  u32* flags = p.flags + (size_t)d * DBLK * 16;
  u32* rel   = p.rel   + (size_t)d * DBLK * 16;
  for (int t = 0; t <= NS_ + 2; ++t) {
    step_body(p, sm, t, d, lid, tid);
    gbar3(flags, rel, lid, DBLK, (u32)(t + 1));
  }
}

// gg x-projection precompute: gix[bs][row] = sum_k utt[bs][k] * gg_wih[row][k], k<1024 (fp64)
__global__ __launch_bounds__(512) void gix_kernel(const float* utt, const float* ggw, float* gix) {
  __shared__ float xs[16][1028];
  const int tid = threadIdx.x;
  long bs0 = (long)blockIdx.x * 16;
  for (int i = tid; i < 16 * 256; i += 512) {
    int bb = i >> 8, kf = i & 255;
    *(f4*)&xs[bb][kf * 4] = *(const f4*)(utt + (bs0 + bb) * 1024 + kf * 4);
  }
  __syncthreads();
  int R = blockIdx.y * 32 + (tid >> 4);
  int bi = tid & 15;
  const f4* w4 = (const f4*)(ggw + (size_t)R * 1536);
  const f4* x4 = (const f4*)&xs[bi][0];
  double acc = 0;
  for (int k = 0; k < 256; ++k) acc += dot4d(x4[k], w4[k]);
  gix[(size_t)(bs0 + bi) * 1536 + R] = (float)acc;
}

__global__ void init_kernel(float* glob, const float* init_global, u32* flags, u32* rel) {
  long stride = (long)gridDim.x * blockDim.x;
  long t0 = (long)blockIdx.x * blockDim.x + threadIdx.x;
  for (long i = t0; i < (long)NB_ * NSP_ * NH_; i += stride) {
    int sp = ((int)i >> 9) & (NSP_ - 1);
    int k = (int)i & (NH_ - 1);
    glob[i] = init_global[sp * NH_ + k];
  }
  for (long i = t0; i < (long)NBLK * 16; i += stride) { flags[i] = 0u; rel[i] = 0u; }
}

extern "C" void kernel_launch(void* const* d_in, const int* in_sizes, int n_in,
                              void* d_out, int out_size, void* d_ws, size_t ws_size,
                              hipStream_t stream) {
  (void)in_sizes; (void)n_in; (void)out_size;
  Params p;
  p.utt    = (const float*)d_in[0];
  p.spk    = (const int*)d_in[1];
  // d_in[2] init_party: DEAD (party GRU feeds only itself, never the output path)
  const float* ig = (const float*)d_in[3];
  p.init_emotion = (const float*)d_in[4];
  // d_in[5..8] pg_*: DEAD (party GRU)
  p.gg_wih = (const float*)d_in[9];
  p.gg_whh = (const float*)d_in[10];
  p.gg_bih = (const float*)d_in[11];
  p.gg_bhh = (const float*)d_in[12];
  p.eg_wih = (const float*)d_in[13];
  p.eg_whh = (const float*)d_in[14];
  p.eg_bih = (const float*)d_in[15];
  p.eg_bhh = (const float*)d_in[16];
  // 17..19 attention weights: softmax over length-1 axis == 1 -> provably unused
  p.ln_g   = (const float*)d_in[20];
  p.ln_b   = (const float*)d_in[21];
  p.out_w1 = (const float*)d_in[22];
  p.out_b1 = (const float*)d_in[23];
  p.out_ln_g = (const float*)d_in[24];
  p.out_ln_b = (const float*)d_in[25];
  p.out_w2 = (const float*)d_in[26];
  p.out_b2 = (const float*)d_in[27];

  char* w = (char*)d_ws;
  auto alloc = [&](size_t bytes) { char* r = w; w += (bytes + 255) & ~(size_t)255; return r; };
  float* gix   = (float*)alloc((size_t)8192 * 1536 * 4);   // ~50.3 MB
  float* g_new = (float*)alloc((size_t)2 * NB_ * NH_ * 4);
  float* e_out = (float*)alloc((size_t)2 * NB_ * NH_ * 4);
  float* glob  = (float*)alloc((size_t)NB_ * NSP_ * NH_ * 4);
  float* h1buf = (float*)alloc((size_t)2 * NB_ * NH2_ * 4);
  u32*   flags = (u32*)alloc((size_t)NBLK * 16 * 4);
  u32*   rel   = (u32*)alloc((size_t)NBLK * 16 * 4);
  if ((size_t)(w - (char*)d_ws) > ws_size) return;  // ws too small -> loud failure (zeros)

  gix_kernel<<<dim3(512, 48), dim3(512), 0, stream>>>(p.utt, p.gg_wih, gix);
  init_kernel<<<dim3(64), dim3(256), 0, stream>>>(glob, ig, flags, rel);

  p.gix = gix;
  p.g_new = g_new; p.e_out = e_out; p.glob = glob;
  p.h1buf = h1buf; p.flags = flags; p.rel = rel; p.out = (float*)d_out;

  seq_kernel<<<dim3(NBLK), dim3(256), 0, stream>>>(p);
}

// Round 21
// 14749.745 us; speedup vs baseline: 5.7483x; 1.0741x over previous
//
#include <hip/hip_runtime.h>

typedef __attribute__((ext_vector_type(4))) float f4;
using u32 = unsigned int;
using u64 = unsigned long long;

constexpr int NB_ = 16;    // total batch
constexpr int BP_ = 8;     // batch per domain
constexpr int NS_ = 512;   // seq len
constexpr int ND_ = 1024;  // input dim
constexpr int NH_ = 512;   // hidden
constexpr int NSP_ = 8;    // speakers
constexpr int NH2_ = 256;  // head hidden
constexpr int HP = 520;    // padded fp32 LDS row (130 f4)
constexpr int DBLK = 81;   // blocks per domain: gg 32 | eg 32 | wb 8 | head 8 | score 1
constexpr int NBLK = 162;  // two independent domains

struct Params {
  const float *utt;
  const float *gg_wih, *gg_whh, *eg_wih, *eg_whh, *out_w1;
  const float *gix;           // precomputed gg x-projection [B*S][1536] fp32
  const float *init_emotion;
  const float *gg_bih, *gg_bhh, *eg_bih, *eg_bhh;
  const float *ln_g, *ln_b, *out_b1, *out_ln_g, *out_ln_b, *out_w2, *out_b2;
  const int *spk;
  float *g_new;      // [2][B][H] raw gg output, parity t&1
  float *e_out;      // [2][B][H] raw eg output, parity te&1
  float *glob;       // [B][SP][H] post-LN (or raw init) global states
  float *h1buf;      // [2][B][H2] relu(e@W1+b1), parity th&1
  u32 *flags;        // [2][DBLK*16] arrival flags, one 64B line per block
  u32 *rel;          // [2][DBLK*16] per-block release lines
  float *out;        // [B][S]
};

__device__ __forceinline__ double sigm_d(double x) { return 1.0 / (1.0 + exp(-x)); }
__device__ __forceinline__ double dot4d(f4 a, f4 w) {
  return ((double)a.x * w.x + (double)a.y * w.y) + ((double)a.z * w.z + (double)a.w * w.w);
}

// ---- cross-block plumbing: relaxed agent-scope atomics (bypass per-XCD L2; no flushes) ----
__device__ __forceinline__ void stA1(float* p, float v) {
  __hip_atomic_store(p, v, __ATOMIC_RELAXED, __HIP_MEMORY_SCOPE_AGENT);
}
__device__ __forceinline__ float ldA1(const float* p) {
  return __hip_atomic_load((float*)p, __ATOMIC_RELAXED, __HIP_MEMORY_SCOPE_AGENT);
}
__device__ __forceinline__ void stA2(float* p, float a, float b) {
  union { float f[2]; u64 u; } x; x.f[0] = a; x.f[1] = b;
  __hip_atomic_store((u64*)p, x.u, __ATOMIC_RELAXED, __HIP_MEMORY_SCOPE_AGENT);
}
__device__ __forceinline__ float2 ldA2(const float* p) {
  u64 u = __hip_atomic_load((u64*)p, __ATOMIC_RELAXED, __HIP_MEMORY_SCOPE_AGENT);
  union { u64 u; float f[2]; } x; x.u = u;
  return make_float2(x.f[0], x.f[1]);
}
__device__ __forceinline__ f4 ldA4(const float* p) {
  float2 lo = ldA2(p), hi = ldA2(p + 2);
  f4 v; v.x = lo.x; v.y = lo.y; v.z = hi.x; v.w = hi.y;
  return v;
}

// Distributed flag barrier over one domain's DBLK blocks (R17-validated pattern).
__device__ __forceinline__ void gbar3(u32* flags, u32* rel, int lid, int nb, u32 epoch) {
  __syncthreads();
  const int tid = threadIdx.x;
  if (lid == 0) {
    if (tid > 0 && tid < nb) {
      while (__hip_atomic_load(&flags[(size_t)tid * 16], __ATOMIC_RELAXED, __HIP_MEMORY_SCOPE_AGENT) < epoch)
        __builtin_amdgcn_s_sleep(1);
    }
    __syncthreads();
    if (tid < nb) {
      asm volatile("s_waitcnt vmcnt(0)" ::: "memory");
      __hip_atomic_store(&rel[(size_t)tid * 16], epoch, __ATOMIC_RELAXED, __HIP_MEMORY_SCOPE_AGENT);
    }
  } else {
    if (tid == 0) {
      asm volatile("s_waitcnt vmcnt(0) lgkmcnt(0)" ::: "memory");
      __hip_atomic_store(&flags[(size_t)lid * 16], epoch, __ATOMIC_RELAXED, __HIP_MEMORY_SCOPE_AGENT);
      while (__hip_atomic_load(&rel[(size_t)lid * 16], __ATOMIC_RELAXED, __HIP_MEMORY_SCOPE_AGENT) < epoch)
        __builtin_amdgcn_s_sleep(2);
    }
  }
  __syncthreads();
}

struct __align__(16) Smem {
  float hA[BP_][HP];
  float hB[BP_][HP];
  double red[16][BP_][4];
  double redH[32][BP_];
  double stats[BP_][2];
  double stats2[BP_][2];
  int spk[BP_], spkp[BP_];
};

// block-local per-b stats: 256 threads = (b 8, kc 32), 16 elems each, shfl over 32 lanes
__device__ __forceinline__ void row_stats8(const float (*h)[HP], double (*st)[2], int tid) {
  int b = tid >> 5, kc = tid & 31;
  double s1 = 0, s2 = 0;
#pragma unroll
  for (int i = 0; i < 16; ++i) {
    double x = (double)h[b][kc + i * 32];
    s1 += x; s2 += x * x;
  }
#pragma unroll
  for (int m = 1; m <= 16; m <<= 1) { s1 += __shfl_xor(s1, m); s2 += __shfl_xor(s2, m); }
  if (kc == 0) {
    double mu = s1 * (1.0 / NH_), var = s2 * (1.0 / NH_) - mu * mu;
    st[b][0] = mu; st[b][1] = 1.0 / sqrt(var + 1e-5);
  }
}

// One pipelined step t within domain d (8 dialogues b0=d*8..+8):
// gg(t)|eg(t-1)|wb(t-1)|head(t-2)|score(t-3).
__device__ void step_body(const Params& p, Smem& sm, int t, int d, int lid, int tid) {
  const int b0 = d * BP_;
  // ---------------- gg(t) (lid 0..31, 16 j each) ----------------
  if (lid < 32) {
    if (t < NS_) {
      const int jj0 = lid * 16;
      if (tid < BP_) {
        sm.spk[tid]  = p.spk[(b0 + tid) * NS_ + t];
        sm.spkp[tid] = (t > 0) ? p.spk[(b0 + tid) * NS_ + t - 1] : -1;
      }
      __syncthreads();
      const float* gprev = p.g_new + (size_t)((t - 1) & 1) * NB_ * NH_;
      for (int idx = tid; idx < BP_ * NH_ / 4; idx += 256) {
        int b = idx >> 7, k = (idx & 127) * 4;
        f4 v = (sm.spk[b] == sm.spkp[b])
                   ? ldA4(&gprev[(b0 + b) * NH_ + k])
                   : ldA4(&p.glob[(size_t)((b0 + b) * NSP_ + sm.spk[b]) * NH_ + k]);
        *(f4*)&sm.hA[b][k] = v;
      }
      __syncthreads();
      row_stats8(sm.hA, sm.stats, tid);
      __syncthreads();
      for (int idx = tid; idx < BP_ * NH_ / 4; idx += 256) {
        int b = idx >> 7, k = (idx & 127) * 4;
        if (sm.spk[b] == sm.spkp[b]) {
          f4 pv = *(f4*)&sm.hA[b][k];
          f4 g4 = *(const f4*)&p.ln_g[k], b4 = *(const f4*)&p.ln_b[k];
          double mu = sm.stats[b][0], rs = sm.stats[b][1];
          f4 v;
          v.x = (float)(((double)pv.x - mu) * rs * g4.x + b4.x);
          v.y = (float)(((double)pv.y - mu) * rs * g4.y + b4.y);
          v.z = (float)(((double)pv.z - mu) * rs * g4.z + b4.z);
          v.w = (float)(((double)pv.w - mu) * rs * g4.w + b4.w);
          *(f4*)&sm.hA[b][k] = v;
        }
      }
      __syncthreads();
      {
        int jj = tid >> 4, kc = tid & 15, j = jj0 + jj;
        const f4* Wr_w = (const f4*)(p.gg_wih + (size_t)j * 1536 + 1024);
        const f4* Wz_w = (const f4*)(p.gg_wih + (size_t)(512 + j) * 1536 + 1024);
        const f4* Wn_w = (const f4*)(p.gg_wih + (size_t)(1024 + j) * 1536 + 1024);
        const f4* Wr_h = (const f4*)(p.gg_whh + (size_t)j * 512);
        const f4* Wz_h = (const f4*)(p.gg_whh + (size_t)(512 + j) * 512);
        const f4* Wn_h = (const f4*)(p.gg_whh + (size_t)(1024 + j) * 512);
        const f4* H = (const f4*)&sm.hA[0][0];
        // SINGLE merged pass: r,z,n (32 fp64 acc, spill-free at BP_=8), unroll 4
        double ar[BP_] = {}, az[BP_] = {}, apn[BP_] = {}, aph[BP_] = {};
#pragma unroll 4
        for (int i = 0; i < 16; ++i) {
          int q = kc + 16 * i;
          f4 wr, wz, wn; int hq;
          if (i < 8) { wr = Wr_w[q]; wz = Wz_w[q]; wn = Wn_w[q]; hq = q; }
          else       { hq = q - 128; wr = Wr_h[hq]; wz = Wz_h[hq]; wn = Wn_h[hq]; }
#pragma unroll
          for (int b = 0; b < BP_; ++b) {
            f4 a = H[b * 130 + hq];
            ar[b] += dot4d(a, wr); az[b] += dot4d(a, wz);
            if (i < 8) apn[b] += dot4d(a, wn); else aph[b] += dot4d(a, wn);
          }
        }
#pragma unroll
        for (int b = 0; b < BP_; ++b) {
          double r = ar[b], z = az[b], pn = apn[b], ph = aph[b];
#pragma unroll
          for (int m = 1; m <= 8; m <<= 1) {
            r += __shfl_xor(r, m); z += __shfl_xor(z, m);
            pn += __shfl_xor(pn, m); ph += __shfl_xor(ph, m);
          }
          if (kc == 0) { sm.red[jj][b][0] = r; sm.red[jj][b][1] = z; sm.red[jj][b][2] = pn; sm.red[jj][b][3] = ph; }
        }
      }
      __syncthreads();
      if (tid < 128) {
        int b = tid >> 4, jj = tid & 15, j = jj0 + jj;
        const double* rd = sm.red[jj][b];
        const float* gx = p.gix + (size_t)((b0 + b) * NS_ + t) * 1536;
        double r = sigm_d(rd[0] + (double)gx[j] + (double)p.gg_bih[j] + (double)p.gg_bhh[j]);
        double z = sigm_d(rd[1] + (double)gx[512 + j] + (double)p.gg_bih[512 + j] + (double)p.gg_bhh[512 + j]);
        double inn = rd[2] + (double)gx[1024 + j] + (double)p.gg_bih[1024 + j];
        double hn  = rd[3] + (double)p.gg_bhh[1024 + j];
        double n = tanh(inn + r * hn);
        double hp = (double)sm.hA[b][j];
        double hv = (1.0 - z) * n + z * hp;
        stA1(&p.g_new[(size_t)(t & 1) * NB_ * NH_ + (b0 + b) * NH_ + j], (float)hv);
      }
    }
  }
  // ---------------- eg(t-1) (lid 32..63, 16 j each) ----------------
  else if (lid < 64) {
    if (t >= 1 && t <= NS_) {
      const int te = t - 1;
      const int jj0 = (lid - 32) * 16;
      const float* eprev = p.e_out + (size_t)((te - 1) & 1) * NB_ * NH_;
      const float* gcur  = p.g_new + (size_t)(te & 1) * NB_ * NH_;
      for (int idx = tid; idx < BP_ * NH_ / 2; idx += 256) {
        int half = idx >= BP_ * NH_ / 4;
        int r4 = idx & (BP_ * NH_ / 4 - 1);
        int b = r4 >> 7, k = (r4 & 127) * 4;
        if (!half) {
          f4 v = (te == 0) ? *(const f4*)&p.init_emotion[k] : ldA4(&eprev[(b0 + b) * NH_ + k]);
          *(f4*)&sm.hA[b][k] = v;
        } else {
          *(f4*)&sm.hB[b][k] = ldA4(&gcur[(b0 + b) * NH_ + k]);
        }
      }
      __syncthreads();
      {
        int b = tid >> 5, kc = tid & 31;
        double a1 = 0, a2 = 0, b1 = 0, b2 = 0;
#pragma unroll
        for (int i = 0; i < 16; ++i) {
          double xa = (double)sm.hA[b][kc + i * 32];
          double xb = (double)sm.hB[b][kc + i * 32];
          a1 += xa; a2 += xa * xa; b1 += xb; b2 += xb * xb;
        }
#pragma unroll
        for (int m = 1; m <= 16; m <<= 1) {
          a1 += __shfl_xor(a1, m); a2 += __shfl_xor(a2, m);
          b1 += __shfl_xor(b1, m); b2 += __shfl_xor(b2, m);
        }
        if (kc == 0) {
          double mu = a1 * (1.0 / NH_), var = a2 * (1.0 / NH_) - mu * mu;
          sm.stats[b][0] = mu; sm.stats[b][1] = 1.0 / sqrt(var + 1e-5);
          mu = b1 * (1.0 / NH_); var = b2 * (1.0 / NH_) - mu * mu;
          sm.stats2[b][0] = mu; sm.stats2[b][1] = 1.0 / sqrt(var + 1e-5);
        }
      }
      __syncthreads();
      for (int idx = tid; idx < BP_ * NH_ / 2; idx += 256) {
        int half = idx >= BP_ * NH_ / 4;
        int r4 = idx & (BP_ * NH_ / 4 - 1);
        int b = r4 >> 7, k = (r4 & 127) * 4;
        f4 g4 = *(const f4*)&p.ln_g[k], b4 = *(const f4*)&p.ln_b[k];
        if (!half) {
          if (te > 0) {
            f4 pv = *(f4*)&sm.hA[b][k];
            double mu = sm.stats[b][0], rs = sm.stats[b][1];
            f4 v;
            v.x = (float)(((double)pv.x - mu) * rs * g4.x + b4.x);
            v.y = (float)(((double)pv.y - mu) * rs * g4.y + b4.y);
            v.z = (float)(((double)pv.z - mu) * rs * g4.z + b4.z);
            v.w = (float)(((double)pv.w - mu) * rs * g4.w + b4.w);
            *(f4*)&sm.hA[b][k] = v;
          }
        } else {
          f4 pv = *(f4*)&sm.hB[b][k];
          double mu = sm.stats2[b][0], rs = sm.stats2[b][1];
          f4 v;
          v.x = (float)(((double)pv.x - mu) * rs * g4.x + b4.x);
          v.y = (float)(((double)pv.y - mu) * rs * g4.y + b4.y);
          v.z = (float)(((double)pv.z - mu) * rs * g4.z + b4.z);
          v.w = (float)(((double)pv.w - mu) * rs * g4.w + b4.w);
          *(f4*)&sm.hB[b][k] = v;
        }
      }
      __syncthreads();
      {
        int jj = tid >> 4, kc = tid & 15, j = jj0 + jj;
        const f4* Wr_w = (const f4*)(p.eg_wih + (size_t)j * 1024);
        const f4* Wz_w = (const f4*)(p.eg_wih + (size_t)(512 + j) * 1024);
        const f4* Wn_w = (const f4*)(p.eg_wih + (size_t)(1024 + j) * 1024);
        const f4* Wr_h = (const f4*)(p.eg_whh + (size_t)j * 512);
        const f4* Wz_h = (const f4*)(p.eg_whh + (size_t)(512 + j) * 512);
        const f4* Wn_h = (const f4*)(p.eg_whh + (size_t)(1024 + j) * 512);
        const f4* HA = (const f4*)&sm.hA[0][0];
        const f4* HB = (const f4*)&sm.hB[0][0];
        // SINGLE merged pass: r,z,n (32 fp64 acc), unroll 4
        double ar[BP_] = {}, az[BP_] = {}, apn[BP_] = {}, aph[BP_] = {};
#pragma unroll 4
        for (int i = 0; i < 24; ++i) {
          int q = kc + 16 * i;
          f4 wr, wz, wn; const f4* Ab; int hq;
          if (i < 16) { wr = Wr_w[q]; wz = Wz_w[q]; wn = Wn_w[q]; }
          else        { wr = Wr_h[q - 256]; wz = Wz_h[q - 256]; wn = Wn_h[q - 256]; }
          if (i < 8)       { Ab = HA; hq = q; }
          else if (i < 16) { Ab = HB; hq = q - 128; }
          else             { Ab = HA; hq = q - 256; }
#pragma unroll
          for (int b = 0; b < BP_; ++b) {
            f4 a = Ab[b * 130 + hq];
            ar[b] += dot4d(a, wr); az[b] += dot4d(a, wz);
            if (i < 16) apn[b] += dot4d(a, wn); else aph[b] += dot4d(a, wn);
          }
        }
#pragma unroll
        for (int b = 0; b < BP_; ++b) {
          double r = ar[b], z = az[b], pn = apn[b], ph = aph[b];
#pragma unroll
          for (int m = 1; m <= 8; m <<= 1) {
            r += __shfl_xor(r, m); z += __shfl_xor(z, m);
            pn += __shfl_xor(pn, m); ph += __shfl_xor(ph, m);
          }
          if (kc == 0) { sm.red[jj][b][0] = r; sm.red[jj][b][1] = z; sm.red[jj][b][2] = pn; sm.red[jj][b][3] = ph; }
        }
      }
      __syncthreads();
      if (tid < 128) {
        int b = tid >> 4, jj = tid & 15, j = jj0 + jj;
        const double* rd = sm.red[jj][b];
        double r = sigm_d(rd[0] + (double)p.eg_bih[j] + (double)p.eg_bhh[j]);
        double z = sigm_d(rd[1] + (double)p.eg_bih[512 + j] + (double)p.eg_bhh[512 + j]);
        double inn = rd[2] + (double)p.eg_bih[1024 + j];
        double hn  = rd[3] + (double)p.eg_bhh[1024 + j];
        double n = tanh(inn + r * hn);
        double hp = (double)sm.hA[b][j];
        double hv = (1.0 - z) * n + z * hp;
        stA1(&p.e_out[(size_t)(te & 1) * NB_ * NH_ + (b0 + b) * NH_ + j], (float)hv);
      }
    }
  }
  // ---------------- wb(t-1): one block per local b (lid 64..71) ----------------
  else if (lid < 72) {
    if (t >= 1 && t <= NS_) {
      int b = b0 + (lid - 64), tw = t - 1;
      int spv = p.spk[b * NS_ + tw];
      const float* gsrc = p.g_new + (size_t)(tw & 1) * NB_ * NH_;
      float2 gv = ldA2(&gsrc[b * NH_ + tid * 2]);
      double s1 = (double)gv.x + (double)gv.y;
      double s2 = (double)gv.x * (double)gv.x + (double)gv.y * (double)gv.y;
#pragma unroll
      for (int m = 1; m <= 32; m <<= 1) { s1 += __shfl_xor(s1, m); s2 += __shfl_xor(s2, m); }
      int wid = tid >> 6;
      if ((tid & 63) == 0) { sm.redH[0][wid] = s1; sm.redH[1][wid] = s2; }
      __syncthreads();
      if (tid == 0) {
        double ts1 = sm.redH[0][0] + sm.redH[0][1] + sm.redH[0][2] + sm.redH[0][3];
        double ts2 = sm.redH[1][0] + sm.redH[1][1] + sm.redH[1][2] + sm.redH[1][3];
        double mu = ts1 * (1.0 / NH_), var = ts2 * (1.0 / NH_) - mu * mu;
        sm.stats[0][0] = mu; sm.stats[0][1] = 1.0 / sqrt(var + 1e-5);
      }
      __syncthreads();
      double mu = sm.stats[0][0], rs = sm.stats[0][1];
      float* gd = p.glob + (size_t)(b * NSP_ + spv) * NH_;
      int k2 = tid * 2;
      double o0 = ((double)gv.x - mu) * rs * p.ln_g[k2] + p.ln_b[k2];
      double o1 = ((double)gv.y - mu) * rs * p.ln_g[k2 + 1] + p.ln_b[k2 + 1];
      stA2(&gd[k2], (float)o0, (float)o1);
    }
  }
  // ---------------- head(t-2) (lid 72..79, 32 c each) ----------------
  else if (lid < 80) {
    if (t >= 2 && t <= NS_ + 1) {
      int th = t - 2, ct = lid - 72;
      const float* er = p.e_out + (size_t)(th & 1) * NB_ * NH_;
      for (int idx = tid; idx < BP_ * NH_ / 4; idx += 256) {
        int b = idx >> 7, k = (idx & 127) * 4;
        *(f4*)&sm.hA[b][k] = ldA4(&er[(b0 + b) * NH_ + k]);
      }
      __syncthreads();
      {
        int ci = tid >> 3, kc = tid & 7, c = ct * 32 + ci;
        const f4* W = (const f4*)(p.out_w1 + (size_t)c * 512);
        const f4* H = (const f4*)&sm.hA[0][0];
        double acc[BP_] = {};
#pragma unroll 4
        for (int i = 0; i < 16; ++i) {
          int q = kc + 8 * i;
          f4 w = W[q];
#pragma unroll
          for (int b = 0; b < BP_; ++b) acc[b] += dot4d(H[b * 130 + q], w);
        }
#pragma unroll
        for (int b = 0; b < BP_; ++b) {
          double v = acc[b];
#pragma unroll
          for (int m = 1; m <= 4; m <<= 1) v += __shfl_xor(v, m);
          if (kc == 0) sm.redH[ci][b] = v;
        }
      }
      __syncthreads();
      {
        int b = tid >> 5, ci = tid & 31, c = ct * 32 + ci;
        double h1 = sm.redH[ci][b] + (double)p.out_b1[c];
        stA1(&p.h1buf[(size_t)(th & 1) * NB_ * NH2_ + (b0 + b) * NH2_ + c], (float)fmax(h1, 0.0));
      }
    }
  }
  // ---------------- score(t-3) (lid 80) ----------------
  else {
    if (t >= 3 && t <= NS_ + 2 && tid < 128) {
      int ts = t - 3;
      int b = tid >> 4, cg = tid & 15;
      const float* h1p = p.h1buf + (size_t)(ts & 1) * NB_ * NH2_;
      double s1 = 0, s2 = 0;
      float hv[16];
#pragma unroll
      for (int i = 0; i < 16; ++i) {
        float v = ldA1(&h1p[(b0 + b) * NH2_ + cg * 16 + i]);
        hv[i] = v; s1 += (double)v; s2 += (double)v * (double)v;
      }
#pragma unroll
      for (int m = 1; m <= 8; m <<= 1) { s1 += __shfl_xor(s1, m); s2 += __shfl_xor(s2, m); }
      double mu = s1 * (1.0 / NH2_), var = s2 * (1.0 / NH2_) - mu * mu, rstd = 1.0 / sqrt(var + 1e-5);
      double d = 0;
#pragma unroll
      for (int i = 0; i < 16; ++i) {
        int c = cg * 16 + i;
        d += (((double)hv[i] - mu) * rstd * p.out_ln_g[c] + (double)p.out_ln_b[c]) * (double)p.out_w2[c];
      }
#pragma unroll
      for (int m = 1; m <= 8; m <<= 1) d += __shfl_xor(d, m);
      if (cg == 0) p.out[(b0 + b) * NS_ + ts] = (float)sigm_d(d + (double)p.out_b2[0]);
    }
  }
}

__global__ __launch_bounds__(256, 1) void seq_kernel(Params p) {
  const int bid = blockIdx.x, tid = threadIdx.x;
  const int d = bid / DBLK, lid = bid - d * DBLK;
  __shared__ Smem sm;
  u32* flags = p.flags + (size_t)d * DBLK * 16;
  u32* rel   = p.rel   + (size_t)d * DBLK * 16;
  for (int t = 0; t <= NS_ + 2; ++t) {
    step_body(p, sm, t, d, lid, tid);
    gbar3(flags, rel, lid, DBLK, (u32)(t + 1));
  }
}

// gg x-projection precompute: gix[bs][row] = sum_k utt[bs][k] * gg_wih[row][k], k<1024 (fp64)
__global__ __launch_bounds__(512) void gix_kernel(const float* utt, const float* ggw, float* gix) {
  __shared__ float xs[16][1028];
  const int tid = threadIdx.x;
  long bs0 = (long)blockIdx.x * 16;
  for (int i = tid; i < 16 * 256; i += 512) {
    int bb = i >> 8, kf = i & 255;
    *(f4*)&xs[bb][kf * 4] = *(const f4*)(utt + (bs0 + bb) * 1024 + kf * 4);
  }
  __syncthreads();
  int R = blockIdx.y * 32 + (tid >> 4);
  int bi = tid & 15;
  const f4* w4 = (const f4*)(ggw + (size_t)R * 1536);
  const f4* x4 = (const f4*)&xs[bi][0];
  double acc = 0;
  for (int k = 0; k < 256; ++k) acc += dot4d(x4[k], w4[k]);
  gix[(size_t)(bs0 + bi) * 1536 + R] = (float)acc;
}

__global__ void init_kernel(float* glob, const float* init_global, u32* flags, u32* rel) {
  long stride = (long)gridDim.x * blockDim.x;
  long t0 = (long)blockIdx.x * blockDim.x + threadIdx.x;
  for (long i = t0; i < (long)NB_ * NSP_ * NH_; i += stride) {
    int sp = ((int)i >> 9) & (NSP_ - 1);
    int k = (int)i & (NH_ - 1);
    glob[i] = init_global[sp * NH_ + k];
  }
  for (long i = t0; i < (long)NBLK * 16; i += stride) { flags[i] = 0u; rel[i] = 0u; }
}

extern "C" void kernel_launch(void* const* d_in, const int* in_sizes, int n_in,
                              void* d_out, int out_size, void* d_ws, size_t ws_size,
                              hipStream_t stream) {
  (void)in_sizes; (void)n_in; (void)out_size;
  Params p;
  p.utt    = (const float*)d_in[0];
  p.spk    = (const int*)d_in[1];
  // d_in[2] init_party: DEAD (party GRU feeds only itself, never the output path)
  const float* ig = (const float*)d_in[3];
  p.init_emotion = (const float*)d_in[4];
  // d_in[5..8] pg_*: DEAD (party GRU)
  p.gg_wih = (const float*)d_in[9];
  p.gg_whh = (const float*)d_in[10];
  p.gg_bih = (const float*)d_in[11];
  p.gg_bhh = (const float*)d_in[12];
  p.eg_wih = (const float*)d_in[13];
  p.eg_whh = (const float*)d_in[14];
  p.eg_bih = (const float*)d_in[15];
  p.eg_bhh = (const float*)d_in[16];
  // 17..19 attention weights: softmax over length-1 axis == 1 -> provably unused
  p.ln_g   = (const float*)d_in[20];
  p.ln_b   = (const float*)d_in[21];
  p.out_w1 = (const float*)d_in[22];
  p.out_b1 = (const float*)d_in[23];
  p.out_ln_g = (const float*)d_in[24];
  p.out_ln_b = (const float*)d_in[25];
  p.out_w2 = (const float*)d_in[26];
  p.out_b2 = (const float*)d_in[27];

  char* w = (char*)d_ws;
  auto alloc = [&](size_t bytes) { char* r = w; w += (bytes + 255) & ~(size_t)255; return r; };
  float* gix   = (float*)alloc((size_t)8192 * 1536 * 4);   // ~50.3 MB
  float* g_new = (float*)alloc((size_t)2 * NB_ * NH_ * 4);
  float* e_out = (float*)alloc((size_t)2 * NB_ * NH_ * 4);
  float* glob  = (float*)alloc((size_t)NB_ * NSP_ * NH_ * 4);
  float* h1buf = (float*)alloc((size_t)2 * NB_ * NH2_ * 4);
  u32*   flags = (u32*)alloc((size_t)NBLK * 16 * 4);
  u32*   rel   = (u32*)alloc((size_t)NBLK * 16 * 4);
  if ((size_t)(w - (char*)d_ws) > ws_size) return;  // ws too small -> loud failure (zeros)

  gix_kernel<<<dim3(512, 48), dim3(512), 0, stream>>>(p.utt, p.gg_wih, gix);
  init_kernel<<<dim3(64), dim3(256), 0, stream>>>(glob, ig, flags, rel);

  p.gix = gix;
  p.g_new = g_new; p.e_out = e_out; p.glob = glob;
  p.h1buf = h1buf; p.flags = flags; p.rel = rel; p.out = (float*)d_out;

  seq_kernel<<<dim3(NBLK), dim3(256), 0, stream>>>(p);
}

// Round 22
// 11802.016 us; speedup vs baseline: 7.1840x; 1.2498x over previous
//
#include <hip/hip_runtime.h>

typedef __attribute__((ext_vector_type(4))) float f4;
using u32 = unsigned int;
using u64 = unsigned long long;

constexpr int NB_ = 16;    // total batch
constexpr int BP_ = 8;     // batch per domain
constexpr int NS_ = 512;   // seq len
constexpr int ND_ = 1024;  // input dim
constexpr int NH_ = 512;   // hidden
constexpr int NSP_ = 8;    // speakers
constexpr int NH2_ = 256;  // head hidden
constexpr int HP = 520;    // padded fp32 LDS row (130 f4)
constexpr int DBLK = 113;  // blocks per domain: gg 32 | eg 64 | wb 8 | head 8 | score 1
constexpr int NBLK = 226;  // two independent domains

struct Params {
  const float *utt;
  const float *gg_wih, *gg_whh, *eg_wih, *eg_whh, *out_w1;
  const float *gix;           // precomputed gg x-projection [B*S][1536] fp32
  const float *init_emotion;
  const float *gg_bih, *gg_bhh, *eg_bih, *eg_bhh;
  const float *ln_g, *ln_b, *out_b1, *out_ln_g, *out_ln_b, *out_w2, *out_b2;
  const int *spk;
  float *g_new;      // [2][B][H] raw gg output, parity t&1
  float *e_out;      // [2][B][H] raw eg output, parity te&1
  float *glob;       // [B][SP][H] post-LN (or raw init) global states
  float *h1buf;      // [2][B][H2] relu(e@W1+b1), parity th&1
  u32 *flags;        // [2][DBLK*16] arrival flags, one 64B line per block
  u32 *rel;          // [2][DBLK*16] per-block release lines
  float *out;        // [B][S]
};

__device__ __forceinline__ double sigm_d(double x) { return 1.0 / (1.0 + exp(-x)); }
__device__ __forceinline__ double dot4d(f4 a, f4 w) {
  return ((double)a.x * w.x + (double)a.y * w.y) + ((double)a.z * w.z + (double)a.w * w.w);
}

// ---- cross-block plumbing: relaxed agent-scope atomics (bypass per-XCD L2; no flushes) ----
__device__ __forceinline__ void stA1(float* p, float v) {
  __hip_atomic_store(p, v, __ATOMIC_RELAXED, __HIP_MEMORY_SCOPE_AGENT);
}
__device__ __forceinline__ float ldA1(const float* p) {
  return __hip_atomic_load((float*)p, __ATOMIC_RELAXED, __HIP_MEMORY_SCOPE_AGENT);
}
__device__ __forceinline__ void stA2(float* p, float a, float b) {
  union { float f[2]; u64 u; } x; x.f[0] = a; x.f[1] = b;
  __hip_atomic_store((u64*)p, x.u, __ATOMIC_RELAXED, __HIP_MEMORY_SCOPE_AGENT);
}
__device__ __forceinline__ float2 ldA2(const float* p) {
  u64 u = __hip_atomic_load((u64*)p, __ATOMIC_RELAXED, __HIP_MEMORY_SCOPE_AGENT);
  union { u64 u; float f[2]; } x; x.u = u;
  return make_float2(x.f[0], x.f[1]);
}
__device__ __forceinline__ f4 ldA4(const float* p) {
  float2 lo = ldA2(p), hi = ldA2(p + 2);
  f4 v; v.x = lo.x; v.y = lo.y; v.z = hi.x; v.w = hi.y;
  return v;
}

// Distributed flag barrier over one domain's DBLK blocks (R17-validated pattern).
__device__ __forceinline__ void gbar3(u32* flags, u32* rel, int lid, int nb, u32 epoch) {
  __syncthreads();
  const int tid = threadIdx.x;
  if (lid == 0) {
    if (tid > 0 && tid < nb) {
      while (__hip_atomic_load(&flags[(size_t)tid * 16], __ATOMIC_RELAXED, __HIP_MEMORY_SCOPE_AGENT) < epoch)
        __builtin_amdgcn_s_sleep(1);
    }
    __syncthreads();
    if (tid < nb) {
      asm volatile("s_waitcnt vmcnt(0)" ::: "memory");
      __hip_atomic_store(&rel[(size_t)tid * 16], epoch, __ATOMIC_RELAXED, __HIP_MEMORY_SCOPE_AGENT);
    }
  } else {
    if (tid == 0) {
      asm volatile("s_waitcnt vmcnt(0) lgkmcnt(0)" ::: "memory");
      __hip_atomic_store(&flags[(size_t)lid * 16], epoch, __ATOMIC_RELAXED, __HIP_MEMORY_SCOPE_AGENT);
      while (__hip_atomic_load(&rel[(size_t)lid * 16], __ATOMIC_RELAXED, __HIP_MEMORY_SCOPE_AGENT) < epoch)
        __builtin_amdgcn_s_sleep(2);
    }
  }
  __syncthreads();
}

struct __align__(16) Smem {
  float hA[BP_][HP];
  float hB[BP_][HP];
  double red[16][BP_][4];
  double redH[32][BP_];
  double stats[BP_][2];
  double stats2[BP_][2];
  int spk[BP_], spkp[BP_];
};

// block-local per-b stats: 256 threads = (b 8, kc 32), 16 elems each, shfl over 32 lanes
__device__ __forceinline__ void row_stats8(const float (*h)[HP], double (*st)[2], int tid) {
  int b = tid >> 5, kc = tid & 31;
  double s1 = 0, s2 = 0;
#pragma unroll
  for (int i = 0; i < 16; ++i) {
    double x = (double)h[b][kc + i * 32];
    s1 += x; s2 += x * x;
  }
#pragma unroll
  for (int m = 1; m <= 16; m <<= 1) { s1 += __shfl_xor(s1, m); s2 += __shfl_xor(s2, m); }
  if (kc == 0) {
    double mu = s1 * (1.0 / NH_), var = s2 * (1.0 / NH_) - mu * mu;
    st[b][0] = mu; st[b][1] = 1.0 / sqrt(var + 1e-5);
  }
}

// One pipelined step t within domain d (8 dialogues b0=d*8..+8):
// gg(t)|eg(t-1)|wb(t-1)|head(t-2)|score(t-3).
__device__ void step_body(const Params& p, Smem& sm, int t, int d, int lid, int tid) {
  const int b0 = d * BP_;
  // ---------------- gg(t) (lid 0..31, 16 j each) ----------------
  if (lid < 32) {
    if (t < NS_) {
      const int jj0 = lid * 16;
      if (tid < BP_) {
        sm.spk[tid]  = p.spk[(b0 + tid) * NS_ + t];
        sm.spkp[tid] = (t > 0) ? p.spk[(b0 + tid) * NS_ + t - 1] : -1;
      }
      __syncthreads();
      const float* gprev = p.g_new + (size_t)((t - 1) & 1) * NB_ * NH_;
      for (int idx = tid; idx < BP_ * NH_ / 4; idx += 256) {
        int b = idx >> 7, k = (idx & 127) * 4;
        f4 v = (sm.spk[b] == sm.spkp[b])
                   ? ldA4(&gprev[(b0 + b) * NH_ + k])
                   : ldA4(&p.glob[(size_t)((b0 + b) * NSP_ + sm.spk[b]) * NH_ + k]);
        *(f4*)&sm.hA[b][k] = v;
      }
      __syncthreads();
      row_stats8(sm.hA, sm.stats, tid);
      __syncthreads();
      for (int idx = tid; idx < BP_ * NH_ / 4; idx += 256) {
        int b = idx >> 7, k = (idx & 127) * 4;
        if (sm.spk[b] == sm.spkp[b]) {
          f4 pv = *(f4*)&sm.hA[b][k];
          f4 g4 = *(const f4*)&p.ln_g[k], b4 = *(const f4*)&p.ln_b[k];
          double mu = sm.stats[b][0], rs = sm.stats[b][1];
          f4 v;
          v.x = (float)(((double)pv.x - mu) * rs * g4.x + b4.x);
          v.y = (float)(((double)pv.y - mu) * rs * g4.y + b4.y);
          v.z = (float)(((double)pv.z - mu) * rs * g4.z + b4.z);
          v.w = (float)(((double)pv.w - mu) * rs * g4.w + b4.w);
          *(f4*)&sm.hA[b][k] = v;
        }
      }
      __syncthreads();
      {
        int jj = tid >> 4, kc = tid & 15, j = jj0 + jj;
        const f4* Wr_w = (const f4*)(p.gg_wih + (size_t)j * 1536 + 1024);
        const f4* Wz_w = (const f4*)(p.gg_wih + (size_t)(512 + j) * 1536 + 1024);
        const f4* Wn_w = (const f4*)(p.gg_wih + (size_t)(1024 + j) * 1536 + 1024);
        const f4* Wr_h = (const f4*)(p.gg_whh + (size_t)j * 512);
        const f4* Wz_h = (const f4*)(p.gg_whh + (size_t)(512 + j) * 512);
        const f4* Wn_h = (const f4*)(p.gg_whh + (size_t)(1024 + j) * 512);
        const f4* H = (const f4*)&sm.hA[0][0];
        double ar[BP_] = {}, az[BP_] = {}, apn[BP_] = {}, aph[BP_] = {};
#pragma unroll 4
        for (int i = 0; i < 16; ++i) {
          int q = kc + 16 * i;
          f4 wr, wz, wn; int hq;
          if (i < 8) { wr = Wr_w[q]; wz = Wz_w[q]; wn = Wn_w[q]; hq = q; }
          else       { hq = q - 128; wr = Wr_h[hq]; wz = Wz_h[hq]; wn = Wn_h[hq]; }
#pragma unroll
          for (int b = 0; b < BP_; ++b) {
            f4 a = H[b * 130 + hq];
            ar[b] += dot4d(a, wr); az[b] += dot4d(a, wz);
            if (i < 8) apn[b] += dot4d(a, wn); else aph[b] += dot4d(a, wn);
          }
        }
#pragma unroll
        for (int b = 0; b < BP_; ++b) {
          double r = ar[b], z = az[b], pn = apn[b], ph = aph[b];
#pragma unroll
          for (int m = 1; m <= 8; m <<= 1) {
            r += __shfl_xor(r, m); z += __shfl_xor(z, m);
            pn += __shfl_xor(pn, m); ph += __shfl_xor(ph, m);
          }
          if (kc == 0) { sm.red[jj][b][0] = r; sm.red[jj][b][1] = z; sm.red[jj][b][2] = pn; sm.red[jj][b][3] = ph; }
        }
      }
      __syncthreads();
      if (tid < 128) {
        int b = tid >> 4, jj = tid & 15, j = jj0 + jj;
        const double* rd = sm.red[jj][b];
        const float* gx = p.gix + (size_t)((b0 + b) * NS_ + t) * 1536;
        double r = sigm_d(rd[0] + (double)gx[j] + (double)p.gg_bih[j] + (double)p.gg_bhh[j]);
        double z = sigm_d(rd[1] + (double)gx[512 + j] + (double)p.gg_bih[512 + j] + (double)p.gg_bhh[512 + j]);
        double inn = rd[2] + (double)gx[1024 + j] + (double)p.gg_bih[1024 + j];
        double hn  = rd[3] + (double)p.gg_bhh[1024 + j];
        double n = tanh(inn + r * hn);
        double hp = (double)sm.hA[b][j];
        double hv = (1.0 - z) * n + z * hp;
        stA1(&p.g_new[(size_t)(t & 1) * NB_ * NH_ + (b0 + b) * NH_ + j], (float)hv);
      }
    }
  }
  // ---------------- eg(t-1) (lid 32..95, 8 j each) ----------------
  else if (lid < 96) {
    if (t >= 1 && t <= NS_) {
      const int te = t - 1;
      const int jj0 = (lid - 32) * 8;
      const float* eprev = p.e_out + (size_t)((te - 1) & 1) * NB_ * NH_;
      const float* gcur  = p.g_new + (size_t)(te & 1) * NB_ * NH_;
      for (int idx = tid; idx < BP_ * NH_ / 2; idx += 256) {
        int half = idx >= BP_ * NH_ / 4;
        int r4 = idx & (BP_ * NH_ / 4 - 1);
        int b = r4 >> 7, k = (r4 & 127) * 4;
        if (!half) {
          f4 v = (te == 0) ? *(const f4*)&p.init_emotion[k] : ldA4(&eprev[(b0 + b) * NH_ + k]);
          *(f4*)&sm.hA[b][k] = v;
        } else {
          *(f4*)&sm.hB[b][k] = ldA4(&gcur[(b0 + b) * NH_ + k]);
        }
      }
      __syncthreads();
      {
        int b = tid >> 5, kc = tid & 31;
        double a1 = 0, a2 = 0, b1 = 0, b2 = 0;
#pragma unroll
        for (int i = 0; i < 16; ++i) {
          double xa = (double)sm.hA[b][kc + i * 32];
          double xb = (double)sm.hB[b][kc + i * 32];
          a1 += xa; a2 += xa * xa; b1 += xb; b2 += xb * xb;
        }
#pragma unroll
        for (int m = 1; m <= 16; m <<= 1) {
          a1 += __shfl_xor(a1, m); a2 += __shfl_xor(a2, m);
          b1 += __shfl_xor(b1, m); b2 += __shfl_xor(b2, m);
        }
        if (kc == 0) {
          double mu = a1 * (1.0 / NH_), var = a2 * (1.0 / NH_) - mu * mu;
          sm.stats[b][0] = mu; sm.stats[b][1] = 1.0 / sqrt(var + 1e-5);
          mu = b1 * (1.0 / NH_); var = b2 * (1.0 / NH_) - mu * mu;
          sm.stats2[b][0] = mu; sm.stats2[b][1] = 1.0 / sqrt(var + 1e-5);
        }
      }
      __syncthreads();
      for (int idx = tid; idx < BP_ * NH_ / 2; idx += 256) {
        int half = idx >= BP_ * NH_ / 4;
        int r4 = idx & (BP_ * NH_ / 4 - 1);
        int b = r4 >> 7, k = (r4 & 127) * 4;
        f4 g4 = *(const f4*)&p.ln_g[k], b4 = *(const f4*)&p.ln_b[k];
        if (!half) {
          if (te > 0) {
            f4 pv = *(f4*)&sm.hA[b][k];
            double mu = sm.stats[b][0], rs = sm.stats[b][1];
            f4 v;
            v.x = (float)(((double)pv.x - mu) * rs * g4.x + b4.x);
            v.y = (float)(((double)pv.y - mu) * rs * g4.y + b4.y);
            v.z = (float)(((double)pv.z - mu) * rs * g4.z + b4.z);
            v.w = (float)(((double)pv.w - mu) * rs * g4.w + b4.w);
            *(f4*)&sm.hA[b][k] = v;
          }
        } else {
          f4 pv = *(f4*)&sm.hB[b][k];
          double mu = sm.stats2[b][0], rs = sm.stats2[b][1];
          f4 v;
          v.x = (float)(((double)pv.x - mu) * rs * g4.x + b4.x);
          v.y = (float)(((double)pv.y - mu) * rs * g4.y + b4.y);
          v.z = (float)(((double)pv.z - mu) * rs * g4.z + b4.z);
          v.w = (float)(((double)pv.w - mu) * rs * g4.w + b4.w);
          *(f4*)&sm.hB[b][k] = v;
        }
      }
      __syncthreads();
      {
        // 8 j per block: (jj 8 x kc 32) = 256 threads, 12 rolled iterations
        int jj = tid >> 5, kc = tid & 31, j = jj0 + jj;
        const f4* Wr_w = (const f4*)(p.eg_wih + (size_t)j * 1024);
        const f4* Wz_w = (const f4*)(p.eg_wih + (size_t)(512 + j) * 1024);
        const f4* Wn_w = (const f4*)(p.eg_wih + (size_t)(1024 + j) * 1024);
        const f4* Wr_h = (const f4*)(p.eg_whh + (size_t)j * 512);
        const f4* Wz_h = (const f4*)(p.eg_whh + (size_t)(512 + j) * 512);
        const f4* Wn_h = (const f4*)(p.eg_whh + (size_t)(1024 + j) * 512);
        const f4* HA = (const f4*)&sm.hA[0][0];
        const f4* HB = (const f4*)&sm.hB[0][0];
        double ar[BP_] = {}, az[BP_] = {}, apn[BP_] = {}, aph[BP_] = {};
#pragma unroll 4
        for (int i = 0; i < 12; ++i) {
          int q = kc + 32 * i;
          f4 wr, wz, wn; const f4* Ab; int hq;
          if (i < 8) { wr = Wr_w[q]; wz = Wz_w[q]; wn = Wn_w[q]; }
          else       { wr = Wr_h[q - 256]; wz = Wz_h[q - 256]; wn = Wn_h[q - 256]; }
          if (i < 4)      { Ab = HA; hq = q; }
          else if (i < 8) { Ab = HB; hq = q - 128; }
          else            { Ab = HA; hq = q - 256; }
#pragma unroll
          for (int b = 0; b < BP_; ++b) {
            f4 a = Ab[b * 130 + hq];
            ar[b] += dot4d(a, wr); az[b] += dot4d(a, wz);
            if (i < 8) apn[b] += dot4d(a, wn); else aph[b] += dot4d(a, wn);
          }
        }
#pragma unroll
        for (int b = 0; b < BP_; ++b) {
          double r = ar[b], z = az[b], pn = apn[b], ph = aph[b];
#pragma unroll
          for (int m = 1; m <= 16; m <<= 1) {
            r += __shfl_xor(r, m); z += __shfl_xor(z, m);
            pn += __shfl_xor(pn, m); ph += __shfl_xor(ph, m);
          }
          if (kc == 0) { sm.red[jj][b][0] = r; sm.red[jj][b][1] = z; sm.red[jj][b][2] = pn; sm.red[jj][b][3] = ph; }
        }
      }
      __syncthreads();
      if (tid < 64) {
        int b = tid >> 3, jj = tid & 7, j = jj0 + jj;
        const double* rd = sm.red[jj][b];
        double r = sigm_d(rd[0] + (double)p.eg_bih[j] + (double)p.eg_bhh[j]);
        double z = sigm_d(rd[1] + (double)p.eg_bih[512 + j] + (double)p.eg_bhh[512 + j]);
        double inn = rd[2] + (double)p.eg_bih[1024 + j];
        double hn  = rd[3] + (double)p.eg_bhh[1024 + j];
        double n = tanh(inn + r * hn);
        double hp = (double)sm.hA[b][j];
        double hv = (1.0 - z) * n + z * hp;
        stA1(&p.e_out[(size_t)(te & 1) * NB_ * NH_ + (b0 + b) * NH_ + j], (float)hv);
      }
    }
  }
  // ---------------- wb(t-1): one block per local b (lid 96..103) ----------------
  else if (lid < 104) {
    if (t >= 1 && t <= NS_) {
      int b = b0 + (lid - 96), tw = t - 1;
      int spv = p.spk[b * NS_ + tw];
      const float* gsrc = p.g_new + (size_t)(tw & 1) * NB_ * NH_;
      float2 gv = ldA2(&gsrc[b * NH_ + tid * 2]);
      double s1 = (double)gv.x + (double)gv.y;
      double s2 = (double)gv.x * (double)gv.x + (double)gv.y * (double)gv.y;
#pragma unroll
      for (int m = 1; m <= 32; m <<= 1) { s1 += __shfl_xor(s1, m); s2 += __shfl_xor(s2, m); }
      int wid = tid >> 6;
      if ((tid & 63) == 0) { sm.redH[0][wid] = s1; sm.redH[1][wid] = s2; }
      __syncthreads();
      if (tid == 0) {
        double ts1 = sm.redH[0][0] + sm.redH[0][1] + sm.redH[0][2] + sm.redH[0][3];
        double ts2 = sm.redH[1][0] + sm.redH[1][1] + sm.redH[1][2] + sm.redH[1][3];
        double mu = ts1 * (1.0 / NH_), var = ts2 * (1.0 / NH_) - mu * mu;
        sm.stats[0][0] = mu; sm.stats[0][1] = 1.0 / sqrt(var + 1e-5);
      }
      __syncthreads();
      double mu = sm.stats[0][0], rs = sm.stats[0][1];
      float* gd = p.glob + (size_t)(b * NSP_ + spv) * NH_;
      int k2 = tid * 2;
      double o0 = ((double)gv.x - mu) * rs * p.ln_g[k2] + p.ln_b[k2];
      double o1 = ((double)gv.y - mu) * rs * p.ln_g[k2 + 1] + p.ln_b[k2 + 1];
      stA2(&gd[k2], (float)o0, (float)o1);
    }
  }
  // ---------------- head(t-2) (lid 104..111, 32 c each) ----------------
  else if (lid < 112) {
    if (t >= 2 && t <= NS_ + 1) {
      int th = t - 2, ct = lid - 104;
      const float* er = p.e_out + (size_t)(th & 1) * NB_ * NH_;
      for (int idx = tid; idx < BP_ * NH_ / 4; idx += 256) {
        int b = idx >> 7, k = (idx & 127) * 4;
        *(f4*)&sm.hA[b][k] = ldA4(&er[(b0 + b) * NH_ + k]);
      }
      __syncthreads();
      {
        int ci = tid >> 3, kc = tid & 7, c = ct * 32 + ci;
        const f4* W = (const f4*)(p.out_w1 + (size_t)c * 512);
        const f4* H = (const f4*)&sm.hA[0][0];
        double acc[BP_] = {};
#pragma unroll 4
        for (int i = 0; i < 16; ++i) {
          int q = kc + 8 * i;
          f4 w = W[q];
#pragma unroll
          for (int b = 0; b < BP_; ++b) acc[b] += dot4d(H[b * 130 + q], w);
        }
#pragma unroll
        for (int b = 0; b < BP_; ++b) {
          double v = acc[b];
#pragma unroll
          for (int m = 1; m <= 4; m <<= 1) v += __shfl_xor(v, m);
          if (kc == 0) sm.redH[ci][b] = v;
        }
      }
      __syncthreads();
      {
        int b = tid >> 5, ci = tid & 31, c = ct * 32 + ci;
        double h1 = sm.redH[ci][b] + (double)p.out_b1[c];
        stA1(&p.h1buf[(size_t)(th & 1) * NB_ * NH2_ + (b0 + b) * NH2_ + c], (float)fmax(h1, 0.0));
      }
    }
  }
  // ---------------- score(t-3) (lid 112) ----------------
  else {
    if (t >= 3 && t <= NS_ + 2 && tid < 128) {
      int ts = t - 3;
      int b = tid >> 4, cg = tid & 15;
      const float* h1p = p.h1buf + (size_t)(ts & 1) * NB_ * NH2_;
      double s1 = 0, s2 = 0;
      float hv[16];
#pragma unroll
      for (int i = 0; i < 16; ++i) {
        float v = ldA1(&h1p[(b0 + b) * NH2_ + cg * 16 + i]);
        hv[i] = v; s1 += (double)v; s2 += (double)v * (double)v;
      }
#pragma unroll
      for (int m = 1; m <= 8; m <<= 1) { s1 += __shfl_xor(s1, m); s2 += __shfl_xor(s2, m); }
      double mu = s1 * (1.0 / NH2_), var = s2 * (1.0 / NH2_) - mu * mu, rstd = 1.0 / sqrt(var + 1e-5);
      double d = 0;
#pragma unroll
      for (int i = 0; i < 16; ++i) {
        int c = cg * 16 + i;
        d += (((double)hv[i] - mu) * rstd * p.out_ln_g[c] + (double)p.out_ln_b[c]) * (double)p.out_w2[c];
      }
#pragma unroll
      for (int m = 1; m <= 8; m <<= 1) d += __shfl_xor(d, m);
      if (cg == 0) p.out[(b0 + b) * NS_ + ts] = (float)sigm_d(d + (double)p.out_b2[0]);
    }
  }
}

__global__ __launch_bounds__(256, 1) void seq_kernel(Params p) {
  const int bid = blockIdx.x, tid = threadIdx.x;
  const int d = bid / DBLK, lid = bid - d * DBLK;
  __shared__ Smem sm;
  u32* flags = p.flags + (size_t)d * DBLK * 16;
  u32* rel   = p.rel   + (size_t)d * DBLK * 16;
  for (int t = 0; t <= NS_ + 2; ++t) {
    step_body(p, sm, t, d, lid, tid);
    gbar3(flags, rel, lid, DBLK, (u32)(t + 1));
  }
}

// gg x-projection precompute: gix[bs][row] = sum_k utt[bs][k] * gg_wih[row][k], k<1024 (fp64)
__global__ __launch_bounds__(512) void gix_kernel(const float* utt, const float* ggw, float* gix) {
  __shared__ float xs[16][1028];
  const int tid = threadIdx.x;
  long bs0 = (long)blockIdx.x * 16;
  for (int i = tid; i < 16 * 256; i += 512) {
    int bb = i >> 8, kf = i & 255;
    *(f4*)&xs[bb][kf * 4] = *(const f4*)(utt + (bs0 + bb) * 1024 + kf * 4);
  }
  __syncthreads();
  int R = blockIdx.y * 32 + (tid >> 4);
  int bi = tid & 15;
  const f4* w4 = (const f4*)(ggw + (size_t)R * 1536);
  const f4* x4 = (const f4*)&xs[bi][0];
  double acc = 0;
  for (int k = 0; k < 256; ++k) acc += dot4d(x4[k], w4[k]);
  gix[(size_t)(bs0 + bi) * 1536 + R] = (float)acc;
}

__global__ void init_kernel(float* glob, const float* init_global, u32* flags, u32* rel) {
  long stride = (long)gridDim.x * blockDim.x;
  long t0 = (long)blockIdx.x * blockDim.x + threadIdx.x;
  for (long i = t0; i < (long)NB_ * NSP_ * NH_; i += stride) {
    int sp = ((int)i >> 9) & (NSP_ - 1);
    int k = (int)i & (NH_ - 1);
    glob[i] = init_global[sp * NH_ + k];
  }
  for (long i = t0; i < (long)NBLK * 16; i += stride) { flags[i] = 0u; rel[i] = 0u; }
}

extern "C" void kernel_launch(void* const* d_in, const int* in_sizes, int n_in,
                              void* d_out, int out_size, void* d_ws, size_t ws_size,
                              hipStream_t stream) {
  (void)in_sizes; (void)n_in; (void)out_size;
  Params p;
  p.utt    = (const float*)d_in[0];
  p.spk    = (const int*)d_in[1];
  // d_in[2] init_party: DEAD (party GRU feeds only itself, never the output path)
  const float* ig = (const float*)d_in[3];
  p.init_emotion = (const float*)d_in[4];
  // d_in[5..8] pg_*: DEAD (party GRU)
  p.gg_wih = (const float*)d_in[9];
  p.gg_whh = (const float*)d_in[10];
  p.gg_bih = (const float*)d_in[11];
  p.gg_bhh = (const float*)d_in[12];
  p.eg_wih = (const float*)d_in[13];
  p.eg_whh = (const float*)d_in[14];
  p.eg_bih = (const float*)d_in[15];
  p.eg_bhh = (const float*)d_in[16];
  // 17..19 attention weights: softmax over length-1 axis == 1 -> provably unused
  p.ln_g   = (const float*)d_in[20];
  p.ln_b   = (const float*)d_in[21];
  p.out_w1 = (const float*)d_in[22];
  p.out_b1 = (const float*)d_in[23];
  p.out_ln_g = (const float*)d_in[24];
  p.out_ln_b = (const float*)d_in[25];
  p.out_w2 = (const float*)d_in[26];
  p.out_b2 = (const float*)d_in[27];

  char* w = (char*)d_ws;
  auto alloc = [&](size_t bytes) { char* r = w; w += (bytes + 255) & ~(size_t)255; return r; };
  float* gix   = (float*)alloc((size_t)8192 * 1536 * 4);   // ~50.3 MB
  float* g_new = (float*)alloc((size_t)2 * NB_ * NH_ * 4);
  float* e_out = (float*)alloc((size_t)2 * NB_ * NH_ * 4);
  float* glob  = (float*)alloc((size_t)NB_ * NSP_ * NH_ * 4);
  float* h1buf = (float*)alloc((size_t)2 * NB_ * NH2_ * 4);
  u32*   flags = (u32*)alloc((size_t)NBLK * 16 * 4);
  u32*   rel   = (u32*)alloc((size_t)NBLK * 16 * 4);
  if ((size_t)(w - (char*)d_ws) > ws_size) return;  // ws too small -> loud failure (zeros)

  gix_kernel<<<dim3(512, 48), dim3(512), 0, stream>>>(p.utt, p.gg_wih, gix);
  init_kernel<<<dim3(64), dim3(256), 0, stream>>>(glob, ig, flags, rel);

  p.gix = gix;
  p.g_new = g_new; p.e_out = e_out; p.glob = glob;
  p.h1buf = h1buf; p.flags = flags; p.rel = rel; p.out = (float*)d_out;

  seq_kernel<<<dim3(NBLK), dim3(256), 0, stream>>>(p);
}